// Round 2
// baseline (4421.611 us; speedup 1.0000x reference)
//
#include <hip/hip_runtime.h>

// Problem constants (match reference)
constexpr int Bz = 8192;   // batch
constexpr int Sz = 115;    // state dim
constexpr int Ez = 3072;   // embedding dim
constexpr int NEz = 4096;  // num keys
// C=128, A=23, K=10, TAU=1, EPS=1e-5

typedef _Float16 half4v __attribute__((ext_vector_type(4)));

// =====================================================================
// Generic fp32 tiled GEMM: C[M x N] = act(A[M x K] @ B + bias)
// B is K x N (row-major). Tile 128x128x16, 256 threads, 8x8 per thread.
// M, N multiples of 128. K arbitrary.
// =====================================================================
template<bool RELU, bool BIAS>
__global__ __launch_bounds__(256)
void gemm128(const float* __restrict__ A, const float* __restrict__ Bm,
             const float* __restrict__ bias, float* __restrict__ C,
             int N, int Kd)
{
  __shared__ float As[16][132];
  __shared__ float Bs[16][132];
  const int t  = threadIdx.x;
  const int tx = t & 15, ty = t >> 4;
  const int row0 = blockIdx.y * 128;
  const int col0 = blockIdx.x * 128;
  const int ar = t >> 2, ac = (t & 3) * 4;
  const int bk = t >> 5, bc = (t & 31) * 4;
  const bool a4 = (Kd & 3) == 0;

  float acc[8][8];
#pragma unroll
  for (int i = 0; i < 8; ++i)
#pragma unroll
    for (int j = 0; j < 8; ++j) acc[i][j] = 0.f;

  for (int k0 = 0; k0 < Kd; k0 += 16) {
    const bool fullA = (k0 + 16 <= Kd) && a4;
    { // stage A tile (transposed into LDS)
      const float* ap = A + (size_t)(row0 + ar) * Kd + k0 + ac;
      if (fullA) {
        float4 v0 = *(const float4*)ap;
        float4 v1 = *(const float4*)(ap + (size_t)64 * Kd);
        As[ac + 0][ar] = v0.x; As[ac + 1][ar] = v0.y;
        As[ac + 2][ar] = v0.z; As[ac + 3][ar] = v0.w;
        As[ac + 0][ar + 64] = v1.x; As[ac + 1][ar + 64] = v1.y;
        As[ac + 2][ar + 64] = v1.z; As[ac + 3][ar + 64] = v1.w;
      } else {
#pragma unroll
        for (int e = 0; e < 4; ++e) {
          const int k = k0 + ac + e;
          float v0 = 0.f, v1 = 0.f;
          if (k < Kd) { v0 = ap[e]; v1 = ap[e + (size_t)64 * Kd]; }
          As[ac + e][ar] = v0; As[ac + e][ar + 64] = v1;
        }
      }
    }
    { // stage B tile (K x N)
      const float* bp = Bm + (size_t)(k0 + bk) * N + col0 + bc;
      if (k0 + 16 <= Kd) {
        *(float4*)&Bs[bk][bc]     = *(const float4*)bp;
        *(float4*)&Bs[bk + 8][bc] = *(const float4*)(bp + (size_t)8 * N);
      } else {
        float4 z; z.x = z.y = z.z = z.w = 0.f;
        *(float4*)&Bs[bk][bc]     = (k0 + bk     < Kd) ? *(const float4*)bp : z;
        *(float4*)&Bs[bk + 8][bc] = (k0 + bk + 8 < Kd) ? *(const float4*)(bp + (size_t)8 * N) : z;
      }
    }
    __syncthreads();
#pragma unroll
    for (int kk = 0; kk < 16; ++kk) {
      float a[8], b[8];
      *(float4*)&a[0] = *(const float4*)&As[kk][ty * 4];
      *(float4*)&a[4] = *(const float4*)&As[kk][64 + ty * 4];
      *(float4*)&b[0] = *(const float4*)&Bs[kk][tx * 4];
      *(float4*)&b[4] = *(const float4*)&Bs[kk][64 + tx * 4];
#pragma unroll
      for (int i = 0; i < 8; ++i)
#pragma unroll
        for (int j = 0; j < 8; ++j)
          acc[i][j] = fmaf(a[i], b[j], acc[i][j]);
    }
    __syncthreads();
  }

  float bv[8];
#pragma unroll
  for (int j = 0; j < 8; ++j) bv[j] = 0.f;
  if (BIAS) {
    *(float4*)&bv[0] = *(const float4*)&bias[col0 + tx * 4];
    *(float4*)&bv[4] = *(const float4*)&bias[col0 + 64 + tx * 4];
  }
#pragma unroll
  for (int i = 0; i < 8; ++i) {
    const int r = row0 + ((i < 4) ? (ty * 4 + i) : (64 + ty * 4 + i - 4));
    float o[8];
#pragma unroll
    for (int j = 0; j < 8; ++j) {
      o[j] = acc[i][j] + bv[j];
      if (RELU) o[j] = fmaxf(o[j], 0.f);
    }
    *(float4*)&C[(size_t)r * N + col0 + tx * 4]      = *(float4*)&o[0];
    *(float4*)&C[(size_t)r * N + col0 + 64 + tx * 4] = *(float4*)&o[4];
  }
}

// =====================================================================
// Scores GEMM: S[b,n] = (half)( dot(qn[b,:], keys[n,:]) * rk[n] )
// A = qn (Bz x Ez), B = keys (NEz x Ez) accessed as B^T. K = 3072 (mult of 4).
// Same 128x128x16 tiling.
// =====================================================================
__global__ __launch_bounds__(256)
void gemm_scores(const float* __restrict__ A, const float* __restrict__ Bm,
                 const float* __restrict__ rk, _Float16* __restrict__ S)
{
  __shared__ float As[16][132];
  __shared__ float Bs[16][132];
  const int t  = threadIdx.x;
  const int tx = t & 15, ty = t >> 4;
  const int row0 = blockIdx.y * 128;
  const int col0 = blockIdx.x * 128;
  const int ar = t >> 2, ac = (t & 3) * 4;
  const int Kd = Ez;

  float acc[8][8];
#pragma unroll
  for (int i = 0; i < 8; ++i)
#pragma unroll
    for (int j = 0; j < 8; ++j) acc[i][j] = 0.f;

  for (int k0 = 0; k0 < Kd; k0 += 16) {
    {
      const float* ap = A + (size_t)(row0 + ar) * Kd + k0 + ac;
      float4 v0 = *(const float4*)ap;
      float4 v1 = *(const float4*)(ap + (size_t)64 * Kd);
      As[ac + 0][ar] = v0.x; As[ac + 1][ar] = v0.y;
      As[ac + 2][ar] = v0.z; As[ac + 3][ar] = v0.w;
      As[ac + 0][ar + 64] = v1.x; As[ac + 1][ar + 64] = v1.y;
      As[ac + 2][ar + 64] = v1.z; As[ac + 3][ar + 64] = v1.w;
    }
    {
      const float* bp = Bm + (size_t)(col0 + ar) * Kd + k0 + ac;
      float4 v0 = *(const float4*)bp;
      float4 v1 = *(const float4*)(bp + (size_t)64 * Kd);
      Bs[ac + 0][ar] = v0.x; Bs[ac + 1][ar] = v0.y;
      Bs[ac + 2][ar] = v0.z; Bs[ac + 3][ar] = v0.w;
      Bs[ac + 0][ar + 64] = v1.x; Bs[ac + 1][ar + 64] = v1.y;
      Bs[ac + 2][ar + 64] = v1.z; Bs[ac + 3][ar + 64] = v1.w;
    }
    __syncthreads();
#pragma unroll
    for (int kk = 0; kk < 16; ++kk) {
      float a[8], b[8];
      *(float4*)&a[0] = *(const float4*)&As[kk][ty * 4];
      *(float4*)&a[4] = *(const float4*)&As[kk][64 + ty * 4];
      *(float4*)&b[0] = *(const float4*)&Bs[kk][tx * 4];
      *(float4*)&b[4] = *(const float4*)&Bs[kk][64 + tx * 4];
#pragma unroll
      for (int i = 0; i < 8; ++i)
#pragma unroll
        for (int j = 0; j < 8; ++j)
          acc[i][j] = fmaf(a[i], b[j], acc[i][j]);
    }
    __syncthreads();
  }

  float rk0[8];
  *(float4*)&rk0[0] = *(const float4*)&rk[col0 + tx * 4];
  *(float4*)&rk0[4] = *(const float4*)&rk[col0 + 64 + tx * 4];
#pragma unroll
  for (int i = 0; i < 8; ++i) {
    const int r = row0 + ((i < 4) ? (ty * 4 + i) : (64 + ty * 4 + i - 4));
    half4v h0, h1;
#pragma unroll
    for (int j = 0; j < 4; ++j) h0[j] = (_Float16)(acc[i][j] * rk0[j]);
#pragma unroll
    for (int j = 0; j < 4; ++j) h1[j] = (_Float16)(acc[i][4 + j] * rk0[4 + j]);
    *(half4v*)&S[(size_t)r * NEz + col0 + tx * 4]      = h0;
    *(half4v*)&S[(size_t)r * NEz + col0 + 64 + tx * 4] = h1;
  }
}

// =====================================================================
// Fused small GEMM (N=128 fixed) + row LayerNorm (+optional ReLU).
// A = [A1 (M x K1) | state-slice (M x K2 at col eoff, stride 115)]
// =====================================================================
template<bool RELU>
__global__ __launch_bounds__(256)
void gemm_ln(const float* __restrict__ A1, int K1,
             const float* __restrict__ A2, int eoff, int K2,
             const float* __restrict__ W, const float* __restrict__ bias,
             const float* __restrict__ g, const float* __restrict__ be,
             float* __restrict__ out)
{
  __shared__ float As[32][68];
  __shared__ float Bs[32][132];
  __shared__ float rsum[64][17];
  __shared__ float rsq[64][17];
  __shared__ float stm[64], str[64];
  const int t = threadIdx.x;
  const int tx = t & 15, ty = t >> 4;
  const int row0 = blockIdx.x * 64;
  const int Kt = K1 + K2;
  const int ar = t >> 2, ac = (t & 3) * 8;
  const int bk = t >> 3, bc = (t & 7) * 16;

  float acc[4][8];
#pragma unroll
  for (int i = 0; i < 4; ++i)
#pragma unroll
    for (int j = 0; j < 8; ++j) acc[i][j] = 0.f;

  for (int k0 = 0; k0 < Kt; k0 += 32) {
    const int grow = row0 + ar;
#pragma unroll
    for (int e = 0; e < 8; ++e) {
      const int k = k0 + ac + e;
      float v = 0.f;
      if (k < K1)      v = A1[(size_t)grow * K1 + k];
      else if (k < Kt) v = A2[(size_t)grow * 115 + eoff + (k - K1)];
      As[ac + e][ar] = v;
    }
    {
      const int k = k0 + bk;
#pragma unroll
      for (int qd = 0; qd < 4; ++qd) {
        float4 z; z.x = z.y = z.z = z.w = 0.f;
        *(float4*)&Bs[bk][bc + 4 * qd] =
            (k < Kt) ? *(const float4*)&W[(size_t)k * 128 + bc + 4 * qd] : z;
      }
    }
    __syncthreads();
#pragma unroll
    for (int kk = 0; kk < 32; ++kk) {
      float a[4], b[8];
      *(float4*)&a[0] = *(const float4*)&As[kk][ty * 4];
      *(float4*)&b[0] = *(const float4*)&Bs[kk][tx * 4];
      *(float4*)&b[4] = *(const float4*)&Bs[kk][64 + tx * 4];
#pragma unroll
      for (int i = 0; i < 4; ++i)
#pragma unroll
        for (int j = 0; j < 8; ++j)
          acc[i][j] = fmaf(a[i], b[j], acc[i][j]);
    }
    __syncthreads();
  }

  float bv[8];
  *(float4*)&bv[0] = *(const float4*)&bias[tx * 4];
  *(float4*)&bv[4] = *(const float4*)&bias[64 + tx * 4];
#pragma unroll
  for (int i = 0; i < 4; ++i) {
    float s = 0.f, q = 0.f;
#pragma unroll
    for (int j = 0; j < 8; ++j) {
      acc[i][j] += bv[j];
      s += acc[i][j];
      q += acc[i][j] * acc[i][j];
    }
    rsum[ty * 4 + i][tx] = s;
    rsq[ty * 4 + i][tx]  = q;
  }
  __syncthreads();
  if (t < 64) {
    float s = 0.f, q = 0.f;
#pragma unroll
    for (int x = 0; x < 16; ++x) { s += rsum[t][x]; q += rsq[t][x]; }
    const float m = s * (1.f / 128.f);
    const float v = q * (1.f / 128.f) - m * m;
    stm[t] = m;
    str[t] = rsqrtf(v + 1e-5f);
  }
  __syncthreads();
#pragma unroll
  for (int i = 0; i < 4; ++i) {
    const int r = ty * 4 + i;
    const float m = stm[r], rs = str[r];
    float o[8];
#pragma unroll
    for (int j = 0; j < 8; ++j) {
      const int col = (j < 4) ? (tx * 4 + j) : (64 + tx * 4 + (j - 4));
      float y = (acc[i][j] - m) * rs * g[col] + be[col];
      if (RELU) y = fmaxf(y, 0.f);
      o[j] = y;
    }
    *(float4*)&out[(size_t)(row0 + r) * 128 + tx * 4]      = *(float4*)&o[0];
    *(float4*)&out[(size_t)(row0 + r) * 128 + 64 + tx * 4] = *(float4*)&o[4];
  }
}

// =====================================================================
// Block-wide (256 threads) sum helper
// =====================================================================
__device__ __forceinline__ float blockSum256(float v, float* sh)
{
#pragma unroll
  for (int d = 32; d; d >>= 1) v += __shfl_down(v, d, 64);
  __syncthreads();
  if ((threadIdx.x & 63) == 0) sh[threadIdx.x >> 6] = v;
  __syncthreads();
  return sh[0] + sh[1] + sh[2] + sh[3];
}

// Row LN (width 3072) + L2 normalize, in place: q -> qn
__global__ __launch_bounds__(256)
void ln_l2_q(float* __restrict__ q, const float* __restrict__ g,
             const float* __restrict__ be)
{
  __shared__ float sh[4];
  const int row = blockIdx.x, t = threadIdx.x;
  float* qr = q + (size_t)row * Ez;
  float x[12];
#pragma unroll
  for (int i = 0; i < 12; ++i) x[i] = qr[t + (i << 8)];
  float s = 0.f;
#pragma unroll
  for (int i = 0; i < 12; ++i) s += x[i];
  const float m = blockSum256(s, sh) * (1.f / (float)Ez);
  float vs = 0.f;
#pragma unroll
  for (int i = 0; i < 12; ++i) { const float d = x[i] - m; vs += d * d; }
  const float v = blockSum256(vs, sh) * (1.f / (float)Ez);
  const float rs = rsqrtf(v + 1e-5f);
  float y[12]; float qs = 0.f;
#pragma unroll
  for (int i = 0; i < 12; ++i) {
    const int c = t + (i << 8);
    const float yy = (x[i] - m) * rs * g[c] + be[c];
    y[i] = yy; qs += yy * yy;
  }
  const float tot = blockSum256(qs, sh);
  const float s2 = rsqrtf(tot + 1e-12f);
#pragma unroll
  for (int i = 0; i < 12; ++i) qr[t + (i << 8)] = y[i] * s2;
}

// Per-key reciprocal norm: rk[n] = rsqrtf(sum(keys[n,:]^2) + 1e-12)
__global__ __launch_bounds__(256)
void keynorm(const float* __restrict__ keys, float* __restrict__ rk)
{
  __shared__ float sh[4];
  const int row = blockIdx.x, t = threadIdx.x;
  const float* xr = keys + (size_t)row * Ez;
  float qs = 0.f;
#pragma unroll
  for (int i = 0; i < 12; ++i) { const float x = xr[t + (i << 8)]; qs += x * x; }
  const float tot = blockSum256(qs, sh);
  if (t == 0) rk[row] = rsqrtf(tot + 1e-12f);
}

// =====================================================================
// Top-16 per row of the 8192 x 4096 fp16 score matrix (iterated argmax).
// =====================================================================
__global__ __launch_bounds__(256)
void topk16(const _Float16* __restrict__ S, int* __restrict__ outIdx)
{
  __shared__ float wv[4];
  __shared__ int wi[4];
  __shared__ int gi;
  const int row = blockIdx.x, t = threadIdx.x;
  const _Float16* sr = S + (size_t)row * NEz;
  float xv[16];
#pragma unroll
  for (int j = 0; j < 16; ++j) xv[j] = (float)sr[t + (j << 8)];

  for (int it = 0; it < 16; ++it) {
    float bvv = xv[0]; int bj = 0;
#pragma unroll
    for (int j = 1; j < 16; ++j)
      if (xv[j] > bvv) { bvv = xv[j]; bj = j; }
    int bc = t + (bj << 8);
#pragma unroll
    for (int d = 32; d; d >>= 1) {
      const float ov = __shfl_down(bvv, d, 64);
      const int   oc = __shfl_down(bc, d, 64);
      if (ov > bvv || (ov == bvv && oc < bc)) { bvv = ov; bc = oc; }
    }
    if ((t & 63) == 0) { wv[t >> 6] = bvv; wi[t >> 6] = bc; }
    __syncthreads();
    if (t == 0) {
      float fv = wv[0]; int fc = wi[0];
#pragma unroll
      for (int w = 1; w < 4; ++w)
        if (wv[w] > fv || (wv[w] == fv && wi[w] < fc)) { fv = wv[w]; fc = wi[w]; }
      gi = fc;
      outIdx[(size_t)row * 16 + it] = fc;
    }
    __syncthreads();
    const int w = gi;
    if ((w & 255) == t) {
      const int jc = w >> 8;
#pragma unroll
      for (int j = 0; j < 16; ++j)
        if (j == jc) xv[j] = -3.402823466e38f;
    }
  }
}

// =====================================================================
// fp64 rescore of the 16 candidates against raw keys * rk; exact top-10.
// =====================================================================
__global__ __launch_bounds__(256)
void rescore(const float* __restrict__ qn, const float* __restrict__ keys,
             const float* __restrict__ rk, const int* __restrict__ cand,
             int* __restrict__ outIdx)
{
  __shared__ double sv[16];
  __shared__ int si[16];
  const int row = blockIdx.x, t = threadIdx.x;
  const int gr = t >> 4, l = t & 15;
  const int id = cand[(size_t)row * 16 + gr];
  const float* qr = qn + (size_t)row * Ez;
  const float* kr = keys + (size_t)id * Ez;
  double s = 0.0;
  for (int c = l; c < Ez; c += 16)
    s += (double)qr[c] * (double)kr[c];
#pragma unroll
  for (int d = 8; d; d >>= 1) s += __shfl_down(s, d, 16);
  if (l == 0) { sv[gr] = s * (double)rk[id]; si[gr] = id; }
  __syncthreads();
  if (t == 0) {
    for (int it = 0; it < 10; ++it) {
      int bj = 0; double bvv = sv[0]; int bi = si[0];
      for (int j = 1; j < 16; ++j) {
        const double v = sv[j]; const int i2 = si[j];
        if (v > bvv || (v == bvv && i2 < bi)) { bj = j; bvv = v; bi = i2; }
      }
      outIdx[(size_t)row * 10 + it] = bi;
      sv[bj] = -1e300;
    }
  }
}

// context[b] = mean over 10 gathered (raw) key rows
__global__ __launch_bounds__(256)
void gather_ctx(const float* __restrict__ keys, const int* __restrict__ idx10,
                float* __restrict__ ctx)
{
  const int row = blockIdx.x, t = threadIdx.x;
  int id[10];
#pragma unroll
  for (int j = 0; j < 10; ++j) id[j] = idx10[(size_t)row * 10 + j];
#pragma unroll
  for (int i = 0; i < 12; ++i) {
    const int c = t + (i << 8);
    float s = 0.f;
#pragma unroll
    for (int j = 0; j < 10; ++j) s += keys[(size_t)id[j] * Ez + c];
    ctx[(size_t)row * Ez + c] = s * 0.1f;
  }
}

// =====================================================================
// Router: 115 -> 64 -> 64 -> 4, clip(+-20), + gumbel, softmax, straight-through
// =====================================================================
__global__ __launch_bounds__(256)
void router_kernel(const float* __restrict__ state, const float* __restrict__ gn,
                   const float* __restrict__ w1, const float* __restrict__ b1,
                   const float* __restrict__ w2, const float* __restrict__ b2,
                   const float* __restrict__ w3, const float* __restrict__ b3,
                   float* __restrict__ outAlpha)
{
  const int row = blockIdx.x * 256 + threadIdx.x;
  const float* sr = state + (size_t)row * Sz;
  float h1[64];
#pragma unroll
  for (int j = 0; j < 64; ++j) h1[j] = b1[j];
  for (int k = 0; k < Sz; ++k) {
    const float a = sr[k];
    const float* wr = w1 + (size_t)k * 64;
#pragma unroll
    for (int j = 0; j < 64; ++j) h1[j] = fmaf(a, wr[j], h1[j]);
  }
#pragma unroll
  for (int j = 0; j < 64; ++j) h1[j] = fmaxf(h1[j], 0.f);
  float h2[64];
#pragma unroll
  for (int j = 0; j < 64; ++j) h2[j] = b2[j];
#pragma unroll
  for (int k = 0; k < 64; ++k) {
    const float a = h1[k];
    const float* wr = w2 + (size_t)k * 64;
#pragma unroll
    for (int j = 0; j < 64; ++j) h2[j] = fmaf(a, wr[j], h2[j]);
  }
#pragma unroll
  for (int j = 0; j < 64; ++j) h2[j] = fmaxf(h2[j], 0.f);
  float z[4];
#pragma unroll
  for (int a = 0; a < 4; ++a) {
    float s = b3[a];
#pragma unroll
    for (int k = 0; k < 64; ++k) s = fmaf(h2[k], w3[k * 4 + a], s);
    s = fminf(fmaxf(s, -20.f), 20.f);
    z[a] = s + gn[(size_t)row * 4 + a];   // TAU = 1
  }
  float mz = z[0];
#pragma unroll
  for (int a = 1; a < 4; ++a) mz = fmaxf(mz, z[a]);
  float e[4]; float se = 0.f;
#pragma unroll
  for (int a = 0; a < 4; ++a) { e[a] = expf(z[a] - mz); se += e[a]; }
  const float inv = 1.f / se;
  float y[4];
#pragma unroll
  for (int a = 0; a < 4; ++a) y[a] = e[a] * inv;
  int am = 0;
#pragma unroll
  for (int a = 1; a < 4; ++a) if (y[a] > y[am]) am = a;
#pragma unroll
  for (int a = 0; a < 4; ++a) {
    const float hard = (a == am) ? 1.f : 0.f;
    outAlpha[(size_t)row * 4 + a] = y[a] + (hard - y[a]);
  }
}

// critic head: value = c2 @ w3 + b3 (N=1)
__global__ __launch_bounds__(256)
void critic_head(const float* __restrict__ c2, const float* __restrict__ w3,
                 const float* __restrict__ b3, float* __restrict__ outv)
{
  const int row = blockIdx.x * 256 + threadIdx.x;
  const float* xr = c2 + (size_t)row * 256;
  float s = b3[0];
  for (int k = 0; k < 256; ++k) s = fmaf(xr[k], w3[k], s);
  outv[row] = s;
}

// actor head: l = x2 @ w3(128x23) + b3 ; logits (+)= alpha[:,k] * l
__global__ __launch_bounds__(256)
void actor_out(const float* __restrict__ X, const float* __restrict__ W3,
               const float* __restrict__ b3, const float* __restrict__ alpha,
               float* __restrict__ outL, int kidx)
{
  __shared__ float wsm[128 * 23];
  __shared__ float bs[23];
  const int t = threadIdx.x;
  for (int i = t; i < 128 * 23; i += 256) wsm[i] = W3[i];
  if (t < 23) bs[t] = b3[t];
  __syncthreads();
  const int row = blockIdx.x * 64 + (t >> 2);
  const int cg = t & 3;
  float acc[6] = {0.f, 0.f, 0.f, 0.f, 0.f, 0.f};
  const float* xr = X + (size_t)row * 128;
  for (int kk = 0; kk < 128; ++kk) {
    const float a = xr[kk];
#pragma unroll
    for (int j = 0; j < 6; ++j) {
      const int col = cg + 4 * j;
      if (col < 23) acc[j] = fmaf(a, wsm[kk * 23 + col], acc[j]);
    }
  }
  const float al = alpha[(size_t)row * 4 + kidx];
#pragma unroll
  for (int j = 0; j < 6; ++j) {
    const int col = cg + 4 * j;
    if (col < 23) {
      const float v = al * (acc[j] + bs[col]);
      const size_t o = (size_t)row * 23 + col;
      outL[o] = (kidx == 0) ? v : (outL[o] + v);
    }
  }
}

// =====================================================================
extern "C" void kernel_launch(void* const* d_in, const int* in_sizes, int n_in,
                              void* d_out, int out_size, void* d_ws, size_t ws_size,
                              hipStream_t stream)
{
  const float* state  = (const float*)d_in[0];
  const float* gumbel = (const float*)d_in[1];
  const float* keys   = (const float*)d_in[2];
  const float* se_w1 = (const float*)d_in[3];
  const float* se_b1 = (const float*)d_in[4];
  const float* se_w2 = (const float*)d_in[5];
  const float* se_b2 = (const float*)d_in[6];
  const float* se_w3 = (const float*)d_in[7];
  const float* se_b3 = (const float*)d_in[8];
  const float* se_g  = (const float*)d_in[9];
  const float* se_be = (const float*)d_in[10];
  const float* cc_w1 = (const float*)d_in[11];
  const float* cc_b1 = (const float*)d_in[12];
  const float* cc_w2 = (const float*)d_in[13];
  const float* cc_b2 = (const float*)d_in[14];
  const float* cc_g  = (const float*)d_in[15];
  const float* cc_be = (const float*)d_in[16];
  const float* r_w1 = (const float*)d_in[57];
  const float* r_b1 = (const float*)d_in[58];
  const float* r_w2 = (const float*)d_in[59];
  const float* r_b2 = (const float*)d_in[60];
  const float* r_w3 = (const float*)d_in[61];
  const float* r_b3 = (const float*)d_in[62];
  const float* c_w1 = (const float*)d_in[63];
  const float* c_b1 = (const float*)d_in[64];
  const float* c_w2 = (const float*)d_in[65];
  const float* c_b2 = (const float*)d_in[66];
  const float* c_w3 = (const float*)d_in[67];
  const float* c_b3 = (const float*)d_in[68];

  // ---- workspace layout (~169 MB peak, phase-overlapped) ----
  float* wsf = (float*)d_ws;
  // R0: q / qn (8192 x 3072 fp32); reused for ctx after rescore.
  float* q = wsf;                                       // 25,165,824 floats
  // R1: 16,777,216-float union region
  float* R1 = q + (size_t)Bz * Ez;
  //   phase E (encoder):   sA | sB
  float* sA = R1;                                       // 8192*512
  float* sB = R1 + (size_t)Bz * 512;                    // 8192*512
  //   phase S (retrieval): fp16 score matrix
  _Float16* scoresH = (_Float16*)R1;                    // 8192*4096 halves
  //   phase P (post):      cc hidden, shared, x1, x2, critic h1, h2
  float* cch  = R1;                                     // 8192*512
  float* shr  = cch + (size_t)Bz * 512;                 // 8192*128
  float* x1   = shr + (size_t)Bz * 128;                 // 8192*128
  float* x2   = x1  + (size_t)Bz * 128;                 // 8192*128
  float* cr1  = x2  + (size_t)Bz * 128;                 // 8192*256
  float* cr2  = cr1 + (size_t)Bz * 256;                 // 8192*256
  // tail: small buffers
  float* tail = R1 + (size_t)16777216;
  float* rk   = tail;                                   // 4096
  int*  cand  = (int*)(tail + 4096);                    // 8192*16
  int*  sel   = cand + (size_t)Bz * 16;                 // 8192*10

  float* outL = (float*)d_out;                  // 8192*23
  float* outA = outL + (size_t)Bz * 23;         // 8192*4
  float* outV = outA + (size_t)Bz * 4;          // 8192*1

  const dim3 blk(256);

  // --- state encoder ---
  gemm128<true,  true><<<dim3(4, 64),  blk, 0, stream>>>(state, se_w1, se_b1, sA, 512, 115);
  gemm128<true,  true><<<dim3(4, 64),  blk, 0, stream>>>(sA,    se_w2, se_b2, sB, 512, 512);
  gemm128<false, true><<<dim3(24, 64), blk, 0, stream>>>(sB,    se_w3, se_b3, q, 3072, 512);
  ln_l2_q<<<dim3(Bz), blk, 0, stream>>>(q, se_g, se_be);
  keynorm<<<dim3(NEz), blk, 0, stream>>>(keys, rk);

  // --- retrieval: fp16 score screen, top-16, fp64 rescore -> top-10 ---
  gemm_scores<<<dim3(32, 64), blk, 0, stream>>>(q, keys, rk, scoresH);
  topk16<<<dim3(Bz), blk, 0, stream>>>(scoresH, cand);
  rescore<<<dim3(Bz), blk, 0, stream>>>(q, keys, rk, cand, sel);
  gather_ctx<<<dim3(Bz), blk, 0, stream>>>(keys, sel, q);   // q := context now

  // --- context compressor ---
  gemm128<true, true><<<dim3(4, 64), blk, 0, stream>>>(q, cc_w1, cc_b1, cch, 512, 3072);
  gemm_ln<false><<<dim3(128), blk, 0, stream>>>(cch, 512, nullptr, 0, 0,
                                                cc_w2, cc_b2, cc_g, cc_be, shr);

  // --- critic ---
  gemm128<true, true><<<dim3(2, 64), blk, 0, stream>>>(state, c_w1, c_b1, cr1, 256, 115);
  gemm128<true, true><<<dim3(2, 64), blk, 0, stream>>>(cr1, c_w2, c_b2, cr2, 256, 256);
  critic_head<<<dim3(32), blk, 0, stream>>>(cr2, c_w3, c_b3, outV);

  // --- router / gumbel straight-through ---
  router_kernel<<<dim3(32), blk, 0, stream>>>(state, gumbel, r_w1, r_b1, r_w2, r_b2,
                                              r_w3, r_b3, outA);

  // --- actors ---
  const int eoffs[4] = {0, 20, 40, 45};
  const int elens[4] = {50, 20, 10, 15};
  for (int k = 0; k < 4; ++k) {
    const int base = 17 + 10 * k;
    const float* w1 = (const float*)d_in[base + 0];
    const float* b1 = (const float*)d_in[base + 1];
    const float* g1 = (const float*)d_in[base + 2];
    const float* be1 = (const float*)d_in[base + 3];
    const float* w2 = (const float*)d_in[base + 4];
    const float* b2 = (const float*)d_in[base + 5];
    const float* g2 = (const float*)d_in[base + 6];
    const float* be2 = (const float*)d_in[base + 7];
    const float* w3 = (const float*)d_in[base + 8];
    const float* b3 = (const float*)d_in[base + 9];
    gemm_ln<true><<<dim3(128), blk, 0, stream>>>(shr, 128, state, eoffs[k], elens[k],
                                                 w1, b1, g1, be1, x1);
    gemm_ln<true><<<dim3(128), blk, 0, stream>>>(x1, 128, nullptr, 0, 0,
                                                 w2, b2, g2, be2, x2);
    actor_out<<<dim3(128), blk, 0, stream>>>(x2, w3, b3, outA, outL, k);
  }
}

// Round 3
// 1893.126 us; speedup vs baseline: 2.3356x; 2.3356x over previous
//
#include <hip/hip_runtime.h>

// Problem constants (match reference)
constexpr int Bz = 8192;   // batch
constexpr int Sz = 115;    // state dim
constexpr int Ez = 3072;   // embedding dim
constexpr int NEz = 4096;  // num keys
// C=128, A=23, K=10, TAU=1, EPS=1e-5

typedef _Float16 half4v __attribute__((ext_vector_type(4)));
typedef __attribute__((ext_vector_type(8))) short short8;
typedef __attribute__((ext_vector_type(4))) float floatx4;
typedef unsigned short ushort_t;
typedef unsigned int uint_t;

__device__ __forceinline__ ushort_t f2bf(float f) {
  uint_t u = __float_as_uint(f);
  uint_t r = (u + 0x7FFFu + ((u >> 16) & 1u)) >> 16;   // RNE
  return (ushort_t)r;
}

// async global->LDS, 16 B per lane; lds dest = wave-uniform base + lane*16
__device__ __forceinline__ void gload16(const ushort_t* g, ushort_t* l) {
  __builtin_amdgcn_global_load_lds(
      (__attribute__((address_space(1))) const void*)g,
      (__attribute__((address_space(3))) void*)l, 16, 0, 0);
}

// =====================================================================
// Generic fp32 tiled GEMM: C[M x N] = act(A[M x K] @ B + bias)
// B is K x N row-major. Tile 128x128x16, 256 threads, 8x8/thread.
// =====================================================================
template<bool RELU, bool BIAS>
__global__ __launch_bounds__(256)
void gemm128(const float* __restrict__ A, const float* __restrict__ Bm,
             const float* __restrict__ bias, float* __restrict__ C,
             int N, int Kd)
{
  __shared__ float As[16][132];
  __shared__ float Bs[16][132];
  const int t  = threadIdx.x;
  const int tx = t & 15, ty = t >> 4;
  const int row0 = blockIdx.y * 128;
  const int col0 = blockIdx.x * 128;
  const int ar = t >> 2, ac = (t & 3) * 4;
  const int bk = t >> 5, bc = (t & 31) * 4;
  const bool a4 = (Kd & 3) == 0;

  float acc[8][8];
#pragma unroll
  for (int i = 0; i < 8; ++i)
#pragma unroll
    for (int j = 0; j < 8; ++j) acc[i][j] = 0.f;

  for (int k0 = 0; k0 < Kd; k0 += 16) {
    const bool fullA = (k0 + 16 <= Kd) && a4;
    {
      const float* ap = A + (size_t)(row0 + ar) * Kd + k0 + ac;
      if (fullA) {
        float4 v0 = *(const float4*)ap;
        float4 v1 = *(const float4*)(ap + (size_t)64 * Kd);
        As[ac + 0][ar] = v0.x; As[ac + 1][ar] = v0.y;
        As[ac + 2][ar] = v0.z; As[ac + 3][ar] = v0.w;
        As[ac + 0][ar + 64] = v1.x; As[ac + 1][ar + 64] = v1.y;
        As[ac + 2][ar + 64] = v1.z; As[ac + 3][ar + 64] = v1.w;
      } else {
#pragma unroll
        for (int e = 0; e < 4; ++e) {
          const int k = k0 + ac + e;
          float v0 = 0.f, v1 = 0.f;
          if (k < Kd) { v0 = ap[e]; v1 = ap[e + (size_t)64 * Kd]; }
          As[ac + e][ar] = v0; As[ac + e][ar + 64] = v1;
        }
      }
    }
    {
      const float* bp = Bm + (size_t)(k0 + bk) * N + col0 + bc;
      if (k0 + 16 <= Kd) {
        *(float4*)&Bs[bk][bc]     = *(const float4*)bp;
        *(float4*)&Bs[bk + 8][bc] = *(const float4*)(bp + (size_t)8 * N);
      } else {
        float4 z; z.x = z.y = z.z = z.w = 0.f;
        *(float4*)&Bs[bk][bc]     = (k0 + bk     < Kd) ? *(const float4*)bp : z;
        *(float4*)&Bs[bk + 8][bc] = (k0 + bk + 8 < Kd) ? *(const float4*)(bp + (size_t)8 * N) : z;
      }
    }
    __syncthreads();
#pragma unroll
    for (int kk = 0; kk < 16; ++kk) {
      float a[8], b[8];
      *(float4*)&a[0] = *(const float4*)&As[kk][ty * 4];
      *(float4*)&a[4] = *(const float4*)&As[kk][64 + ty * 4];
      *(float4*)&b[0] = *(const float4*)&Bs[kk][tx * 4];
      *(float4*)&b[4] = *(const float4*)&Bs[kk][64 + tx * 4];
#pragma unroll
      for (int i = 0; i < 8; ++i)
#pragma unroll
        for (int j = 0; j < 8; ++j)
          acc[i][j] = fmaf(a[i], b[j], acc[i][j]);
    }
    __syncthreads();
  }

  float bv[8];
#pragma unroll
  for (int j = 0; j < 8; ++j) bv[j] = 0.f;
  if (BIAS) {
    *(float4*)&bv[0] = *(const float4*)&bias[col0 + tx * 4];
    *(float4*)&bv[4] = *(const float4*)&bias[col0 + 64 + tx * 4];
  }
#pragma unroll
  for (int i = 0; i < 8; ++i) {
    const int r = row0 + ((i < 4) ? (ty * 4 + i) : (64 + ty * 4 + i - 4));
    float o[8];
#pragma unroll
    for (int j = 0; j < 8; ++j) {
      o[j] = acc[i][j] + bv[j];
      if (RELU) o[j] = fmaxf(o[j], 0.f);
    }
    *(float4*)&C[(size_t)r * N + col0 + tx * 4]      = *(float4*)&o[0];
    *(float4*)&C[(size_t)r * N + col0 + 64 + tx * 4] = *(float4*)&o[4];
  }
}

// =====================================================================
// bf16 MFMA GEMM, A(M x K) @ B(N x K)^T, both row-major bf16 (K-contig).
// Tile 128x128xBK32, 256 thr = 4 waves (2x2 of 64x64), 4x4 MFMA acc/wave.
// EPI=0: store fp16 (scores). EPI=1: fp32 + bias + ReLU.
// =====================================================================
template<int EPI>
__global__ __launch_bounds__(256)
void mfma_bt(const ushort_t* __restrict__ A, const ushort_t* __restrict__ B,
             const float* __restrict__ bias, void* __restrict__ Cout,
             int N, int Kd)
{
  __shared__ ushort_t Al[128 * 32];
  __shared__ ushort_t Bl[128 * 32];
  const int t = threadIdx.x;
  const int wid = t >> 6, lane = t & 63;
  const int wr = wid >> 1, wc = wid & 1;
  const int row0 = blockIdx.y * 128;
  const int col0 = blockIdx.x * 128;
  const int srow = lane >> 2;          // staging row within 16-row chunk
  const int scol = (lane & 3) * 8;     // staging halves offset within 32

  const ushort_t* ga0 = A + (size_t)(row0 + wid * 16 + srow) * Kd + scol;
  const ushort_t* ga1 = A + (size_t)(row0 + (wid + 4) * 16 + srow) * Kd + scol;
  const ushort_t* gb0 = B + (size_t)(col0 + wid * 16 + srow) * Kd + scol;
  const ushort_t* gb1 = B + (size_t)(col0 + (wid + 4) * 16 + srow) * Kd + scol;
  ushort_t* la0 = &Al[(wid * 16) * 32];
  ushort_t* la1 = &Al[((wid + 4) * 16) * 32];
  ushort_t* lb0 = &Bl[(wid * 16) * 32];
  ushort_t* lb1 = &Bl[((wid + 4) * 16) * 32];

  const int mr = lane & 15, qd = lane >> 4;

  floatx4 acc[4][4];
#pragma unroll
  for (int i = 0; i < 4; ++i)
#pragma unroll
    for (int j = 0; j < 4; ++j) acc[i][j] = (floatx4){0.f, 0.f, 0.f, 0.f};

  for (int kb = 0; kb < Kd; kb += 32) {
    gload16(ga0 + kb, la0);
    gload16(ga1 + kb, la1);
    gload16(gb0 + kb, lb0);
    gload16(gb1 + kb, lb1);
    __syncthreads();
    short8 aF[4], bF[4];
#pragma unroll
    for (int i = 0; i < 4; ++i)
      aF[i] = *(const short8*)&Al[(wr * 64 + i * 16 + mr) * 32 + qd * 8];
#pragma unroll
    for (int j = 0; j < 4; ++j)
      bF[j] = *(const short8*)&Bl[(wc * 64 + j * 16 + mr) * 32 + qd * 8];
#pragma unroll
    for (int i = 0; i < 4; ++i)
#pragma unroll
      for (int j = 0; j < 4; ++j)
        acc[i][j] = __builtin_amdgcn_mfma_f32_16x16x32_bf16(aF[i], bF[j], acc[i][j], 0, 0, 0);
    __syncthreads();
  }

  // C/D layout: col = lane&15, row = (lane>>4)*4 + reg
#pragma unroll
  for (int i = 0; i < 4; ++i) {
#pragma unroll
    for (int j = 0; j < 4; ++j) {
      const int col = col0 + wc * 64 + j * 16 + mr;
#pragma unroll
      for (int r = 0; r < 4; ++r) {
        const int row = row0 + wr * 64 + i * 16 + qd * 4 + r;
        if (EPI == 0) {
          ((_Float16*)Cout)[(size_t)row * N + col] = (_Float16)acc[i][j][r];
        } else {
          float v = acc[i][j][r] + bias[col];
          ((float*)Cout)[(size_t)row * N + col] = fmaxf(v, 0.f);
        }
      }
    }
  }
}

// =====================================================================
// fp32 scores GEMM (fallback path only, round-2-identical numerics)
// =====================================================================
__global__ __launch_bounds__(256)
void gemm_scores(const float* __restrict__ A, const float* __restrict__ Bm,
                 const float* __restrict__ rk, _Float16* __restrict__ S)
{
  __shared__ float As[16][132];
  __shared__ float Bs[16][132];
  const int t  = threadIdx.x;
  const int tx = t & 15, ty = t >> 4;
  const int row0 = blockIdx.y * 128;
  const int col0 = blockIdx.x * 128;
  const int ar = t >> 2, ac = (t & 3) * 4;
  const int Kd = Ez;

  float acc[8][8];
#pragma unroll
  for (int i = 0; i < 8; ++i)
#pragma unroll
    for (int j = 0; j < 8; ++j) acc[i][j] = 0.f;

  for (int k0 = 0; k0 < Kd; k0 += 16) {
    {
      const float* ap = A + (size_t)(row0 + ar) * Kd + k0 + ac;
      float4 v0 = *(const float4*)ap;
      float4 v1 = *(const float4*)(ap + (size_t)64 * Kd);
      As[ac + 0][ar] = v0.x; As[ac + 1][ar] = v0.y;
      As[ac + 2][ar] = v0.z; As[ac + 3][ar] = v0.w;
      As[ac + 0][ar + 64] = v1.x; As[ac + 1][ar + 64] = v1.y;
      As[ac + 2][ar + 64] = v1.z; As[ac + 3][ar + 64] = v1.w;
    }
    {
      const float* bp = Bm + (size_t)(col0 + ar) * Kd + k0 + ac;
      float4 v0 = *(const float4*)bp;
      float4 v1 = *(const float4*)(bp + (size_t)64 * Kd);
      Bs[ac + 0][ar] = v0.x; Bs[ac + 1][ar] = v0.y;
      Bs[ac + 2][ar] = v0.z; Bs[ac + 3][ar] = v0.w;
      Bs[ac + 0][ar + 64] = v1.x; Bs[ac + 1][ar + 64] = v1.y;
      Bs[ac + 2][ar + 64] = v1.z; Bs[ac + 3][ar + 64] = v1.w;
    }
    __syncthreads();
#pragma unroll
    for (int kk = 0; kk < 16; ++kk) {
      float a[8], b[8];
      *(float4*)&a[0] = *(const float4*)&As[kk][ty * 4];
      *(float4*)&a[4] = *(const float4*)&As[kk][64 + ty * 4];
      *(float4*)&b[0] = *(const float4*)&Bs[kk][tx * 4];
      *(float4*)&b[4] = *(const float4*)&Bs[kk][64 + tx * 4];
#pragma unroll
      for (int i = 0; i < 8; ++i)
#pragma unroll
        for (int j = 0; j < 8; ++j)
          acc[i][j] = fmaf(a[i], b[j], acc[i][j]);
    }
    __syncthreads();
  }

  float rk0[8];
  *(float4*)&rk0[0] = *(const float4*)&rk[col0 + tx * 4];
  *(float4*)&rk0[4] = *(const float4*)&rk[col0 + 64 + tx * 4];
#pragma unroll
  for (int i = 0; i < 8; ++i) {
    const int r = row0 + ((i < 4) ? (ty * 4 + i) : (64 + ty * 4 + i - 4));
    half4v h0, h1;
#pragma unroll
    for (int j = 0; j < 4; ++j) h0[j] = (_Float16)(acc[i][j] * rk0[j]);
#pragma unroll
    for (int j = 0; j < 4; ++j) h1[j] = (_Float16)(acc[i][4 + j] * rk0[4 + j]);
    *(half4v*)&S[(size_t)r * NEz + col0 + tx * 4]      = h0;
    *(half4v*)&S[(size_t)r * NEz + col0 + 64 + tx * 4] = h1;
  }
}

// =====================================================================
// Batched (4-actor) fused GEMM(N=128) + LayerNorm (+ReLU).
// blockIdx.y selects the parameter set.
// =====================================================================
struct LN4 {
  const float* W[4]; const float* b[4]; const float* g[4]; const float* be[4];
  int eoff[4]; int elen[4];
};

template<bool RELU, bool HASEXT>
__global__ __launch_bounds__(256)
void gemm_ln4(const float* __restrict__ A1base, size_t a1stride, int K1,
              const float* __restrict__ A2, LN4 p,
              float* __restrict__ outbase, size_t ostride)
{
  __shared__ float As[32][68];
  __shared__ float Bs[32][132];
  __shared__ float rsum[64][17];
  __shared__ float rsq[64][17];
  __shared__ float stm[64], str[64];
  const int a = blockIdx.y;
  const float* A1 = A1base + (size_t)a * a1stride;
  float* out = outbase + (size_t)a * ostride;
  const float* W = p.W[a];
  const float* bias = p.b[a];
  const float* g = p.g[a];
  const float* be = p.be[a];
  const int eoff = HASEXT ? p.eoff[a] : 0;
  const int K2 = HASEXT ? p.elen[a] : 0;

  const int t = threadIdx.x;
  const int tx = t & 15, ty = t >> 4;
  const int row0 = blockIdx.x * 64;
  const int Kt = K1 + K2;
  const int ar = t >> 2, ac = (t & 3) * 8;
  const int bk = t >> 3, bc = (t & 7) * 16;

  float acc[4][8];
#pragma unroll
  for (int i = 0; i < 4; ++i)
#pragma unroll
    for (int j = 0; j < 8; ++j) acc[i][j] = 0.f;

  for (int k0 = 0; k0 < Kt; k0 += 32) {
    const int grow = row0 + ar;
#pragma unroll
    for (int e = 0; e < 8; ++e) {
      const int k = k0 + ac + e;
      float v = 0.f;
      if (k < K1)      v = A1[(size_t)grow * K1 + k];
      else if (k < Kt) v = A2[(size_t)grow * 115 + eoff + (k - K1)];
      As[ac + e][ar] = v;
    }
    {
      const int k = k0 + bk;
#pragma unroll
      for (int qd = 0; qd < 4; ++qd) {
        float4 z; z.x = z.y = z.z = z.w = 0.f;
        *(float4*)&Bs[bk][bc + 4 * qd] =
            (k < Kt) ? *(const float4*)&W[(size_t)k * 128 + bc + 4 * qd] : z;
      }
    }
    __syncthreads();
#pragma unroll
    for (int kk = 0; kk < 32; ++kk) {
      float av[4], bv2[8];
      *(float4*)&av[0]  = *(const float4*)&As[kk][ty * 4];
      *(float4*)&bv2[0] = *(const float4*)&Bs[kk][tx * 4];
      *(float4*)&bv2[4] = *(const float4*)&Bs[kk][64 + tx * 4];
#pragma unroll
      for (int i = 0; i < 4; ++i)
#pragma unroll
        for (int j = 0; j < 8; ++j)
          acc[i][j] = fmaf(av[i], bv2[j], acc[i][j]);
    }
    __syncthreads();
  }

  float bv[8];
  *(float4*)&bv[0] = *(const float4*)&bias[tx * 4];
  *(float4*)&bv[4] = *(const float4*)&bias[64 + tx * 4];
#pragma unroll
  for (int i = 0; i < 4; ++i) {
    float s = 0.f, q = 0.f;
#pragma unroll
    for (int j = 0; j < 8; ++j) {
      acc[i][j] += bv[j];
      s += acc[i][j];
      q += acc[i][j] * acc[i][j];
    }
    rsum[ty * 4 + i][tx] = s;
    rsq[ty * 4 + i][tx]  = q;
  }
  __syncthreads();
  if (t < 64) {
    float s = 0.f, q = 0.f;
#pragma unroll
    for (int x = 0; x < 16; ++x) { s += rsum[t][x]; q += rsq[t][x]; }
    const float m = s * (1.f / 128.f);
    const float v = q * (1.f / 128.f) - m * m;
    stm[t] = m;
    str[t] = rsqrtf(v + 1e-5f);
  }
  __syncthreads();
#pragma unroll
  for (int i = 0; i < 4; ++i) {
    const int r = ty * 4 + i;
    const float m = stm[r], rs = str[r];
    float o[8];
#pragma unroll
    for (int j = 0; j < 8; ++j) {
      const int col = (j < 4) ? (tx * 4 + j) : (64 + tx * 4 + (j - 4));
      float y = (acc[i][j] - m) * rs * g[col] + be[col];
      if (RELU) y = fmaxf(y, 0.f);
      o[j] = y;
    }
    *(float4*)&out[(size_t)(row0 + r) * 128 + tx * 4]      = *(float4*)&o[0];
    *(float4*)&out[(size_t)(row0 + r) * 128 + 64 + tx * 4] = *(float4*)&o[4];
  }
}

// =====================================================================
// Block-wide (256 threads) sum helper
// =====================================================================
__device__ __forceinline__ float blockSum256(float v, float* sh)
{
#pragma unroll
  for (int d = 32; d; d >>= 1) v += __shfl_down(v, d, 64);
  __syncthreads();
  if ((threadIdx.x & 63) == 0) sh[threadIdx.x >> 6] = v;
  __syncthreads();
  return sh[0] + sh[1] + sh[2] + sh[3];
}

// Row LN (width 3072) + L2 normalize, in place
__global__ __launch_bounds__(256)
void ln_l2_q(float* __restrict__ q, const float* __restrict__ g,
             const float* __restrict__ be)
{
  __shared__ float sh[4];
  const int row = blockIdx.x, t = threadIdx.x;
  float* qr = q + (size_t)row * Ez;
  float x[12];
#pragma unroll
  for (int i = 0; i < 12; ++i) x[i] = qr[t + (i << 8)];
  float s = 0.f;
#pragma unroll
  for (int i = 0; i < 12; ++i) s += x[i];
  const float m = blockSum256(s, sh) * (1.f / (float)Ez);
  float vs = 0.f;
#pragma unroll
  for (int i = 0; i < 12; ++i) { const float d = x[i] - m; vs += d * d; }
  const float v = blockSum256(vs, sh) * (1.f / (float)Ez);
  const float rs = rsqrtf(v + 1e-5f);
  float y[12]; float qs = 0.f;
#pragma unroll
  for (int i = 0; i < 12; ++i) {
    const int c = t + (i << 8);
    const float yy = (x[i] - m) * rs * g[c] + be[c];
    y[i] = yy; qs += yy * yy;
  }
  const float tot = blockSum256(qs, sh);
  const float s2 = rsqrtf(tot + 1e-12f);
#pragma unroll
  for (int i = 0; i < 12; ++i) qr[t + (i << 8)] = y[i] * s2;
}

// rk[n] = rsqrtf(sum(keys[n,:]^2) + 1e-12)
__global__ __launch_bounds__(256)
void keynorm(const float* __restrict__ keys, float* __restrict__ rk)
{
  __shared__ float sh[4];
  const int row = blockIdx.x, t = threadIdx.x;
  const float* xr = keys + (size_t)row * Ez;
  float qs = 0.f;
#pragma unroll
  for (int i = 0; i < 12; ++i) { const float x = xr[t + (i << 8)]; qs += x * x; }
  const float tot = blockSum256(qs, sh);
  if (t == 0) rk[row] = rsqrtf(tot + 1e-12f);
}

// q (fp32) -> bf16, elementwise (count multiple of 1024)
__global__ __launch_bounds__(256)
void cvt_q_bf16(const float* __restrict__ in, ushort_t* __restrict__ out)
{
  const size_t i = ((size_t)blockIdx.x * 256 + threadIdx.x) * 4;
  float4 v = *(const float4*)(in + i);
  ushort4 o;
  o.x = f2bf(v.x); o.y = f2bf(v.y); o.z = f2bf(v.z); o.w = f2bf(v.w);
  *(ushort4*)(out + i) = o;
}

// kn_bf[n,c] = bf16(keys[n,c] * rk[n])
__global__ __launch_bounds__(256)
void cvt_kn_bf16(const float* __restrict__ keys, const float* __restrict__ rk,
                 ushort_t* __restrict__ out)
{
  const int row = blockIdx.x, t = threadIdx.x;
  const float s = rk[row];
  const float* kr = keys + (size_t)row * Ez;
  ushort_t* orow = out + (size_t)row * Ez;
#pragma unroll
  for (int i = 0; i < 3; ++i) {
    const int c = (t + (i << 8)) << 2;
    float4 v = *(const float4*)&kr[c];
    ushort4 o;
    o.x = f2bf(v.x * s); o.y = f2bf(v.y * s);
    o.z = f2bf(v.z * s); o.w = f2bf(v.w * s);
    *(ushort4*)&orow[c] = o;
  }
}

// cc_w1 (3072 x 512 fp32) -> transposed bf16 (512 x 3072)
__global__ __launch_bounds__(256)
void cvt_w1t(const float* __restrict__ w, ushort_t* __restrict__ out)
{
  const int idx = blockIdx.x * 256 + threadIdx.x;   // 1,572,864 total
  const int k = idx >> 9, n = idx & 511;
  out[(size_t)n * Ez + k] = f2bf(w[idx]);
}

// =====================================================================
// Top-16 per row of the 8192 x 4096 fp16 score matrix (iterated argmax).
// Thread t holds cols {2t+b + j2*512}.
// =====================================================================
__global__ __launch_bounds__(256)
void topk16(const _Float16* __restrict__ S, int* __restrict__ outIdx)
{
  __shared__ float wv[4];
  __shared__ int wi[4];
  __shared__ int gi;
  const int row = blockIdx.x, t = threadIdx.x;
  const _Float16* sr = S + (size_t)row * NEz;
  float xv[16];
#pragma unroll
  for (int j2 = 0; j2 < 8; ++j2) {
    const int c = 2 * t + (j2 << 9);
    const _Float16* p = &sr[c];
    xv[2 * j2]     = (float)p[0];
    xv[2 * j2 + 1] = (float)p[1];
  }

  for (int it = 0; it < 16; ++it) {
    float bvv = xv[0]; int bj = 0;
#pragma unroll
    for (int j = 1; j < 16; ++j)
      if (xv[j] > bvv) { bvv = xv[j]; bj = j; }
    int bc = 2 * t + (bj & 1) + ((bj >> 1) << 9);
#pragma unroll
    for (int d = 32; d; d >>= 1) {
      const float ov = __shfl_down(bvv, d, 64);
      const int   oc = __shfl_down(bc, d, 64);
      if (ov > bvv || (ov == bvv && oc < bc)) { bvv = ov; bc = oc; }
    }
    if ((t & 63) == 0) { wv[t >> 6] = bvv; wi[t >> 6] = bc; }
    __syncthreads();
    if (t == 0) {
      float fv = wv[0]; int fc = wi[0];
#pragma unroll
      for (int w = 1; w < 4; ++w)
        if (wv[w] > fv || (wv[w] == fv && wi[w] < fc)) { fv = wv[w]; fc = wi[w]; }
      gi = fc;
      outIdx[(size_t)row * 16 + it] = fc;
    }
    __syncthreads();
    const int w = gi;
    if (((w & 511) >> 1) == t) {
      const int jc = ((w >> 9) << 1) | (w & 1);
#pragma unroll
      for (int j = 0; j < 16; ++j)
        if (j == jc) xv[j] = -3.402823466e38f;
    }
  }
}

// =====================================================================
// fp64 rescore of the 16 candidates on fp32 q & keys*rk; exact top-10 set.
// =====================================================================
__global__ __launch_bounds__(256)
void rescore(const float* __restrict__ qn, const float* __restrict__ keys,
             const float* __restrict__ rk, const int* __restrict__ cand,
             int* __restrict__ outIdx)
{
  __shared__ double sv[16];
  __shared__ int si[16];
  const int row = blockIdx.x, t = threadIdx.x;
  const int gr = t >> 4, l = t & 15;
  const int id = cand[(size_t)row * 16 + gr];
  const float* qr = qn + (size_t)row * Ez;
  const float* kr = keys + (size_t)id * Ez;
  double s = 0.0;
  for (int c = l; c < Ez; c += 16)
    s += (double)qr[c] * (double)kr[c];
#pragma unroll
  for (int d = 8; d; d >>= 1) s += __shfl_down(s, d, 16);
  if (l == 0) { sv[gr] = s * (double)rk[id]; si[gr] = id; }
  __syncthreads();
  if (t == 0) {
    for (int it = 0; it < 10; ++it) {
      int bj = 0; double bvv = sv[0]; int bi = si[0];
      for (int j = 1; j < 16; ++j) {
        const double v = sv[j]; const int i2 = si[j];
        if (v > bvv || (v == bvv && i2 < bi)) { bj = j; bvv = v; bi = i2; }
      }
      outIdx[(size_t)row * 10 + it] = bi;
      sv[bj] = -1e300;
    }
  }
}

// context mean of 10 raw key rows -> bf16 (fast path)
__global__ __launch_bounds__(256)
void gather_ctx_bf(const float* __restrict__ keys, const int* __restrict__ idx10,
                   ushort_t* __restrict__ ctxb)
{
  const int row = blockIdx.x, t = threadIdx.x;
  int id[10];
#pragma unroll
  for (int j = 0; j < 10; ++j) id[j] = idx10[(size_t)row * 10 + j];
#pragma unroll
  for (int i = 0; i < 6; ++i) {
    const int c = 2 * t + (i << 9);
    float s0 = 0.f, s1 = 0.f;
#pragma unroll
    for (int j = 0; j < 10; ++j) {
      float2 v = *(const float2*)&keys[(size_t)id[j] * Ez + c];
      s0 += v.x; s1 += v.y;
    }
    ushort2 o; o.x = f2bf(s0 * 0.1f); o.y = f2bf(s1 * 0.1f);
    *(ushort2*)&ctxb[(size_t)row * Ez + c] = o;
  }
}

// context mean -> fp32 (fallback path)
__global__ __launch_bounds__(256)
void gather_ctx(const float* __restrict__ keys, const int* __restrict__ idx10,
                float* __restrict__ ctx)
{
  const int row = blockIdx.x, t = threadIdx.x;
  int id[10];
#pragma unroll
  for (int j = 0; j < 10; ++j) id[j] = idx10[(size_t)row * 10 + j];
#pragma unroll
  for (int i = 0; i < 12; ++i) {
    const int c = t + (i << 8);
    float s = 0.f;
#pragma unroll
    for (int j = 0; j < 10; ++j) s += keys[(size_t)id[j] * Ez + c];
    ctx[(size_t)row * Ez + c] = s * 0.1f;
  }
}

// =====================================================================
// Router: 115 -> 64 -> 64 -> 4, clip, + gumbel, softmax, straight-through
// =====================================================================
__global__ __launch_bounds__(256)
void router_kernel(const float* __restrict__ state, const float* __restrict__ gn,
                   const float* __restrict__ w1, const float* __restrict__ b1,
                   const float* __restrict__ w2, const float* __restrict__ b2,
                   const float* __restrict__ w3, const float* __restrict__ b3,
                   float* __restrict__ outAlpha)
{
  const int row = blockIdx.x * 256 + threadIdx.x;
  const float* sr = state + (size_t)row * Sz;
  float h1[64];
#pragma unroll
  for (int j = 0; j < 64; ++j) h1[j] = b1[j];
  for (int k = 0; k < Sz; ++k) {
    const float a = sr[k];
    const float* wr = w1 + (size_t)k * 64;
#pragma unroll
    for (int j = 0; j < 64; ++j) h1[j] = fmaf(a, wr[j], h1[j]);
  }
#pragma unroll
  for (int j = 0; j < 64; ++j) h1[j] = fmaxf(h1[j], 0.f);
  float h2[64];
#pragma unroll
  for (int j = 0; j < 64; ++j) h2[j] = b2[j];
#pragma unroll
  for (int k = 0; k < 64; ++k) {
    const float a = h1[k];
    const float* wr = w2 + (size_t)k * 64;
#pragma unroll
    for (int j = 0; j < 64; ++j) h2[j] = fmaf(a, wr[j], h2[j]);
  }
#pragma unroll
  for (int j = 0; j < 64; ++j) h2[j] = fmaxf(h2[j], 0.f);
  float z[4];
#pragma unroll
  for (int a = 0; a < 4; ++a) {
    float s = b3[a];
#pragma unroll
    for (int k = 0; k < 64; ++k) s = fmaf(h2[k], w3[k * 4 + a], s);
    s = fminf(fmaxf(s, -20.f), 20.f);
    z[a] = s + gn[(size_t)row * 4 + a];   // TAU = 1
  }
  float mz = z[0];
#pragma unroll
  for (int a = 1; a < 4; ++a) mz = fmaxf(mz, z[a]);
  float e[4]; float se = 0.f;
#pragma unroll
  for (int a = 0; a < 4; ++a) { e[a] = expf(z[a] - mz); se += e[a]; }
  const float inv = 1.f / se;
  float y[4];
#pragma unroll
  for (int a = 0; a < 4; ++a) y[a] = e[a] * inv;
  int am = 0;
#pragma unroll
  for (int a = 1; a < 4; ++a) if (y[a] > y[am]) am = a;
#pragma unroll
  for (int a = 0; a < 4; ++a) {
    const float hard = (a == am) ? 1.f : 0.f;
    outAlpha[(size_t)row * 4 + a] = y[a] + (hard - y[a]);
  }
}

// critic head
__global__ __launch_bounds__(256)
void critic_head(const float* __restrict__ c2, const float* __restrict__ w3,
                 const float* __restrict__ b3, float* __restrict__ outv)
{
  const int row = blockIdx.x * 256 + threadIdx.x;
  const float* xr = c2 + (size_t)row * 256;
  float s = b3[0];
  for (int k = 0; k < 256; ++k) s = fmaf(xr[k], w3[k], s);
  outv[row] = s;
}

// all-4 actor heads fused: logits[row] = sum_a alpha[row,a]*(x2[a]@W3a + b3a)
struct HeadP { const float* w3[4]; const float* b3[4]; };

__global__ __launch_bounds__(256)
void actor_head4(const float* __restrict__ x2g, HeadP p,
                 const float* __restrict__ alpha, float* __restrict__ outL)
{
  __shared__ float wsm[4][128 * 23];
  __shared__ float bs[4][23];
  const int t = threadIdx.x;
#pragma unroll
  for (int a = 0; a < 4; ++a) {
    for (int i = t; i < 128 * 23; i += 256) wsm[a][i] = p.w3[a][i];
    if (t < 23) bs[a][t] = p.b3[a][t];
  }
  __syncthreads();
  const int row = blockIdx.x * 64 + (t >> 2);
  const int cg = t & 3;
  float sum[6] = {0.f, 0.f, 0.f, 0.f, 0.f, 0.f};
#pragma unroll
  for (int a = 0; a < 4; ++a) {
    const float al = alpha[(size_t)row * 4 + a];
    const float* xr = x2g + (size_t)a * Bz * 128 + (size_t)row * 128;
    float acc[6] = {0.f, 0.f, 0.f, 0.f, 0.f, 0.f};
    for (int kk = 0; kk < 128; ++kk) {
      const float xa = xr[kk];
#pragma unroll
      for (int j = 0; j < 6; ++j) {
        const int col = cg + 4 * j;
        if (col < 23) acc[j] = fmaf(xa, wsm[a][kk * 23 + col], acc[j]);
      }
    }
#pragma unroll
    for (int j = 0; j < 6; ++j) {
      const int col = cg + 4 * j;
      if (col < 23) sum[j] += al * (acc[j] + bs[a][col]);
    }
  }
#pragma unroll
  for (int j = 0; j < 6; ++j) {
    const int col = cg + 4 * j;
    if (col < 23) outL[(size_t)row * 23 + col] = sum[j];
  }
}

// =====================================================================
extern "C" void kernel_launch(void* const* d_in, const int* in_sizes, int n_in,
                              void* d_out, int out_size, void* d_ws, size_t ws_size,
                              hipStream_t stream)
{
  const float* state  = (const float*)d_in[0];
  const float* gumbel = (const float*)d_in[1];
  const float* keys   = (const float*)d_in[2];
  const float* se_w1 = (const float*)d_in[3];
  const float* se_b1 = (const float*)d_in[4];
  const float* se_w2 = (const float*)d_in[5];
  const float* se_b2 = (const float*)d_in[6];
  const float* se_w3 = (const float*)d_in[7];
  const float* se_b3 = (const float*)d_in[8];
  const float* se_g  = (const float*)d_in[9];
  const float* se_be = (const float*)d_in[10];
  const float* cc_w1 = (const float*)d_in[11];
  const float* cc_b1 = (const float*)d_in[12];
  const float* cc_w2 = (const float*)d_in[13];
  const float* cc_b2 = (const float*)d_in[14];
  const float* cc_g  = (const float*)d_in[15];
  const float* cc_be = (const float*)d_in[16];
  const float* r_w1 = (const float*)d_in[57];
  const float* r_b1 = (const float*)d_in[58];
  const float* r_w2 = (const float*)d_in[59];
  const float* r_b2 = (const float*)d_in[60];
  const float* r_w3 = (const float*)d_in[61];
  const float* r_b3 = (const float*)d_in[62];
  const float* c_w1 = (const float*)d_in[63];
  const float* c_b1 = (const float*)d_in[64];
  const float* c_w2 = (const float*)d_in[65];
  const float* c_b2 = (const float*)d_in[66];
  const float* c_w3 = (const float*)d_in[67];
  const float* c_b3 = (const float*)d_in[68];

  // ---- workspace layout ----
  float* wsf = (float*)d_ws;
  const size_t qF = (size_t)Bz * Ez;          // 25,165,824 floats
  const size_t uF = (size_t)16777216;         // union region, floats
  float* q = wsf;
  float* U = wsf + qF;
  // U internal (time-multiplexed):
  float* sA  = U;                              // encoder ping
  float* sB  = U + 4194304;                    // encoder pong
  _Float16* scoresH = (_Float16*)U;            // 8192x4096 halves (64 MB)
  float* shr = U;                              // 8192x128
  float* x1g = U + 1 * 1048576;                // 4 x 8192x128
  float* x2g = U + 5 * 1048576;                // 4 x 8192x128
  float* cch = U + 9 * 1048576;                // 8192x512 (dies before cr1)
  float* cr1 = U + 9 * 1048576;                // 8192x256
  float* cr2 = U + 11 * 1048576;               // 8192x256
  // fast-path bf16 buffers after U:
  ushort_t* qbf  = (ushort_t*)(wsf + qF + uF);     // 8192x3072
  ushort_t* knbf = qbf + qF;                       // 4096x3072
  ushort_t* w1T  = knbf + (size_t)NEz * Ez;        // 512x3072
  const size_t bfHalves = qF + (size_t)NEz * Ez + (size_t)512 * Ez;
  const size_t baseBytes = (qF + uF) * sizeof(float);
  const size_t tailBytes = 4096 * 4 + (size_t)Bz * 16 * 4 + (size_t)Bz * 10 * 4;
  const bool fast = ws_size >= baseBytes + bfHalves * 2 + tailBytes;
  float* tailF = (float*)((char*)d_ws + (fast ? baseBytes + bfHalves * 2 : baseBytes));
  float* rk  = tailF;
  int* cand  = (int*)(tailF + 4096);
  int* sel   = cand + (size_t)Bz * 16;
  ushort_t* ctxb = (ushort_t*)q;               // bf16 ctx overlays dead q

  float* outL = (float*)d_out;                 // 8192*23
  float* outA = outL + (size_t)Bz * 23;        // 8192*4
  float* outV = outA + (size_t)Bz * 4;         // 8192*1

  const dim3 blk(256);

  // --- state encoder (fp32 — ranking-critical) ---
  gemm128<true,  true><<<dim3(4, 64),  blk, 0, stream>>>(state, se_w1, se_b1, sA, 512, 115);
  gemm128<true,  true><<<dim3(4, 64),  blk, 0, stream>>>(sA,    se_w2, se_b2, sB, 512, 512);
  gemm128<false, true><<<dim3(24, 64), blk, 0, stream>>>(sB,    se_w3, se_b3, q, 3072, 512);
  ln_l2_q<<<dim3(Bz), blk, 0, stream>>>(q, se_g, se_be);
  keynorm<<<dim3(NEz), blk, 0, stream>>>(keys, rk);

  // --- retrieval screen ---
  if (fast) {
    cvt_q_bf16<<<dim3(24576), blk, 0, stream>>>(q, qbf);
    cvt_kn_bf16<<<dim3(NEz), blk, 0, stream>>>(keys, rk, knbf);
    cvt_w1t<<<dim3(6144), blk, 0, stream>>>(cc_w1, w1T);
    mfma_bt<0><<<dim3(32, 64), blk, 0, stream>>>(qbf, knbf, nullptr, scoresH, NEz, Ez);
  } else {
    gemm_scores<<<dim3(32, 64), blk, 0, stream>>>(q, keys, rk, scoresH);
  }
  topk16<<<dim3(Bz), blk, 0, stream>>>(scoresH, cand);
  rescore<<<dim3(Bz), blk, 0, stream>>>(q, keys, rk, cand, sel);

  // --- context + compressor ---
  if (fast) {
    gather_ctx_bf<<<dim3(Bz), blk, 0, stream>>>(keys, sel, ctxb);
    mfma_bt<1><<<dim3(4, 64), blk, 0, stream>>>(ctxb, w1T, cc_b1, cch, 512, Ez);
  } else {
    gather_ctx<<<dim3(Bz), blk, 0, stream>>>(keys, sel, q);
    gemm128<true, true><<<dim3(4, 64), blk, 0, stream>>>(q, cc_w1, cc_b1, cch, 512, Ez);
  }
  {
    LN4 pcc = {};
    pcc.W[0] = cc_w2; pcc.b[0] = cc_b2; pcc.g[0] = cc_g; pcc.be[0] = cc_be;
    gemm_ln4<false, false><<<dim3(128, 1), blk, 0, stream>>>(cch, 0, 512, nullptr, pcc,
                                                             shr, 0);
  }

  // --- critic ---
  gemm128<true, true><<<dim3(2, 64), blk, 0, stream>>>(state, c_w1, c_b1, cr1, 256, 115);
  gemm128<true, true><<<dim3(2, 64), blk, 0, stream>>>(cr1, c_w2, c_b2, cr2, 256, 256);
  critic_head<<<dim3(32), blk, 0, stream>>>(cr2, c_w3, c_b3, outV);

  // --- router ---
  router_kernel<<<dim3(32), blk, 0, stream>>>(state, gumbel, r_w1, r_b1, r_w2, r_b2,
                                              r_w3, r_b3, outA);

  // --- actors (batched over blockIdx.y) ---
  {
    LN4 p1 = {}, p2 = {};
    HeadP ph = {};
    const int eoffs[4] = {0, 20, 40, 45};
    const int elens[4] = {50, 20, 10, 15};
    for (int a = 0; a < 4; ++a) {
      const int base = 17 + 10 * a;
      p1.W[a]  = (const float*)d_in[base + 0];
      p1.b[a]  = (const float*)d_in[base + 1];
      p1.g[a]  = (const float*)d_in[base + 2];
      p1.be[a] = (const float*)d_in[base + 3];
      p1.eoff[a] = eoffs[a]; p1.elen[a] = elens[a];
      p2.W[a]  = (const float*)d_in[base + 4];
      p2.b[a]  = (const float*)d_in[base + 5];
      p2.g[a]  = (const float*)d_in[base + 6];
      p2.be[a] = (const float*)d_in[base + 7];
      ph.w3[a] = (const float*)d_in[base + 8];
      ph.b3[a] = (const float*)d_in[base + 9];
    }
    gemm_ln4<true, true ><<<dim3(128, 4), blk, 0, stream>>>(shr, 0, 128, state, p1,
                                                            x1g, (size_t)Bz * 128);
    gemm_ln4<true, false><<<dim3(128, 4), blk, 0, stream>>>(x1g, (size_t)Bz * 128, 128,
                                                            nullptr, p2,
                                                            x2g, (size_t)Bz * 128);
    actor_head4<<<dim3(128), blk, 0, stream>>>(x2g, ph, outA, outL);
  }
}

// Round 4
// 1630.398 us; speedup vs baseline: 2.7120x; 1.1611x over previous
//
#include <hip/hip_runtime.h>

// Problem constants (match reference)
constexpr int Bz = 8192;   // batch
constexpr int Sz = 115;    // state dim
constexpr int Ez = 3072;   // embedding dim
constexpr int NEz = 4096;  // num keys
// C=128, A=23, K=10, TAU=1, EPS=1e-5

typedef __attribute__((ext_vector_type(8))) short short8;
typedef __attribute__((ext_vector_type(4))) float floatx4;
typedef unsigned short ushort_t;
typedef unsigned int uint_t;

__device__ __forceinline__ ushort_t f2bf(float f) {
  uint_t u = __float_as_uint(f);
  uint_t r = (u + 0x7FFFu + ((u >> 16) & 1u)) >> 16;   // RNE
  return (ushort_t)r;
}
__device__ __forceinline__ float bf2f(ushort_t b) {
  uint_t u = ((uint_t)b) << 16;
  return __uint_as_float(u);
}
// fp32 -> fp16 -> order-preserving u16 key (monotone total order)
__device__ __forceinline__ ushort_t f2key(float v) {
  _Float16 h = (_Float16)v;
  ushort_t b = __builtin_bit_cast(ushort_t, h);
  return b ^ ((b & 0x8000u) ? 0xFFFFu : 0x8000u);
}
__device__ __forceinline__ uint_t umax_(uint_t a, uint_t b) { return a > b ? a : b; }

// async global->LDS, 16 B per lane; lds dest = wave-uniform base + lane*16
__device__ __forceinline__ void gload16(const ushort_t* g, ushort_t* l) {
  __builtin_amdgcn_global_load_lds(
      (__attribute__((address_space(1))) const void*)g,
      (__attribute__((address_space(3))) void*)l, 16, 0, 0);
}

// =====================================================================
// Generic fp32 tiled GEMM: C[M x N] = act(A[M x K] @ B + bias)
// B is K x N row-major. Tile 128x128x16, 256 threads, 8x8/thread.
// =====================================================================
template<bool RELU, bool BIAS>
__global__ __launch_bounds__(256)
void gemm128(const float* __restrict__ A, const float* __restrict__ Bm,
             const float* __restrict__ bias, float* __restrict__ C,
             int N, int Kd)
{
  __shared__ float As[16][132];
  __shared__ float Bs[16][132];
  const int t  = threadIdx.x;
  const int tx = t & 15, ty = t >> 4;
  const int row0 = blockIdx.y * 128;
  const int col0 = blockIdx.x * 128;
  const int ar = t >> 2, ac = (t & 3) * 4;
  const int bk = t >> 5, bc = (t & 31) * 4;
  const bool a4 = (Kd & 3) == 0;

  float acc[8][8];
#pragma unroll
  for (int i = 0; i < 8; ++i)
#pragma unroll
    for (int j = 0; j < 8; ++j) acc[i][j] = 0.f;

  for (int k0 = 0; k0 < Kd; k0 += 16) {
    const bool fullA = (k0 + 16 <= Kd) && a4;
    {
      const float* ap = A + (size_t)(row0 + ar) * Kd + k0 + ac;
      if (fullA) {
        float4 v0 = *(const float4*)ap;
        float4 v1 = *(const float4*)(ap + (size_t)64 * Kd);
        As[ac + 0][ar] = v0.x; As[ac + 1][ar] = v0.y;
        As[ac + 2][ar] = v0.z; As[ac + 3][ar] = v0.w;
        As[ac + 0][ar + 64] = v1.x; As[ac + 1][ar + 64] = v1.y;
        As[ac + 2][ar + 64] = v1.z; As[ac + 3][ar + 64] = v1.w;
      } else {
#pragma unroll
        for (int e = 0; e < 4; ++e) {
          const int k = k0 + ac + e;
          float v0 = 0.f, v1 = 0.f;
          if (k < Kd) { v0 = ap[e]; v1 = ap[e + (size_t)64 * Kd]; }
          As[ac + e][ar] = v0; As[ac + e][ar + 64] = v1;
        }
      }
    }
    {
      const float* bp = Bm + (size_t)(k0 + bk) * N + col0 + bc;
      if (k0 + 16 <= Kd) {
        *(float4*)&Bs[bk][bc]     = *(const float4*)bp;
        *(float4*)&Bs[bk + 8][bc] = *(const float4*)(bp + (size_t)8 * N);
      } else {
        float4 z; z.x = z.y = z.z = z.w = 0.f;
        *(float4*)&Bs[bk][bc]     = (k0 + bk     < Kd) ? *(const float4*)bp : z;
        *(float4*)&Bs[bk + 8][bc] = (k0 + bk + 8 < Kd) ? *(const float4*)(bp + (size_t)8 * N) : z;
      }
    }
    __syncthreads();
#pragma unroll
    for (int kk = 0; kk < 16; ++kk) {
      float a[8], b[8];
      *(float4*)&a[0] = *(const float4*)&As[kk][ty * 4];
      *(float4*)&a[4] = *(const float4*)&As[kk][64 + ty * 4];
      *(float4*)&b[0] = *(const float4*)&Bs[kk][tx * 4];
      *(float4*)&b[4] = *(const float4*)&Bs[kk][64 + tx * 4];
#pragma unroll
      for (int i = 0; i < 8; ++i)
#pragma unroll
        for (int j = 0; j < 8; ++j)
          acc[i][j] = fmaf(a[i], b[j], acc[i][j]);
    }
    __syncthreads();
  }

  float bv[8];
#pragma unroll
  for (int j = 0; j < 8; ++j) bv[j] = 0.f;
  if (BIAS) {
    *(float4*)&bv[0] = *(const float4*)&bias[col0 + tx * 4];
    *(float4*)&bv[4] = *(const float4*)&bias[col0 + 64 + tx * 4];
  }
#pragma unroll
  for (int i = 0; i < 8; ++i) {
    const int r = row0 + ((i < 4) ? (ty * 4 + i) : (64 + ty * 4 + i - 4));
    float o[8];
#pragma unroll
    for (int j = 0; j < 8; ++j) {
      o[j] = acc[i][j] + bv[j];
      if (RELU) o[j] = fmaxf(o[j], 0.f);
    }
    *(float4*)&C[(size_t)r * N + col0 + tx * 4]      = *(float4*)&o[0];
    *(float4*)&C[(size_t)r * N + col0 + 64 + tx * 4] = *(float4*)&o[4];
  }
}

// =====================================================================
// bf16 MFMA GEMM, A(M x K) @ B(N x K)^T, both row-major bf16 (K-contig).
// Tile 128x128xBK32, 256 thr = 4 waves (2x2 of 64x64), 4x4 MFMA acc/wave.
// EPI=0: store order-preserving u16 score keys. EPI=1: fp32 + bias + ReLU.
// =====================================================================
template<int EPI>
__global__ __launch_bounds__(256)
void mfma_bt(const ushort_t* __restrict__ A, const ushort_t* __restrict__ B,
             const float* __restrict__ bias, void* __restrict__ Cout,
             int N, int Kd)
{
  __shared__ ushort_t Al[128 * 32];
  __shared__ ushort_t Bl[128 * 32];
  const int t = threadIdx.x;
  const int wid = t >> 6, lane = t & 63;
  const int wr = wid >> 1, wc = wid & 1;
  const int row0 = blockIdx.y * 128;
  const int col0 = blockIdx.x * 128;
  const int srow = lane >> 2;
  const int scol = (lane & 3) * 8;

  const ushort_t* ga0 = A + (size_t)(row0 + wid * 16 + srow) * Kd + scol;
  const ushort_t* ga1 = A + (size_t)(row0 + (wid + 4) * 16 + srow) * Kd + scol;
  const ushort_t* gb0 = B + (size_t)(col0 + wid * 16 + srow) * Kd + scol;
  const ushort_t* gb1 = B + (size_t)(col0 + (wid + 4) * 16 + srow) * Kd + scol;
  ushort_t* la0 = &Al[(wid * 16) * 32];
  ushort_t* la1 = &Al[((wid + 4) * 16) * 32];
  ushort_t* lb0 = &Bl[(wid * 16) * 32];
  ushort_t* lb1 = &Bl[((wid + 4) * 16) * 32];

  const int mr = lane & 15, qd = lane >> 4;

  floatx4 acc[4][4];
#pragma unroll
  for (int i = 0; i < 4; ++i)
#pragma unroll
    for (int j = 0; j < 4; ++j) acc[i][j] = (floatx4){0.f, 0.f, 0.f, 0.f};

  for (int kb = 0; kb < Kd; kb += 32) {
    gload16(ga0 + kb, la0);
    gload16(ga1 + kb, la1);
    gload16(gb0 + kb, lb0);
    gload16(gb1 + kb, lb1);
    __syncthreads();
    short8 aF[4], bF[4];
#pragma unroll
    for (int i = 0; i < 4; ++i)
      aF[i] = *(const short8*)&Al[(wr * 64 + i * 16 + mr) * 32 + qd * 8];
#pragma unroll
    for (int j = 0; j < 4; ++j)
      bF[j] = *(const short8*)&Bl[(wc * 64 + j * 16 + mr) * 32 + qd * 8];
#pragma unroll
    for (int i = 0; i < 4; ++i)
#pragma unroll
      for (int j = 0; j < 4; ++j)
        acc[i][j] = __builtin_amdgcn_mfma_f32_16x16x32_bf16(aF[i], bF[j], acc[i][j], 0, 0, 0);
    __syncthreads();
  }

  // C/D layout: col = lane&15, row = (lane>>4)*4 + reg
#pragma unroll
  for (int i = 0; i < 4; ++i) {
#pragma unroll
    for (int j = 0; j < 4; ++j) {
      const int col = col0 + wc * 64 + j * 16 + mr;
#pragma unroll
      for (int r = 0; r < 4; ++r) {
        const int row = row0 + wr * 64 + i * 16 + qd * 4 + r;
        if (EPI == 0) {
          ((ushort_t*)Cout)[(size_t)row * N + col] = f2key(acc[i][j][r]);
        } else {
          float v = acc[i][j][r] + bias[col];
          ((float*)Cout)[(size_t)row * N + col] = fmaxf(v, 0.f);
        }
      }
    }
  }
}

// =====================================================================
// bf16x3 split-precision MFMA GEMM (fp32-accurate): C = A@B^T + bias
// A = Ah+Al (M x K), B = Bh+Bl (N x K), all bf16 K-contig row-major.
// acc += Al*Bh + Ah*Bl + Ah*Bh  (per K-chunk; al*bl term ~2^-18, dropped)
// =====================================================================
__global__ __launch_bounds__(256)
void mfma3_bt(const ushort_t* __restrict__ Ah, const ushort_t* __restrict__ Alo,
              const ushort_t* __restrict__ Bh, const ushort_t* __restrict__ Blo,
              const float* __restrict__ bias, float* __restrict__ Cout,
              int N, int Kd)
{
  __shared__ ushort_t AhL[128 * 32];
  __shared__ ushort_t AlL[128 * 32];
  __shared__ ushort_t BhL[128 * 32];
  __shared__ ushort_t BlL[128 * 32];
  const int t = threadIdx.x;
  const int wid = t >> 6, lane = t & 63;
  const int wr = wid >> 1, wc = wid & 1;
  const int row0 = blockIdx.y * 128;
  const int col0 = blockIdx.x * 128;
  const int srow = lane >> 2;
  const int scol = (lane & 3) * 8;

  const size_t aoff0 = (size_t)(row0 + wid * 16 + srow) * Kd + scol;
  const size_t aoff1 = (size_t)(row0 + (wid + 4) * 16 + srow) * Kd + scol;
  const size_t boff0 = (size_t)(col0 + wid * 16 + srow) * Kd + scol;
  const size_t boff1 = (size_t)(col0 + (wid + 4) * 16 + srow) * Kd + scol;
  const int l0 = (wid * 16) * 32;
  const int l1 = ((wid + 4) * 16) * 32;

  const int mr = lane & 15, qd = lane >> 4;

  floatx4 acc[4][4];
#pragma unroll
  for (int i = 0; i < 4; ++i)
#pragma unroll
    for (int j = 0; j < 4; ++j) acc[i][j] = (floatx4){0.f, 0.f, 0.f, 0.f};

  for (int kb = 0; kb < Kd; kb += 32) {
    gload16(Ah + aoff0 + kb, &AhL[l0]);
    gload16(Ah + aoff1 + kb, &AhL[l1]);
    gload16(Alo + aoff0 + kb, &AlL[l0]);
    gload16(Alo + aoff1 + kb, &AlL[l1]);
    gload16(Bh + boff0 + kb, &BhL[l0]);
    gload16(Bh + boff1 + kb, &BhL[l1]);
    gload16(Blo + boff0 + kb, &BlL[l0]);
    gload16(Blo + boff1 + kb, &BlL[l1]);
    __syncthreads();
    short8 ahF[4], alF[4], bhF[4], blF[4];
#pragma unroll
    for (int i = 0; i < 4; ++i) {
      const int o = (wr * 64 + i * 16 + mr) * 32 + qd * 8;
      ahF[i] = *(const short8*)&AhL[o];
      alF[i] = *(const short8*)&AlL[o];
    }
#pragma unroll
    for (int j = 0; j < 4; ++j) {
      const int o = (wc * 64 + j * 16 + mr) * 32 + qd * 8;
      bhF[j] = *(const short8*)&BhL[o];
      blF[j] = *(const short8*)&BlL[o];
    }
#pragma unroll
    for (int i = 0; i < 4; ++i)
#pragma unroll
      for (int j = 0; j < 4; ++j) {
        acc[i][j] = __builtin_amdgcn_mfma_f32_16x16x32_bf16(alF[i], bhF[j], acc[i][j], 0, 0, 0);
        acc[i][j] = __builtin_amdgcn_mfma_f32_16x16x32_bf16(ahF[i], blF[j], acc[i][j], 0, 0, 0);
        acc[i][j] = __builtin_amdgcn_mfma_f32_16x16x32_bf16(ahF[i], bhF[j], acc[i][j], 0, 0, 0);
      }
    __syncthreads();
  }

#pragma unroll
  for (int i = 0; i < 4; ++i) {
#pragma unroll
    for (int j = 0; j < 4; ++j) {
      const int col = col0 + wc * 64 + j * 16 + mr;
#pragma unroll
      for (int r = 0; r < 4; ++r) {
        const int row = row0 + wr * 64 + i * 16 + qd * 4 + r;
        Cout[(size_t)row * N + col] = acc[i][j][r] + bias[col];
      }
    }
  }
}

// =====================================================================
// fp32 scores GEMM (fallback path only) -> u16 score keys
// =====================================================================
__global__ __launch_bounds__(256)
void gemm_scores(const float* __restrict__ A, const float* __restrict__ Bm,
                 const float* __restrict__ rk, ushort_t* __restrict__ S)
{
  __shared__ float As[16][132];
  __shared__ float Bs[16][132];
  const int t  = threadIdx.x;
  const int tx = t & 15, ty = t >> 4;
  const int row0 = blockIdx.y * 128;
  const int col0 = blockIdx.x * 128;
  const int ar = t >> 2, ac = (t & 3) * 4;
  const int Kd = Ez;

  float acc[8][8];
#pragma unroll
  for (int i = 0; i < 8; ++i)
#pragma unroll
    for (int j = 0; j < 8; ++j) acc[i][j] = 0.f;

  for (int k0 = 0; k0 < Kd; k0 += 16) {
    {
      const float* ap = A + (size_t)(row0 + ar) * Kd + k0 + ac;
      float4 v0 = *(const float4*)ap;
      float4 v1 = *(const float4*)(ap + (size_t)64 * Kd);
      As[ac + 0][ar] = v0.x; As[ac + 1][ar] = v0.y;
      As[ac + 2][ar] = v0.z; As[ac + 3][ar] = v0.w;
      As[ac + 0][ar + 64] = v1.x; As[ac + 1][ar + 64] = v1.y;
      As[ac + 2][ar + 64] = v1.z; As[ac + 3][ar + 64] = v1.w;
    }
    {
      const float* bp = Bm + (size_t)(col0 + ar) * Kd + k0 + ac;
      float4 v0 = *(const float4*)bp;
      float4 v1 = *(const float4*)(bp + (size_t)64 * Kd);
      Bs[ac + 0][ar] = v0.x; Bs[ac + 1][ar] = v0.y;
      Bs[ac + 2][ar] = v0.z; Bs[ac + 3][ar] = v0.w;
      Bs[ac + 0][ar + 64] = v1.x; Bs[ac + 1][ar + 64] = v1.y;
      Bs[ac + 2][ar + 64] = v1.z; Bs[ac + 3][ar + 64] = v1.w;
    }
    __syncthreads();
#pragma unroll
    for (int kk = 0; kk < 16; ++kk) {
      float a[8], b[8];
      *(float4*)&a[0] = *(const float4*)&As[kk][ty * 4];
      *(float4*)&a[4] = *(const float4*)&As[kk][64 + ty * 4];
      *(float4*)&b[0] = *(const float4*)&Bs[kk][tx * 4];
      *(float4*)&b[4] = *(const float4*)&Bs[kk][64 + tx * 4];
#pragma unroll
      for (int i = 0; i < 8; ++i)
#pragma unroll
        for (int j = 0; j < 8; ++j)
          acc[i][j] = fmaf(a[i], b[j], acc[i][j]);
    }
    __syncthreads();
  }

  float rk0[8];
  *(float4*)&rk0[0] = *(const float4*)&rk[col0 + tx * 4];
  *(float4*)&rk0[4] = *(const float4*)&rk[col0 + 64 + tx * 4];
#pragma unroll
  for (int i = 0; i < 8; ++i) {
    const int r = row0 + ((i < 4) ? (ty * 4 + i) : (64 + ty * 4 + i - 4));
    ushort4 h0, h1;
    h0.x = f2key(acc[i][0] * rk0[0]); h0.y = f2key(acc[i][1] * rk0[1]);
    h0.z = f2key(acc[i][2] * rk0[2]); h0.w = f2key(acc[i][3] * rk0[3]);
    h1.x = f2key(acc[i][4] * rk0[4]); h1.y = f2key(acc[i][5] * rk0[5]);
    h1.z = f2key(acc[i][6] * rk0[6]); h1.w = f2key(acc[i][7] * rk0[7]);
    *(ushort4*)&S[(size_t)r * NEz + col0 + tx * 4]      = h0;
    *(ushort4*)&S[(size_t)r * NEz + col0 + 64 + tx * 4] = h1;
  }
}

// =====================================================================
// Batched (4-actor) fused GEMM(N=128) + LayerNorm (+ReLU).
// =====================================================================
struct LN4 {
  const float* W[4]; const float* b[4]; const float* g[4]; const float* be[4];
  int eoff[4]; int elen[4];
};

template<bool RELU, bool HASEXT>
__global__ __launch_bounds__(256)
void gemm_ln4(const float* __restrict__ A1base, size_t a1stride, int K1,
              const float* __restrict__ A2, LN4 p,
              float* __restrict__ outbase, size_t ostride)
{
  __shared__ float As[32][68];
  __shared__ float Bs[32][132];
  __shared__ float rsum[64][17];
  __shared__ float rsq[64][17];
  __shared__ float stm[64], str[64];
  const int a = blockIdx.y;
  const float* A1 = A1base + (size_t)a * a1stride;
  float* out = outbase + (size_t)a * ostride;
  const float* W = p.W[a];
  const float* bias = p.b[a];
  const float* g = p.g[a];
  const float* be = p.be[a];
  const int eoff = HASEXT ? p.eoff[a] : 0;
  const int K2 = HASEXT ? p.elen[a] : 0;

  const int t = threadIdx.x;
  const int tx = t & 15, ty = t >> 4;
  const int row0 = blockIdx.x * 64;
  const int Kt = K1 + K2;
  const int ar = t >> 2, ac = (t & 3) * 8;
  const int bk = t >> 3, bc = (t & 7) * 16;

  float acc[4][8];
#pragma unroll
  for (int i = 0; i < 4; ++i)
#pragma unroll
    for (int j = 0; j < 8; ++j) acc[i][j] = 0.f;

  for (int k0 = 0; k0 < Kt; k0 += 32) {
    const int grow = row0 + ar;
#pragma unroll
    for (int e = 0; e < 8; ++e) {
      const int k = k0 + ac + e;
      float v = 0.f;
      if (k < K1)      v = A1[(size_t)grow * K1 + k];
      else if (k < Kt) v = A2[(size_t)grow * 115 + eoff + (k - K1)];
      As[ac + e][ar] = v;
    }
    {
      const int k = k0 + bk;
#pragma unroll
      for (int qd = 0; qd < 4; ++qd) {
        float4 z; z.x = z.y = z.z = z.w = 0.f;
        *(float4*)&Bs[bk][bc + 4 * qd] =
            (k < Kt) ? *(const float4*)&W[(size_t)k * 128 + bc + 4 * qd] : z;
      }
    }
    __syncthreads();
#pragma unroll
    for (int kk = 0; kk < 32; ++kk) {
      float av[4], bv2[8];
      *(float4*)&av[0]  = *(const float4*)&As[kk][ty * 4];
      *(float4*)&bv2[0] = *(const float4*)&Bs[kk][tx * 4];
      *(float4*)&bv2[4] = *(const float4*)&Bs[kk][64 + tx * 4];
#pragma unroll
      for (int i = 0; i < 4; ++i)
#pragma unroll
        for (int j = 0; j < 8; ++j)
          acc[i][j] = fmaf(av[i], bv2[j], acc[i][j]);
    }
    __syncthreads();
  }

  float bv[8];
  *(float4*)&bv[0] = *(const float4*)&bias[tx * 4];
  *(float4*)&bv[4] = *(const float4*)&bias[64 + tx * 4];
#pragma unroll
  for (int i = 0; i < 4; ++i) {
    float s = 0.f, q = 0.f;
#pragma unroll
    for (int j = 0; j < 8; ++j) {
      acc[i][j] += bv[j];
      s += acc[i][j];
      q += acc[i][j] * acc[i][j];
    }
    rsum[ty * 4 + i][tx] = s;
    rsq[ty * 4 + i][tx]  = q;
  }
  __syncthreads();
  if (t < 64) {
    float s = 0.f, q = 0.f;
#pragma unroll
    for (int x = 0; x < 16; ++x) { s += rsum[t][x]; q += rsq[t][x]; }
    const float m = s * (1.f / 128.f);
    const float v = q * (1.f / 128.f) - m * m;
    stm[t] = m;
    str[t] = rsqrtf(v + 1e-5f);
  }
  __syncthreads();
#pragma unroll
  for (int i = 0; i < 4; ++i) {
    const int r = ty * 4 + i;
    const float m = stm[r], rs = str[r];
    float o[8];
#pragma unroll
    for (int j = 0; j < 8; ++j) {
      const int col = (j < 4) ? (tx * 4 + j) : (64 + tx * 4 + (j - 4));
      float y = (acc[i][j] - m) * rs * g[col] + be[col];
      if (RELU) y = fmaxf(y, 0.f);
      o[j] = y;
    }
    *(float4*)&out[(size_t)(row0 + r) * 128 + tx * 4]      = *(float4*)&o[0];
    *(float4*)&out[(size_t)(row0 + r) * 128 + 64 + tx * 4] = *(float4*)&o[4];
  }
}

// =====================================================================
// Block-wide (256 threads) sum helper
// =====================================================================
__device__ __forceinline__ float blockSum256(float v, float* sh)
{
#pragma unroll
  for (int d = 32; d; d >>= 1) v += __shfl_down(v, d, 64);
  __syncthreads();
  if ((threadIdx.x & 63) == 0) sh[threadIdx.x >> 6] = v;
  __syncthreads();
  return sh[0] + sh[1] + sh[2] + sh[3];
}

// Row LN (width 3072) + L2 normalize, in place; optional bf16 copy out
template<bool CVT>
__global__ __launch_bounds__(256)
void ln_l2_q(float* __restrict__ q, const float* __restrict__ g,
             const float* __restrict__ be, ushort_t* __restrict__ qb)
{
  __shared__ float sh[4];
  const int row = blockIdx.x, t = threadIdx.x;
  float* qr = q + (size_t)row * Ez;
  float x[12];
#pragma unroll
  for (int i = 0; i < 12; ++i) x[i] = qr[t + (i << 8)];
  float s = 0.f;
#pragma unroll
  for (int i = 0; i < 12; ++i) s += x[i];
  const float m = blockSum256(s, sh) * (1.f / (float)Ez);
  float vs = 0.f;
#pragma unroll
  for (int i = 0; i < 12; ++i) { const float d = x[i] - m; vs += d * d; }
  const float v = blockSum256(vs, sh) * (1.f / (float)Ez);
  const float rs = rsqrtf(v + 1e-5f);
  float y[12]; float qs = 0.f;
#pragma unroll
  for (int i = 0; i < 12; ++i) {
    const int c = t + (i << 8);
    const float yy = (x[i] - m) * rs * g[c] + be[c];
    y[i] = yy; qs += yy * yy;
  }
  const float tot = blockSum256(qs, sh);
  const float s2 = rsqrtf(tot + 1e-12f);
#pragma unroll
  for (int i = 0; i < 12; ++i) {
    const int c = t + (i << 8);
    const float yn = y[i] * s2;
    qr[c] = yn;
    if (CVT) qb[(size_t)row * Ez + c] = f2bf(yn);
  }
}

// rk[n] only (fallback)
__global__ __launch_bounds__(256)
void keynorm(const float* __restrict__ keys, float* __restrict__ rk)
{
  __shared__ float sh[4];
  const int row = blockIdx.x, t = threadIdx.x;
  const float* xr = keys + (size_t)row * Ez;
  float qs = 0.f;
#pragma unroll
  for (int i = 0; i < 12; ++i) { const float x = xr[t + (i << 8)]; qs += x * x; }
  const float tot = blockSum256(qs, sh);
  if (t == 0) rk[row] = rsqrtf(tot + 1e-12f);
}

// fused: rk[n] + knbf[n,:] = bf16(keys[n,:] * rk[n])
__global__ __launch_bounds__(256)
void keys_norm_cvt(const float* __restrict__ keys, float* __restrict__ rk,
                   ushort_t* __restrict__ knb)
{
  __shared__ float sh[4];
  const int row = blockIdx.x, t = threadIdx.x;
  const float* xr = keys + (size_t)row * Ez;
  float x[12]; float qs = 0.f;
#pragma unroll
  for (int i = 0; i < 12; ++i) { x[i] = xr[t + (i << 8)]; qs += x[i] * x[i]; }
  const float tot = blockSum256(qs, sh);
  const float s = rsqrtf(tot + 1e-12f);
  if (t == 0) rk[row] = s;
#pragma unroll
  for (int i = 0; i < 12; ++i)
    knb[(size_t)row * Ez + t + (i << 8)] = f2bf(x[i] * s);
}

// elementwise split fp32 -> bf16 hi + bf16 lo (count multiple of 1024)
__global__ __launch_bounds__(256)
void split_bf(const float* __restrict__ in, ushort_t* __restrict__ oh,
              ushort_t* __restrict__ ol)
{
  const size_t i = ((size_t)blockIdx.x * 256 + threadIdx.x) * 4;
  float4 v = *(const float4*)(in + i);
  ushort4 h, l;
  h.x = f2bf(v.x); l.x = f2bf(v.x - bf2f(h.x));
  h.y = f2bf(v.y); l.y = f2bf(v.y - bf2f(h.y));
  h.z = f2bf(v.z); l.z = f2bf(v.z - bf2f(h.z));
  h.w = f2bf(v.w); l.w = f2bf(v.w - bf2f(h.w));
  *(ushort4*)(oh + i) = h;
  *(ushort4*)(ol + i) = l;
}

// se_w3 (512 x 3072 fp32) -> transposed hi/lo bf16 (3072 x 512 each)
__global__ __launch_bounds__(256)
void w3_transpose_split(const float* __restrict__ w,
                        ushort_t* __restrict__ hT, ushort_t* __restrict__ lT)
{
  __shared__ float tile[64][65];
  const int k0 = blockIdx.x * 64;       // 512/64 = 8
  const int n0 = blockIdx.y * 64;       // 3072/64 = 48
  const int t = threadIdx.x;
  const int c = t & 63, r4 = t >> 6;
#pragma unroll
  for (int rr = 0; rr < 16; ++rr) {
    const int r = rr * 4 + r4;
    tile[r][c] = w[(size_t)(k0 + r) * 3072 + n0 + c];
  }
  __syncthreads();
#pragma unroll
  for (int rr = 0; rr < 16; ++rr) {
    const int n = rr * 4 + r4;
    const float a = tile[c][n];
    const ushort_t h = f2bf(a);
    hT[(size_t)(n0 + n) * 512 + k0 + c] = h;
    lT[(size_t)(n0 + n) * 512 + k0 + c] = f2bf(a - bf2f(h));
  }
}

// cc_w1 (3072 x 512 fp32) -> transposed bf16 (512 x 3072)
__global__ __launch_bounds__(256)
void cvt_w1t(const float* __restrict__ w, ushort_t* __restrict__ out)
{
  const int idx = blockIdx.x * 256 + threadIdx.x;
  const int k = idx >> 9, n = idx & 511;
  out[(size_t)n * Ez + k] = f2bf(w[idx]);
}

// =====================================================================
// Top-16 per row of the 8192 x 4096 u16-key score matrix.
// Packed u32 = (key<<12) | (4095-col): max-reduce == (max score, min col).
// Stage 1: each wave top-16 of its 1024 cols (no barriers).
// Stage 2: wave 0 reduces 64 candidates -> 16.
// =====================================================================
__global__ __launch_bounds__(256)
void topk16(const ushort_t* __restrict__ S, int* __restrict__ outIdx)
{
  __shared__ uint_t cand[64];
  const int row = blockIdx.x, t = threadIdx.x;
  const int w = t >> 6, lane = t & 63;
  const ushort_t* sr = S + (size_t)row * NEz + (w << 10);
  uint_t p[16];
#pragma unroll
  for (int j = 0; j < 16; ++j) {
    const int c = (j << 6) + lane;
    const uint_t key = sr[c];
    const int gc = (w << 10) + c;
    p[j] = (key << 12) | (uint_t)(4095 - gc);
  }
  for (int it = 0; it < 16; ++it) {
    uint_t m = p[0];
#pragma unroll
    for (int j = 1; j < 16; ++j) m = umax_(m, p[j]);
#pragma unroll
    for (int d = 1; d < 64; d <<= 1)
      m = umax_(m, (uint_t)__shfl_xor((int)m, d, 64));
    if (lane == it) cand[(w << 4) + it] = m;
#pragma unroll
    for (int j = 0; j < 16; ++j) p[j] = (p[j] == m) ? 0u : p[j];
  }
  __syncthreads();
  if (t < 64) {
    uint_t mine = cand[t];
    for (int it = 0; it < 16; ++it) {
      uint_t m = mine;
#pragma unroll
      for (int d = 1; d < 64; d <<= 1)
        m = umax_(m, (uint_t)__shfl_xor((int)m, d, 64));
      if (t == it) outIdx[(size_t)row * 16 + it] = 4095 - (int)(m & 0xFFFu);
      mine = (mine == m) ? 0u : mine;
    }
  }
}

// =====================================================================
// fp64 rescore of the 16 candidates on fp32 q & keys*rk; exact top-10 set.
// =====================================================================
__global__ __launch_bounds__(256)
void rescore(const float* __restrict__ qn, const float* __restrict__ keys,
             const float* __restrict__ rk, const int* __restrict__ cand,
             int* __restrict__ outIdx)
{
  __shared__ double sv[16];
  __shared__ int si[16];
  const int row = blockIdx.x, t = threadIdx.x;
  const int gr = t >> 4, l = t & 15;
  const int id = cand[(size_t)row * 16 + gr];
  const float* qr = qn + (size_t)row * Ez;
  const float* kr = keys + (size_t)id * Ez;
  double s = 0.0;
  for (int c = l; c < Ez; c += 16)
    s += (double)qr[c] * (double)kr[c];
#pragma unroll
  for (int d = 8; d; d >>= 1) s += __shfl_down(s, d, 16);
  if (l == 0) { sv[gr] = s * (double)rk[id]; si[gr] = id; }
  __syncthreads();
  if (t == 0) {
    for (int it = 0; it < 10; ++it) {
      int bj = 0; double bvv = sv[0]; int bi = si[0];
      for (int j = 1; j < 16; ++j) {
        const double v = sv[j]; const int i2 = si[j];
        if (v > bvv || (v == bvv && i2 < bi)) { bj = j; bvv = v; bi = i2; }
      }
      outIdx[(size_t)row * 10 + it] = bi;
      sv[bj] = -1e300;
    }
  }
}

// context mean of 10 raw key rows -> bf16 (fast path)
__global__ __launch_bounds__(256)
void gather_ctx_bf(const float* __restrict__ keys, const int* __restrict__ idx10,
                   ushort_t* __restrict__ ctxb)
{
  const int row = blockIdx.x, t = threadIdx.x;
  int id[10];
#pragma unroll
  for (int j = 0; j < 10; ++j) id[j] = idx10[(size_t)row * 10 + j];
#pragma unroll
  for (int i = 0; i < 6; ++i) {
    const int c = 2 * t + (i << 9);
    float s0 = 0.f, s1 = 0.f;
#pragma unroll
    for (int j = 0; j < 10; ++j) {
      float2 v = *(const float2*)&keys[(size_t)id[j] * Ez + c];
      s0 += v.x; s1 += v.y;
    }
    ushort2 o; o.x = f2bf(s0 * 0.1f); o.y = f2bf(s1 * 0.1f);
    *(ushort2*)&ctxb[(size_t)row * Ez + c] = o;
  }
}

// context mean -> fp32 (fallback path)
__global__ __launch_bounds__(256)
void gather_ctx(const float* __restrict__ keys, const int* __restrict__ idx10,
                float* __restrict__ ctx)
{
  const int row = blockIdx.x, t = threadIdx.x;
  int id[10];
#pragma unroll
  for (int j = 0; j < 10; ++j) id[j] = idx10[(size_t)row * 10 + j];
#pragma unroll
  for (int i = 0; i < 12; ++i) {
    const int c = t + (i << 8);
    float s = 0.f;
#pragma unroll
    for (int j = 0; j < 10; ++j) s += keys[(size_t)id[j] * Ez + c];
    ctx[(size_t)row * Ez + c] = s * 0.1f;
  }
}

// =====================================================================
// Router: 115 -> 64 -> 64 -> 4, clip, + gumbel, softmax, straight-through
// =====================================================================
__global__ __launch_bounds__(256)
void router_kernel(const float* __restrict__ state, const float* __restrict__ gn,
                   const float* __restrict__ w1, const float* __restrict__ b1,
                   const float* __restrict__ w2, const float* __restrict__ b2,
                   const float* __restrict__ w3, const float* __restrict__ b3,
                   float* __restrict__ outAlpha)
{
  const int row = blockIdx.x * 256 + threadIdx.x;
  const float* sr = state + (size_t)row * Sz;
  float h1[64];
#pragma unroll
  for (int j = 0; j < 64; ++j) h1[j] = b1[j];
  for (int k = 0; k < Sz; ++k) {
    const float a = sr[k];
    const float* wr = w1 + (size_t)k * 64;
#pragma unroll
    for (int j = 0; j < 64; ++j) h1[j] = fmaf(a, wr[j], h1[j]);
  }
#pragma unroll
  for (int j = 0; j < 64; ++j) h1[j] = fmaxf(h1[j], 0.f);
  float h2[64];
#pragma unroll
  for (int j = 0; j < 64; ++j) h2[j] = b2[j];
#pragma unroll
  for (int k = 0; k < 64; ++k) {
    const float a = h1[k];
    const float* wr = w2 + (size_t)k * 64;
#pragma unroll
    for (int j = 0; j < 64; ++j) h2[j] = fmaf(a, wr[j], h2[j]);
  }
#pragma unroll
  for (int j = 0; j < 64; ++j) h2[j] = fmaxf(h2[j], 0.f);
  float z[4];
#pragma unroll
  for (int a = 0; a < 4; ++a) {
    float s = b3[a];
#pragma unroll
    for (int k = 0; k < 64; ++k) s = fmaf(h2[k], w3[k * 4 + a], s);
    s = fminf(fmaxf(s, -20.f), 20.f);
    z[a] = s + gn[(size_t)row * 4 + a];   // TAU = 1
  }
  float mz = z[0];
#pragma unroll
  for (int a = 1; a < 4; ++a) mz = fmaxf(mz, z[a]);
  float e[4]; float se = 0.f;
#pragma unroll
  for (int a = 0; a < 4; ++a) { e[a] = expf(z[a] - mz); se += e[a]; }
  const float inv = 1.f / se;
  float y[4];
#pragma unroll
  for (int a = 0; a < 4; ++a) y[a] = e[a] * inv;
  int am = 0;
#pragma unroll
  for (int a = 1; a < 4; ++a) if (y[a] > y[am]) am = a;
#pragma unroll
  for (int a = 0; a < 4; ++a) {
    const float hard = (a == am) ? 1.f : 0.f;
    outAlpha[(size_t)row * 4 + a] = y[a] + (hard - y[a]);
  }
}

// critic head
__global__ __launch_bounds__(256)
void critic_head(const float* __restrict__ c2, const float* __restrict__ w3,
                 const float* __restrict__ b3, float* __restrict__ outv)
{
  const int row = blockIdx.x * 256 + threadIdx.x;
  const float* xr = c2 + (size_t)row * 256;
  float s = b3[0];
  for (int k = 0; k < 256; ++k) s = fmaf(xr[k], w3[k], s);
  outv[row] = s;
}

// all-4 actor heads fused
struct HeadP { const float* w3[4]; const float* b3[4]; };

__global__ __launch_bounds__(256)
void actor_head4(const float* __restrict__ x2g, HeadP p,
                 const float* __restrict__ alpha, float* __restrict__ outL)
{
  __shared__ float wsm[4][128 * 23];
  __shared__ float bs[4][23];
  const int t = threadIdx.x;
#pragma unroll
  for (int a = 0; a < 4; ++a) {
    for (int i = t; i < 128 * 23; i += 256) wsm[a][i] = p.w3[a][i];
    if (t < 23) bs[a][t] = p.b3[a][t];
  }
  __syncthreads();
  const int row = blockIdx.x * 64 + (t >> 2);
  const int cg = t & 3;
  float sum[6] = {0.f, 0.f, 0.f, 0.f, 0.f, 0.f};
#pragma unroll
  for (int a = 0; a < 4; ++a) {
    const float al = alpha[(size_t)row * 4 + a];
    const float* xr = x2g + (size_t)a * Bz * 128 + (size_t)row * 128;
    float acc[6] = {0.f, 0.f, 0.f, 0.f, 0.f, 0.f};
    for (int kk = 0; kk < 128; ++kk) {
      const float xa = xr[kk];
#pragma unroll
      for (int j = 0; j < 6; ++j) {
        const int col = cg + 4 * j;
        if (col < 23) acc[j] = fmaf(xa, wsm[a][kk * 23 + col], acc[j]);
      }
    }
#pragma unroll
    for (int j = 0; j < 6; ++j) {
      const int col = cg + 4 * j;
      if (col < 23) sum[j] += al * (acc[j] + bs[a][col]);
    }
  }
#pragma unroll
  for (int j = 0; j < 6; ++j) {
    const int col = cg + 4 * j;
    if (col < 23) outL[(size_t)row * 23 + col] = sum[j];
  }
}

// =====================================================================
extern "C" void kernel_launch(void* const* d_in, const int* in_sizes, int n_in,
                              void* d_out, int out_size, void* d_ws, size_t ws_size,
                              hipStream_t stream)
{
  const float* state  = (const float*)d_in[0];
  const float* gumbel = (const float*)d_in[1];
  const float* keys   = (const float*)d_in[2];
  const float* se_w1 = (const float*)d_in[3];
  const float* se_b1 = (const float*)d_in[4];
  const float* se_w2 = (const float*)d_in[5];
  const float* se_b2 = (const float*)d_in[6];
  const float* se_w3 = (const float*)d_in[7];
  const float* se_b3 = (const float*)d_in[8];
  const float* se_g  = (const float*)d_in[9];
  const float* se_be = (const float*)d_in[10];
  const float* cc_w1 = (const float*)d_in[11];
  const float* cc_b1 = (const float*)d_in[12];
  const float* cc_w2 = (const float*)d_in[13];
  const float* cc_b2 = (const float*)d_in[14];
  const float* cc_g  = (const float*)d_in[15];
  const float* cc_be = (const float*)d_in[16];
  const float* r_w1 = (const float*)d_in[57];
  const float* r_b1 = (const float*)d_in[58];
  const float* r_w2 = (const float*)d_in[59];
  const float* r_b2 = (const float*)d_in[60];
  const float* r_w3 = (const float*)d_in[61];
  const float* r_b3 = (const float*)d_in[62];
  const float* c_w1 = (const float*)d_in[63];
  const float* c_b1 = (const float*)d_in[64];
  const float* c_w2 = (const float*)d_in[65];
  const float* c_b2 = (const float*)d_in[66];
  const float* c_w3 = (const float*)d_in[67];
  const float* c_b3 = (const float*)d_in[68];

  // ---- workspace layout ----
  float* wsf = (float*)d_ws;
  const size_t qF = (size_t)Bz * Ez;          // 25,165,824 floats
  const size_t uF = (size_t)16777216;         // union region, floats
  float* q = wsf;
  float* U = wsf + qF;
  // U internal (time-multiplexed):
  float* sA  = U;                              // encoder ping   [0, 4.19M)
  float* sB  = U + 4194304;                    // encoder pong   [4.19M, 8.39M)
  ushort_t* sBh  = (ushort_t*)(U + 8388608);   // bf16 hi of sB  (4.19M halves)
  ushort_t* sBl  = (ushort_t*)(U + 10485760);  // bf16 lo of sB
  ushort_t* w3hT = (ushort_t*)(U + 12582912);  // se_w3^T hi (3072x512)
  ushort_t* w3lT = (ushort_t*)(U + 14155776);  // se_w3^T lo
  ushort_t* scoresU = (ushort_t*)U;            // 8192x4096 u16 keys (whole U)
  float* shr = U;                              // 8192x128
  float* x1g = U + 1 * 1048576;                // 4 x 8192x128
  float* x2g = U + 5 * 1048576;                // 4 x 8192x128
  float* cch = U + 9 * 1048576;                // 8192x512 (dies before cr1)
  float* cr1 = U + 9 * 1048576;                // 8192x256
  float* cr2 = U + 11 * 1048576;               // 8192x256
  // fast-path bf16 buffers after U:
  ushort_t* qbf  = (ushort_t*)(wsf + qF + uF);     // 8192x3072
  ushort_t* knbf = qbf + qF;                       // 4096x3072
  ushort_t* w1T  = knbf + (size_t)NEz * Ez;        // 512x3072
  const size_t bfHalves = qF + (size_t)NEz * Ez + (size_t)512 * Ez;
  const size_t baseBytes = (qF + uF) * sizeof(float);
  const size_t tailBytes = 4096 * 4 + (size_t)Bz * 16 * 4 + (size_t)Bz * 10 * 4;
  const bool fast = ws_size >= baseBytes + bfHalves * 2 + tailBytes;
  float* tailF = (float*)((char*)d_ws + (fast ? baseBytes + bfHalves * 2 : baseBytes));
  float* rk  = tailF;
  int* cand  = (int*)(tailF + 4096);
  int* sel   = cand + (size_t)Bz * 16;
  ushort_t* ctxb = (ushort_t*)q;               // bf16 ctx overlays dead q

  float* outL = (float*)d_out;                 // 8192*23
  float* outA = outL + (size_t)Bz * 23;        // 8192*4
  float* outV = outA + (size_t)Bz * 4;         // 8192*1

  const dim3 blk(256);

  // --- state encoder ---
  gemm128<true, true><<<dim3(4, 64), blk, 0, stream>>>(state, se_w1, se_b1, sA, 512, 115);
  gemm128<true, true><<<dim3(4, 64), blk, 0, stream>>>(sA,    se_w2, se_b2, sB, 512, 512);
  if (fast) {
    // se_w3 via bf16x3 split-precision MFMA (fp32-accurate)
    split_bf<<<dim3(4096), blk, 0, stream>>>(sB, sBh, sBl);
    w3_transpose_split<<<dim3(8, 48), blk, 0, stream>>>(se_w3, w3hT, w3lT);
    mfma3_bt<<<dim3(24, 64), blk, 0, stream>>>(sBh, sBl, w3hT, w3lT, se_b3, q, 3072, 512);
    ln_l2_q<true><<<dim3(Bz), blk, 0, stream>>>(q, se_g, se_be, qbf);
    keys_norm_cvt<<<dim3(NEz), blk, 0, stream>>>(keys, rk, knbf);
    cvt_w1t<<<dim3(6144), blk, 0, stream>>>(cc_w1, w1T);
    mfma_bt<0><<<dim3(32, 64), blk, 0, stream>>>(qbf, knbf, nullptr, scoresU, NEz, Ez);
  } else {
    gemm128<false, true><<<dim3(24, 64), blk, 0, stream>>>(sB, se_w3, se_b3, q, 3072, 512);
    ln_l2_q<false><<<dim3(Bz), blk, 0, stream>>>(q, se_g, se_be, nullptr);
    keynorm<<<dim3(NEz), blk, 0, stream>>>(keys, rk);
    gemm_scores<<<dim3(32, 64), blk, 0, stream>>>(q, keys, rk, scoresU);
  }

  // --- top-16 screen, fp64 rescore -> exact top-10 set ---
  topk16<<<dim3(Bz), blk, 0, stream>>>(scoresU, cand);
  rescore<<<dim3(Bz), blk, 0, stream>>>(q, keys, rk, cand, sel);

  // --- context + compressor ---
  if (fast) {
    gather_ctx_bf<<<dim3(Bz), blk, 0, stream>>>(keys, sel, ctxb);
    mfma_bt<1><<<dim3(4, 64), blk, 0, stream>>>(ctxb, w1T, cc_b1, cch, 512, Ez);
  } else {
    gather_ctx<<<dim3(Bz), blk, 0, stream>>>(keys, sel, q);
    gemm128<true, true><<<dim3(4, 64), blk, 0, stream>>>(q, cc_w1, cc_b1, cch, 512, Ez);
  }
  {
    LN4 pcc = {};
    pcc.W[0] = cc_w2; pcc.b[0] = cc_b2; pcc.g[0] = cc_g; pcc.be[0] = cc_be;
    gemm_ln4<false, false><<<dim3(128, 1), blk, 0, stream>>>(cch, 0, 512, nullptr, pcc,
                                                             shr, 0);
  }

  // --- critic ---
  gemm128<true, true><<<dim3(2, 64), blk, 0, stream>>>(state, c_w1, c_b1, cr1, 256, 115);
  gemm128<true, true><<<dim3(2, 64), blk, 0, stream>>>(cr1, c_w2, c_b2, cr2, 256, 256);
  critic_head<<<dim3(32), blk, 0, stream>>>(cr2, c_w3, c_b3, outV);

  // --- router ---
  router_kernel<<<dim3(32), blk, 0, stream>>>(state, gumbel, r_w1, r_b1, r_w2, r_b2,
                                              r_w3, r_b3, outA);

  // --- actors (batched over blockIdx.y) ---
  {
    LN4 p1 = {}, p2 = {};
    HeadP ph = {};
    const int eoffs[4] = {0, 20, 40, 45};
    const int elens[4] = {50, 20, 10, 15};
    for (int a = 0; a < 4; ++a) {
      const int base = 17 + 10 * a;
      p1.W[a]  = (const float*)d_in[base + 0];
      p1.b[a]  = (const float*)d_in[base + 1];
      p1.g[a]  = (const float*)d_in[base + 2];
      p1.be[a] = (const float*)d_in[base + 3];
      p1.eoff[a] = eoffs[a]; p1.elen[a] = elens[a];
      p2.W[a]  = (const float*)d_in[base + 4];
      p2.b[a]  = (const float*)d_in[base + 5];
      p2.g[a]  = (const float*)d_in[base + 6];
      p2.be[a] = (const float*)d_in[base + 7];
      ph.w3[a] = (const float*)d_in[base + 8];
      ph.b3[a] = (const float*)d_in[base + 9];
    }
    gemm_ln4<true, true ><<<dim3(128, 4), blk, 0, stream>>>(shr, 0, 128, state, p1,
                                                            x1g, (size_t)Bz * 128);
    gemm_ln4<true, false><<<dim3(128, 4), blk, 0, stream>>>(x1g, (size_t)Bz * 128, 128,
                                                            nullptr, p2,
                                                            x2g, (size_t)Bz * 128);
    actor_head4<<<dim3(128), blk, 0, stream>>>(x2g, ph, outA, outL);
  }
}

// Round 5
// 1436.892 us; speedup vs baseline: 3.0772x; 1.1347x over previous
//
#include <hip/hip_runtime.h>

// Problem constants (match reference)
constexpr int Bz = 8192;   // batch
constexpr int Sz = 115;    // state dim
constexpr int Ez = 3072;   // embedding dim
constexpr int NEz = 4096;  // num keys
// C=128, A=23, K=10, TAU=1, EPS=1e-5

typedef __attribute__((ext_vector_type(8))) short short8;
typedef __attribute__((ext_vector_type(4))) float floatx4;
typedef unsigned short ushort_t;
typedef unsigned int uint_t;

__device__ __forceinline__ ushort_t f2bf(float f) {
  uint_t u = __float_as_uint(f);
  uint_t r = (u + 0x7FFFu + ((u >> 16) & 1u)) >> 16;   // RNE
  return (ushort_t)r;
}
__device__ __forceinline__ float bf2f(ushort_t b) {
  uint_t u = ((uint_t)b) << 16;
  return __uint_as_float(u);
}
// fp32 -> fp16 -> order-preserving u16 key (monotone total order)
__device__ __forceinline__ ushort_t f2key(float v) {
  _Float16 h = (_Float16)v;
  ushort_t b = __builtin_bit_cast(ushort_t, h);
  return b ^ ((b & 0x8000u) ? 0xFFFFu : 0x8000u);
}
__device__ __forceinline__ uint_t umax_(uint_t a, uint_t b) { return a > b ? a : b; }

// async global->LDS, 16 B per lane; lds dest = wave-uniform base + lane*16
__device__ __forceinline__ void gload16(const ushort_t* g, ushort_t* l) {
  __builtin_amdgcn_global_load_lds(
      (__attribute__((address_space(1))) const void*)g,
      (__attribute__((address_space(3))) void*)l, 16, 0, 0);
}

// =====================================================================
// Generic fp32 tiled GEMM: C[M x N] = act(A[M x K] @ B + bias)
// B is K x N row-major. Tile 128x128x16, 256 threads, 8x8/thread.
// =====================================================================
template<bool RELU, bool BIAS>
__global__ __launch_bounds__(256)
void gemm128(const float* __restrict__ A, const float* __restrict__ Bm,
             const float* __restrict__ bias, float* __restrict__ C,
             int N, int Kd)
{
  __shared__ float As[16][132];
  __shared__ float Bs[16][132];
  const int t  = threadIdx.x;
  const int tx = t & 15, ty = t >> 4;
  const int row0 = blockIdx.y * 128;
  const int col0 = blockIdx.x * 128;
  const int ar = t >> 2, ac = (t & 3) * 4;
  const int bk = t >> 5, bc = (t & 31) * 4;
  const bool a4 = (Kd & 3) == 0;

  float acc[8][8];
#pragma unroll
  for (int i = 0; i < 8; ++i)
#pragma unroll
    for (int j = 0; j < 8; ++j) acc[i][j] = 0.f;

  for (int k0 = 0; k0 < Kd; k0 += 16) {
    const bool fullA = (k0 + 16 <= Kd) && a4;
    {
      const float* ap = A + (size_t)(row0 + ar) * Kd + k0 + ac;
      if (fullA) {
        float4 v0 = *(const float4*)ap;
        float4 v1 = *(const float4*)(ap + (size_t)64 * Kd);
        As[ac + 0][ar] = v0.x; As[ac + 1][ar] = v0.y;
        As[ac + 2][ar] = v0.z; As[ac + 3][ar] = v0.w;
        As[ac + 0][ar + 64] = v1.x; As[ac + 1][ar + 64] = v1.y;
        As[ac + 2][ar + 64] = v1.z; As[ac + 3][ar + 64] = v1.w;
      } else {
#pragma unroll
        for (int e = 0; e < 4; ++e) {
          const int k = k0 + ac + e;
          float v0 = 0.f, v1 = 0.f;
          if (k < Kd) { v0 = ap[e]; v1 = ap[e + (size_t)64 * Kd]; }
          As[ac + e][ar] = v0; As[ac + e][ar + 64] = v1;
        }
      }
    }
    {
      const float* bp = Bm + (size_t)(k0 + bk) * N + col0 + bc;
      if (k0 + 16 <= Kd) {
        *(float4*)&Bs[bk][bc]     = *(const float4*)bp;
        *(float4*)&Bs[bk + 8][bc] = *(const float4*)(bp + (size_t)8 * N);
      } else {
        float4 z; z.x = z.y = z.z = z.w = 0.f;
        *(float4*)&Bs[bk][bc]     = (k0 + bk     < Kd) ? *(const float4*)bp : z;
        *(float4*)&Bs[bk + 8][bc] = (k0 + bk + 8 < Kd) ? *(const float4*)(bp + (size_t)8 * N) : z;
      }
    }
    __syncthreads();
#pragma unroll
    for (int kk = 0; kk < 16; ++kk) {
      float a[8], b[8];
      *(float4*)&a[0] = *(const float4*)&As[kk][ty * 4];
      *(float4*)&a[4] = *(const float4*)&As[kk][64 + ty * 4];
      *(float4*)&b[0] = *(const float4*)&Bs[kk][tx * 4];
      *(float4*)&b[4] = *(const float4*)&Bs[kk][64 + tx * 4];
#pragma unroll
      for (int i = 0; i < 8; ++i)
#pragma unroll
        for (int j = 0; j < 8; ++j)
          acc[i][j] = fmaf(a[i], b[j], acc[i][j]);
    }
    __syncthreads();
  }

  float bv[8];
#pragma unroll
  for (int j = 0; j < 8; ++j) bv[j] = 0.f;
  if (BIAS) {
    *(float4*)&bv[0] = *(const float4*)&bias[col0 + tx * 4];
    *(float4*)&bv[4] = *(const float4*)&bias[col0 + 64 + tx * 4];
  }
#pragma unroll
  for (int i = 0; i < 8; ++i) {
    const int r = row0 + ((i < 4) ? (ty * 4 + i) : (64 + ty * 4 + i - 4));
    float o[8];
#pragma unroll
    for (int j = 0; j < 8; ++j) {
      o[j] = acc[i][j] + bv[j];
      if (RELU) o[j] = fmaxf(o[j], 0.f);
    }
    *(float4*)&C[(size_t)r * N + col0 + tx * 4]      = *(float4*)&o[0];
    *(float4*)&C[(size_t)r * N + col0 + 64 + tx * 4] = *(float4*)&o[4];
  }
}

// =====================================================================
// bf16 MFMA GEMM, A(M x K) @ B(N x K)^T, both row-major bf16 (K-contig).
// Tile 128x128xBK32, 256 thr = 4 waves (2x2 of 64x64), 4x4 MFMA acc/wave.
// EPI=0: store order-preserving u16 score keys. EPI=1: fp32 + bias + ReLU.
// =====================================================================
template<int EPI>
__global__ __launch_bounds__(256)
void mfma_bt(const ushort_t* __restrict__ A, const ushort_t* __restrict__ B,
             const float* __restrict__ bias, void* __restrict__ Cout,
             int N, int Kd)
{
  __shared__ ushort_t Al[128 * 32];
  __shared__ ushort_t Bl[128 * 32];
  const int t = threadIdx.x;
  const int wid = t >> 6, lane = t & 63;
  const int wr = wid >> 1, wc = wid & 1;
  const int row0 = blockIdx.y * 128;
  const int col0 = blockIdx.x * 128;
  const int srow = lane >> 2;
  const int scol = (lane & 3) * 8;

  const ushort_t* ga0 = A + (size_t)(row0 + wid * 16 + srow) * Kd + scol;
  const ushort_t* ga1 = A + (size_t)(row0 + (wid + 4) * 16 + srow) * Kd + scol;
  const ushort_t* gb0 = B + (size_t)(col0 + wid * 16 + srow) * Kd + scol;
  const ushort_t* gb1 = B + (size_t)(col0 + (wid + 4) * 16 + srow) * Kd + scol;
  ushort_t* la0 = &Al[(wid * 16) * 32];
  ushort_t* la1 = &Al[((wid + 4) * 16) * 32];
  ushort_t* lb0 = &Bl[(wid * 16) * 32];
  ushort_t* lb1 = &Bl[((wid + 4) * 16) * 32];

  const int mr = lane & 15, qd = lane >> 4;

  floatx4 acc[4][4];
#pragma unroll
  for (int i = 0; i < 4; ++i)
#pragma unroll
    for (int j = 0; j < 4; ++j) acc[i][j] = (floatx4){0.f, 0.f, 0.f, 0.f};

  for (int kb = 0; kb < Kd; kb += 32) {
    gload16(ga0 + kb, la0);
    gload16(ga1 + kb, la1);
    gload16(gb0 + kb, lb0);
    gload16(gb1 + kb, lb1);
    __syncthreads();
    short8 aF[4], bF[4];
#pragma unroll
    for (int i = 0; i < 4; ++i)
      aF[i] = *(const short8*)&Al[(wr * 64 + i * 16 + mr) * 32 + qd * 8];
#pragma unroll
    for (int j = 0; j < 4; ++j)
      bF[j] = *(const short8*)&Bl[(wc * 64 + j * 16 + mr) * 32 + qd * 8];
#pragma unroll
    for (int i = 0; i < 4; ++i)
#pragma unroll
      for (int j = 0; j < 4; ++j)
        acc[i][j] = __builtin_amdgcn_mfma_f32_16x16x32_bf16(aF[i], bF[j], acc[i][j], 0, 0, 0);
    __syncthreads();
  }

  // C/D layout: col = lane&15, row = (lane>>4)*4 + reg
#pragma unroll
  for (int i = 0; i < 4; ++i) {
#pragma unroll
    for (int j = 0; j < 4; ++j) {
      const int col = col0 + wc * 64 + j * 16 + mr;
#pragma unroll
      for (int r = 0; r < 4; ++r) {
        const int row = row0 + wr * 64 + i * 16 + qd * 4 + r;
        if (EPI == 0) {
          ((ushort_t*)Cout)[(size_t)row * N + col] = f2key(acc[i][j][r]);
        } else {
          float v = acc[i][j][r] + bias[col];
          ((float*)Cout)[(size_t)row * N + col] = fmaxf(v, 0.f);
        }
      }
    }
  }
}

// =====================================================================
// bf16x3 split-precision MFMA GEMM (fp32-accurate): C = A@B^T + bias
// =====================================================================
__global__ __launch_bounds__(256)
void mfma3_bt(const ushort_t* __restrict__ Ah, const ushort_t* __restrict__ Alo,
              const ushort_t* __restrict__ Bh, const ushort_t* __restrict__ Blo,
              const float* __restrict__ bias, float* __restrict__ Cout,
              int N, int Kd)
{
  __shared__ ushort_t AhL[128 * 32];
  __shared__ ushort_t AlL[128 * 32];
  __shared__ ushort_t BhL[128 * 32];
  __shared__ ushort_t BlL[128 * 32];
  const int t = threadIdx.x;
  const int wid = t >> 6, lane = t & 63;
  const int wr = wid >> 1, wc = wid & 1;
  const int row0 = blockIdx.y * 128;
  const int col0 = blockIdx.x * 128;
  const int srow = lane >> 2;
  const int scol = (lane & 3) * 8;

  const size_t aoff0 = (size_t)(row0 + wid * 16 + srow) * Kd + scol;
  const size_t aoff1 = (size_t)(row0 + (wid + 4) * 16 + srow) * Kd + scol;
  const size_t boff0 = (size_t)(col0 + wid * 16 + srow) * Kd + scol;
  const size_t boff1 = (size_t)(col0 + (wid + 4) * 16 + srow) * Kd + scol;
  const int l0 = (wid * 16) * 32;
  const int l1 = ((wid + 4) * 16) * 32;

  const int mr = lane & 15, qd = lane >> 4;

  floatx4 acc[4][4];
#pragma unroll
  for (int i = 0; i < 4; ++i)
#pragma unroll
    for (int j = 0; j < 4; ++j) acc[i][j] = (floatx4){0.f, 0.f, 0.f, 0.f};

  for (int kb = 0; kb < Kd; kb += 32) {
    gload16(Ah + aoff0 + kb, &AhL[l0]);
    gload16(Ah + aoff1 + kb, &AhL[l1]);
    gload16(Alo + aoff0 + kb, &AlL[l0]);
    gload16(Alo + aoff1 + kb, &AlL[l1]);
    gload16(Bh + boff0 + kb, &BhL[l0]);
    gload16(Bh + boff1 + kb, &BhL[l1]);
    gload16(Blo + boff0 + kb, &BlL[l0]);
    gload16(Blo + boff1 + kb, &BlL[l1]);
    __syncthreads();
    short8 ahF[4], alF[4], bhF[4], blF[4];
#pragma unroll
    for (int i = 0; i < 4; ++i) {
      const int o = (wr * 64 + i * 16 + mr) * 32 + qd * 8;
      ahF[i] = *(const short8*)&AhL[o];
      alF[i] = *(const short8*)&AlL[o];
    }
#pragma unroll
    for (int j = 0; j < 4; ++j) {
      const int o = (wc * 64 + j * 16 + mr) * 32 + qd * 8;
      bhF[j] = *(const short8*)&BhL[o];
      blF[j] = *(const short8*)&BlL[o];
    }
#pragma unroll
    for (int i = 0; i < 4; ++i)
#pragma unroll
      for (int j = 0; j < 4; ++j) {
        acc[i][j] = __builtin_amdgcn_mfma_f32_16x16x32_bf16(alF[i], bhF[j], acc[i][j], 0, 0, 0);
        acc[i][j] = __builtin_amdgcn_mfma_f32_16x16x32_bf16(ahF[i], blF[j], acc[i][j], 0, 0, 0);
        acc[i][j] = __builtin_amdgcn_mfma_f32_16x16x32_bf16(ahF[i], bhF[j], acc[i][j], 0, 0, 0);
      }
    __syncthreads();
  }

#pragma unroll
  for (int i = 0; i < 4; ++i) {
#pragma unroll
    for (int j = 0; j < 4; ++j) {
      const int col = col0 + wc * 64 + j * 16 + mr;
#pragma unroll
      for (int r = 0; r < 4; ++r) {
        const int row = row0 + wr * 64 + i * 16 + qd * 4 + r;
        Cout[(size_t)row * N + col] = acc[i][j][r] + bias[col];
      }
    }
  }
}

// =====================================================================
// fp32 scores GEMM (fallback path only) -> u16 score keys
// =====================================================================
__global__ __launch_bounds__(256)
void gemm_scores(const float* __restrict__ A, const float* __restrict__ Bm,
                 const float* __restrict__ rk, ushort_t* __restrict__ S)
{
  __shared__ float As[16][132];
  __shared__ float Bs[16][132];
  const int t  = threadIdx.x;
  const int tx = t & 15, ty = t >> 4;
  const int row0 = blockIdx.y * 128;
  const int col0 = blockIdx.x * 128;
  const int ar = t >> 2, ac = (t & 3) * 4;
  const int Kd = Ez;

  float acc[8][8];
#pragma unroll
  for (int i = 0; i < 8; ++i)
#pragma unroll
    for (int j = 0; j < 8; ++j) acc[i][j] = 0.f;

  for (int k0 = 0; k0 < Kd; k0 += 16) {
    {
      const float* ap = A + (size_t)(row0 + ar) * Kd + k0 + ac;
      float4 v0 = *(const float4*)ap;
      float4 v1 = *(const float4*)(ap + (size_t)64 * Kd);
      As[ac + 0][ar] = v0.x; As[ac + 1][ar] = v0.y;
      As[ac + 2][ar] = v0.z; As[ac + 3][ar] = v0.w;
      As[ac + 0][ar + 64] = v1.x; As[ac + 1][ar + 64] = v1.y;
      As[ac + 2][ar + 64] = v1.z; As[ac + 3][ar + 64] = v1.w;
    }
    {
      const float* bp = Bm + (size_t)(col0 + ar) * Kd + k0 + ac;
      float4 v0 = *(const float4*)bp;
      float4 v1 = *(const float4*)(bp + (size_t)64 * Kd);
      Bs[ac + 0][ar] = v0.x; Bs[ac + 1][ar] = v0.y;
      Bs[ac + 2][ar] = v0.z; Bs[ac + 3][ar] = v0.w;
      Bs[ac + 0][ar + 64] = v1.x; Bs[ac + 1][ar + 64] = v1.y;
      Bs[ac + 2][ar + 64] = v1.z; Bs[ac + 3][ar + 64] = v1.w;
    }
    __syncthreads();
#pragma unroll
    for (int kk = 0; kk < 16; ++kk) {
      float a[8], b[8];
      *(float4*)&a[0] = *(const float4*)&As[kk][ty * 4];
      *(float4*)&a[4] = *(const float4*)&As[kk][64 + ty * 4];
      *(float4*)&b[0] = *(const float4*)&Bs[kk][tx * 4];
      *(float4*)&b[4] = *(const float4*)&Bs[kk][64 + tx * 4];
#pragma unroll
      for (int i = 0; i < 8; ++i)
#pragma unroll
        for (int j = 0; j < 8; ++j)
          acc[i][j] = fmaf(a[i], b[j], acc[i][j]);
    }
    __syncthreads();
  }

  float rk0[8];
  *(float4*)&rk0[0] = *(const float4*)&rk[col0 + tx * 4];
  *(float4*)&rk0[4] = *(const float4*)&rk[col0 + 64 + tx * 4];
#pragma unroll
  for (int i = 0; i < 8; ++i) {
    const int r = row0 + ((i < 4) ? (ty * 4 + i) : (64 + ty * 4 + i - 4));
    ushort4 h0, h1;
    h0.x = f2key(acc[i][0] * rk0[0]); h0.y = f2key(acc[i][1] * rk0[1]);
    h0.z = f2key(acc[i][2] * rk0[2]); h0.w = f2key(acc[i][3] * rk0[3]);
    h1.x = f2key(acc[i][4] * rk0[4]); h1.y = f2key(acc[i][5] * rk0[5]);
    h1.z = f2key(acc[i][6] * rk0[6]); h1.w = f2key(acc[i][7] * rk0[7]);
    *(ushort4*)&S[(size_t)r * NEz + col0 + tx * 4]      = h0;
    *(ushort4*)&S[(size_t)r * NEz + col0 + 64 + tx * 4] = h1;
  }
}

// =====================================================================
// Batched (4-actor) fused GEMM(N=128) + LayerNorm (+ReLU).
// =====================================================================
struct LN4 {
  const float* W[4]; const float* b[4]; const float* g[4]; const float* be[4];
  int eoff[4]; int elen[4];
};

template<bool RELU, bool HASEXT>
__global__ __launch_bounds__(256)
void gemm_ln4(const float* __restrict__ A1base, size_t a1stride, int K1,
              const float* __restrict__ A2, LN4 p,
              float* __restrict__ outbase, size_t ostride)
{
  __shared__ float As[32][68];
  __shared__ float Bs[32][132];
  __shared__ float rsum[64][17];
  __shared__ float rsq[64][17];
  __shared__ float stm[64], str[64];
  const int a = blockIdx.y;
  const float* A1 = A1base + (size_t)a * a1stride;
  float* out = outbase + (size_t)a * ostride;
  const float* W = p.W[a];
  const float* bias = p.b[a];
  const float* g = p.g[a];
  const float* be = p.be[a];
  const int eoff = HASEXT ? p.eoff[a] : 0;
  const int K2 = HASEXT ? p.elen[a] : 0;

  const int t = threadIdx.x;
  const int tx = t & 15, ty = t >> 4;
  const int row0 = blockIdx.x * 64;
  const int Kt = K1 + K2;
  const int ar = t >> 2, ac = (t & 3) * 8;
  const int bk = t >> 3, bc = (t & 7) * 16;

  float acc[4][8];
#pragma unroll
  for (int i = 0; i < 4; ++i)
#pragma unroll
    for (int j = 0; j < 8; ++j) acc[i][j] = 0.f;

  for (int k0 = 0; k0 < Kt; k0 += 32) {
    const int grow = row0 + ar;
#pragma unroll
    for (int e = 0; e < 8; ++e) {
      const int k = k0 + ac + e;
      float v = 0.f;
      if (k < K1)      v = A1[(size_t)grow * K1 + k];
      else if (k < Kt) v = A2[(size_t)grow * 115 + eoff + (k - K1)];
      As[ac + e][ar] = v;
    }
    {
      const int k = k0 + bk;
#pragma unroll
      for (int qd = 0; qd < 4; ++qd) {
        float4 z; z.x = z.y = z.z = z.w = 0.f;
        *(float4*)&Bs[bk][bc + 4 * qd] =
            (k < Kt) ? *(const float4*)&W[(size_t)k * 128 + bc + 4 * qd] : z;
      }
    }
    __syncthreads();
#pragma unroll
    for (int kk = 0; kk < 32; ++kk) {
      float av[4], bv2[8];
      *(float4*)&av[0]  = *(const float4*)&As[kk][ty * 4];
      *(float4*)&bv2[0] = *(const float4*)&Bs[kk][tx * 4];
      *(float4*)&bv2[4] = *(const float4*)&Bs[kk][64 + tx * 4];
#pragma unroll
      for (int i = 0; i < 4; ++i)
#pragma unroll
        for (int j = 0; j < 8; ++j)
          acc[i][j] = fmaf(av[i], bv2[j], acc[i][j]);
    }
    __syncthreads();
  }

  float bv[8];
  *(float4*)&bv[0] = *(const float4*)&bias[tx * 4];
  *(float4*)&bv[4] = *(const float4*)&bias[64 + tx * 4];
#pragma unroll
  for (int i = 0; i < 4; ++i) {
    float s = 0.f, q = 0.f;
#pragma unroll
    for (int j = 0; j < 8; ++j) {
      acc[i][j] += bv[j];
      s += acc[i][j];
      q += acc[i][j] * acc[i][j];
    }
    rsum[ty * 4 + i][tx] = s;
    rsq[ty * 4 + i][tx]  = q;
  }
  __syncthreads();
  if (t < 64) {
    float s = 0.f, q = 0.f;
#pragma unroll
    for (int x = 0; x < 16; ++x) { s += rsum[t][x]; q += rsq[t][x]; }
    const float m = s * (1.f / 128.f);
    const float v = q * (1.f / 128.f) - m * m;
    stm[t] = m;
    str[t] = rsqrtf(v + 1e-5f);
  }
  __syncthreads();
#pragma unroll
  for (int i = 0; i < 4; ++i) {
    const int r = ty * 4 + i;
    const float m = stm[r], rs = str[r];
    float o[8];
#pragma unroll
    for (int j = 0; j < 8; ++j) {
      const int col = (j < 4) ? (tx * 4 + j) : (64 + tx * 4 + (j - 4));
      float y = (acc[i][j] - m) * rs * g[col] + be[col];
      if (RELU) y = fmaxf(y, 0.f);
      o[j] = y;
    }
    *(float4*)&out[(size_t)(row0 + r) * 128 + tx * 4]      = *(float4*)&o[0];
    *(float4*)&out[(size_t)(row0 + r) * 128 + 64 + tx * 4] = *(float4*)&o[4];
  }
}

// =====================================================================
// Block-wide (256 threads) sum helper
// =====================================================================
__device__ __forceinline__ float blockSum256(float v, float* sh)
{
#pragma unroll
  for (int d = 32; d; d >>= 1) v += __shfl_down(v, d, 64);
  __syncthreads();
  if ((threadIdx.x & 63) == 0) sh[threadIdx.x >> 6] = v;
  __syncthreads();
  return sh[0] + sh[1] + sh[2] + sh[3];
}

// Row LN (width 3072) + L2 normalize, in place; optional bf16 copy out
template<bool CVT>
__global__ __launch_bounds__(256)
void ln_l2_q(float* __restrict__ q, const float* __restrict__ g,
             const float* __restrict__ be, ushort_t* __restrict__ qb)
{
  __shared__ float sh[4];
  const int row = blockIdx.x, t = threadIdx.x;
  float* qr = q + (size_t)row * Ez;
  float x[12];
#pragma unroll
  for (int i = 0; i < 12; ++i) x[i] = qr[t + (i << 8)];
  float s = 0.f;
#pragma unroll
  for (int i = 0; i < 12; ++i) s += x[i];
  const float m = blockSum256(s, sh) * (1.f / (float)Ez);
  float vs = 0.f;
#pragma unroll
  for (int i = 0; i < 12; ++i) { const float d = x[i] - m; vs += d * d; }
  const float v = blockSum256(vs, sh) * (1.f / (float)Ez);
  const float rs = rsqrtf(v + 1e-5f);
  float y[12]; float qs = 0.f;
#pragma unroll
  for (int i = 0; i < 12; ++i) {
    const int c = t + (i << 8);
    const float yy = (x[i] - m) * rs * g[c] + be[c];
    y[i] = yy; qs += yy * yy;
  }
  const float tot = blockSum256(qs, sh);
  const float s2 = rsqrtf(tot + 1e-12f);
#pragma unroll
  for (int i = 0; i < 12; ++i) {
    const int c = t + (i << 8);
    const float yn = y[i] * s2;
    qr[c] = yn;
    if (CVT) qb[(size_t)row * Ez + c] = f2bf(yn);
  }
}

// rk[n] only (fallback)
__global__ __launch_bounds__(256)
void keynorm(const float* __restrict__ keys, float* __restrict__ rk)
{
  __shared__ float sh[4];
  const int row = blockIdx.x, t = threadIdx.x;
  const float* xr = keys + (size_t)row * Ez;
  float qs = 0.f;
#pragma unroll
  for (int i = 0; i < 12; ++i) { const float x = xr[t + (i << 8)]; qs += x * x; }
  const float tot = blockSum256(qs, sh);
  if (t == 0) rk[row] = rsqrtf(tot + 1e-12f);
}

// fused: rk[n] + knbf[n,:] = bf16(keys[n,:] * rk[n])
__global__ __launch_bounds__(256)
void keys_norm_cvt(const float* __restrict__ keys, float* __restrict__ rk,
                   ushort_t* __restrict__ knb)
{
  __shared__ float sh[4];
  const int row = blockIdx.x, t = threadIdx.x;
  const float* xr = keys + (size_t)row * Ez;
  float x[12]; float qs = 0.f;
#pragma unroll
  for (int i = 0; i < 12; ++i) { x[i] = xr[t + (i << 8)]; qs += x[i] * x[i]; }
  const float tot = blockSum256(qs, sh);
  const float s = rsqrtf(tot + 1e-12f);
  if (t == 0) rk[row] = s;
#pragma unroll
  for (int i = 0; i < 12; ++i)
    knb[(size_t)row * Ez + t + (i << 8)] = f2bf(x[i] * s);
}

// elementwise split fp32 -> bf16 hi + bf16 lo (count multiple of 1024)
__global__ __launch_bounds__(256)
void split_bf(const float* __restrict__ in, ushort_t* __restrict__ oh,
              ushort_t* __restrict__ ol)
{
  const size_t i = ((size_t)blockIdx.x * 256 + threadIdx.x) * 4;
  float4 v = *(const float4*)(in + i);
  ushort4 h, l;
  h.x = f2bf(v.x); l.x = f2bf(v.x - bf2f(h.x));
  h.y = f2bf(v.y); l.y = f2bf(v.y - bf2f(h.y));
  h.z = f2bf(v.z); l.z = f2bf(v.z - bf2f(h.z));
  h.w = f2bf(v.w); l.w = f2bf(v.w - bf2f(h.w));
  *(ushort4*)(oh + i) = h;
  *(ushort4*)(ol + i) = l;
}

// se_w3 (512 x 3072 fp32) -> transposed hi/lo bf16 (3072 x 512 each)
__global__ __launch_bounds__(256)
void w3_transpose_split(const float* __restrict__ w,
                        ushort_t* __restrict__ hT, ushort_t* __restrict__ lT)
{
  __shared__ float tile[64][65];
  const int k0 = blockIdx.x * 64;
  const int n0 = blockIdx.y * 64;
  const int t = threadIdx.x;
  const int c = t & 63, r4 = t >> 6;
#pragma unroll
  for (int rr = 0; rr < 16; ++rr) {
    const int r = rr * 4 + r4;
    tile[r][c] = w[(size_t)(k0 + r) * 3072 + n0 + c];
  }
  __syncthreads();
#pragma unroll
  for (int rr = 0; rr < 16; ++rr) {
    const int n = rr * 4 + r4;
    const float a = tile[c][n];
    const ushort_t h = f2bf(a);
    hT[(size_t)(n0 + n) * 512 + k0 + c] = h;
    lT[(size_t)(n0 + n) * 512 + k0 + c] = f2bf(a - bf2f(h));
  }
}

// cc_w1 (3072 x 512 fp32) -> transposed bf16 (512 x 3072)
__global__ __launch_bounds__(256)
void cvt_w1t(const float* __restrict__ w, ushort_t* __restrict__ out)
{
  const int idx = blockIdx.x * 256 + threadIdx.x;
  const int k = idx >> 9, n = idx & 511;
  out[(size_t)n * Ez + k] = f2bf(w[idx]);
}

// =====================================================================
// Top-16 per row of the 8192 x 4096 u16-key score matrix.
// Packed u32 = (key<<12) | (4095-col): max-reduce == (max score, min col).
// =====================================================================
__global__ __launch_bounds__(256)
void topk16(const ushort_t* __restrict__ S, int* __restrict__ outIdx)
{
  __shared__ uint_t cand[64];
  const int row = blockIdx.x, t = threadIdx.x;
  const int w = t >> 6, lane = t & 63;
  const ushort_t* sr = S + (size_t)row * NEz + (w << 10);
  uint_t p[16];
#pragma unroll
  for (int j = 0; j < 16; ++j) {
    const int c = (j << 6) + lane;
    const uint_t key = sr[c];
    const int gc = (w << 10) + c;
    p[j] = (key << 12) | (uint_t)(4095 - gc);
  }
  for (int it = 0; it < 16; ++it) {
    uint_t m = p[0];
#pragma unroll
    for (int j = 1; j < 16; ++j) m = umax_(m, p[j]);
#pragma unroll
    for (int d = 1; d < 64; d <<= 1)
      m = umax_(m, (uint_t)__shfl_xor((int)m, d, 64));
    if (lane == it) cand[(w << 4) + it] = m;
#pragma unroll
    for (int j = 0; j < 16; ++j) p[j] = (p[j] == m) ? 0u : p[j];
  }
  __syncthreads();
  if (t < 64) {
    uint_t mine = cand[t];
    for (int it = 0; it < 16; ++it) {
      uint_t m = mine;
#pragma unroll
      for (int d = 1; d < 64; d <<= 1)
        m = umax_(m, (uint_t)__shfl_xor((int)m, d, 64));
      if (t == it) outIdx[(size_t)row * 16 + it] = 4095 - (int)(m & 0xFFFu);
      mine = (mine == m) ? 0u : mine;
    }
  }
}

// =====================================================================
// Fused rescore + gather: one block per batch row.
// 1. Stage q row (3072 f32) into LDS (float4 coalesced).
// 2. 4 waves x 4 candidates: fp64 dot(q, keys[cand]) * rk, float4 key reads.
// 3. Thread 0 selects top-10 set (tie -> lower key id).
// 4. Whole block gathers the 10 key rows (L2-hot) -> ctx mean, bf16 or fp32.
// =====================================================================
template<bool BFOUT>
__global__ __launch_bounds__(256)
void rescore_gather(const float* __restrict__ qn, const float* __restrict__ keys,
                    const float* __restrict__ rk, const int* __restrict__ cand,
                    void* __restrict__ ctxOut)
{
  __shared__ float qs[Ez];
  __shared__ double sv[16];
  __shared__ int si[16];
  __shared__ int sel10[10];
  const int row = blockIdx.x, t = threadIdx.x;
  const int w = t >> 6, lane = t & 63;

  // stage q row
  {
    const float* qr = qn + (size_t)row * Ez;
#pragma unroll
    for (int i = 0; i < 3; ++i) {
      const int c = (t << 2) + (i << 10);
      *(float4*)&qs[c] = *(const float4*)&qr[c];
    }
  }
  __syncthreads();

  // rescore 16 candidates, 4 per wave
#pragma unroll
  for (int cc = 0; cc < 4; ++cc) {
    const int slot = w * 4 + cc;
    const int id = cand[(size_t)row * 16 + slot];
    const float* kr = keys + (size_t)id * Ez;
    double s = 0.0;
#pragma unroll
    for (int it = 0; it < 12; ++it) {
      const int c = (lane << 2) + (it << 8);
      float4 k4 = *(const float4*)&kr[c];
      float4 q4 = *(const float4*)&qs[c];
      s += (double)q4.x * (double)k4.x;
      s += (double)q4.y * (double)k4.y;
      s += (double)q4.z * (double)k4.z;
      s += (double)q4.w * (double)k4.w;
    }
#pragma unroll
    for (int d = 32; d; d >>= 1) s += __shfl_down(s, d, 64);
    if (lane == 0) { sv[slot] = s * (double)rk[id]; si[slot] = id; }
  }
  __syncthreads();

  // top-10 set selection
  if (t == 0) {
    for (int it = 0; it < 10; ++it) {
      int bj = 0; double bvv = sv[0]; int bi = si[0];
      for (int j = 1; j < 16; ++j) {
        const double v = sv[j]; const int i2 = si[j];
        if (v > bvv || (v == bvv && i2 < bi)) { bj = j; bvv = v; bi = i2; }
      }
      sel10[it] = bi;
      sv[bj] = -1e300;
    }
  }
  __syncthreads();

  int id[10];
#pragma unroll
  for (int j = 0; j < 10; ++j) id[j] = sel10[j];

  // gather + mean (rows are L2-hot from the rescore pass)
#pragma unroll
  for (int i = 0; i < 3; ++i) {
    const int c = (t << 2) + (i << 10);
    float4 a = {0.f, 0.f, 0.f, 0.f};
#pragma unroll
    for (int j = 0; j < 10; ++j) {
      float4 v = *(const float4*)&keys[(size_t)id[j] * Ez + c];
      a.x += v.x; a.y += v.y; a.z += v.z; a.w += v.w;
    }
    if (BFOUT) {
      ushort4 o;
      o.x = f2bf(a.x * 0.1f); o.y = f2bf(a.y * 0.1f);
      o.z = f2bf(a.z * 0.1f); o.w = f2bf(a.w * 0.1f);
      *(ushort4*)&((ushort_t*)ctxOut)[(size_t)row * Ez + c] = o;
    } else {
      float4 o;
      o.x = a.x * 0.1f; o.y = a.y * 0.1f; o.z = a.z * 0.1f; o.w = a.w * 0.1f;
      *(float4*)&((float*)ctxOut)[(size_t)row * Ez + c] = o;
    }
  }
}

// =====================================================================
// Router: 115 -> 64 -> 64 -> 4, clip, + gumbel, softmax, straight-through
// =====================================================================
__global__ __launch_bounds__(256)
void router_kernel(const float* __restrict__ state, const float* __restrict__ gn,
                   const float* __restrict__ w1, const float* __restrict__ b1,
                   const float* __restrict__ w2, const float* __restrict__ b2,
                   const float* __restrict__ w3, const float* __restrict__ b3,
                   float* __restrict__ outAlpha)
{
  const int row = blockIdx.x * 256 + threadIdx.x;
  const float* sr = state + (size_t)row * Sz;
  float h1[64];
#pragma unroll
  for (int j = 0; j < 64; ++j) h1[j] = b1[j];
  for (int k = 0; k < Sz; ++k) {
    const float a = sr[k];
    const float* wr = w1 + (size_t)k * 64;
#pragma unroll
    for (int j = 0; j < 64; ++j) h1[j] = fmaf(a, wr[j], h1[j]);
  }
#pragma unroll
  for (int j = 0; j < 64; ++j) h1[j] = fmaxf(h1[j], 0.f);
  float h2[64];
#pragma unroll
  for (int j = 0; j < 64; ++j) h2[j] = b2[j];
#pragma unroll
  for (int k = 0; k < 64; ++k) {
    const float a = h1[k];
    const float* wr = w2 + (size_t)k * 64;
#pragma unroll
    for (int j = 0; j < 64; ++j) h2[j] = fmaf(a, wr[j], h2[j]);
  }
#pragma unroll
  for (int j = 0; j < 64; ++j) h2[j] = fmaxf(h2[j], 0.f);
  float z[4];
#pragma unroll
  for (int a = 0; a < 4; ++a) {
    float s = b3[a];
#pragma unroll
    for (int k = 0; k < 64; ++k) s = fmaf(h2[k], w3[k * 4 + a], s);
    s = fminf(fmaxf(s, -20.f), 20.f);
    z[a] = s + gn[(size_t)row * 4 + a];   // TAU = 1
  }
  float mz = z[0];
#pragma unroll
  for (int a = 1; a < 4; ++a) mz = fmaxf(mz, z[a]);
  float e[4]; float se = 0.f;
#pragma unroll
  for (int a = 0; a < 4; ++a) { e[a] = expf(z[a] - mz); se += e[a]; }
  const float inv = 1.f / se;
  float y[4];
#pragma unroll
  for (int a = 0; a < 4; ++a) y[a] = e[a] * inv;
  int am = 0;
#pragma unroll
  for (int a = 1; a < 4; ++a) if (y[a] > y[am]) am = a;
#pragma unroll
  for (int a = 0; a < 4; ++a) {
    const float hard = (a == am) ? 1.f : 0.f;
    outAlpha[(size_t)row * 4 + a] = y[a] + (hard - y[a]);
  }
}

// critic head
__global__ __launch_bounds__(256)
void critic_head(const float* __restrict__ c2, const float* __restrict__ w3,
                 const float* __restrict__ b3, float* __restrict__ outv)
{
  const int row = blockIdx.x * 256 + threadIdx.x;
  const float* xr = c2 + (size_t)row * 256;
  float s = b3[0];
  for (int k = 0; k < 256; ++k) s = fmaf(xr[k], w3[k], s);
  outv[row] = s;
}

// all-4 actor heads fused
struct HeadP { const float* w3[4]; const float* b3[4]; };

__global__ __launch_bounds__(256)
void actor_head4(const float* __restrict__ x2g, HeadP p,
                 const float* __restrict__ alpha, float* __restrict__ outL)
{
  __shared__ float wsm[4][128 * 23];
  __shared__ float bs[4][23];
  const int t = threadIdx.x;
#pragma unroll
  for (int a = 0; a < 4; ++a) {
    for (int i = t; i < 128 * 23; i += 256) wsm[a][i] = p.w3[a][i];
    if (t < 23) bs[a][t] = p.b3[a][t];
  }
  __syncthreads();
  const int row = blockIdx.x * 64 + (t >> 2);
  const int cg = t & 3;
  float sum[6] = {0.f, 0.f, 0.f, 0.f, 0.f, 0.f};
#pragma unroll
  for (int a = 0; a < 4; ++a) {
    const float al = alpha[(size_t)row * 4 + a];
    const float* xr = x2g + (size_t)a * Bz * 128 + (size_t)row * 128;
    float acc[6] = {0.f, 0.f, 0.f, 0.f, 0.f, 0.f};
    for (int kk = 0; kk < 128; ++kk) {
      const float xa = xr[kk];
#pragma unroll
      for (int j = 0; j < 6; ++j) {
        const int col = cg + 4 * j;
        if (col < 23) acc[j] = fmaf(xa, wsm[a][kk * 23 + col], acc[j]);
      }
    }
#pragma unroll
    for (int j = 0; j < 6; ++j) {
      const int col = cg + 4 * j;
      if (col < 23) sum[j] += al * (acc[j] + bs[a][col]);
    }
  }
#pragma unroll
  for (int j = 0; j < 6; ++j) {
    const int col = cg + 4 * j;
    if (col < 23) outL[(size_t)row * 23 + col] = sum[j];
  }
}

// =====================================================================
extern "C" void kernel_launch(void* const* d_in, const int* in_sizes, int n_in,
                              void* d_out, int out_size, void* d_ws, size_t ws_size,
                              hipStream_t stream)
{
  const float* state  = (const float*)d_in[0];
  const float* gumbel = (const float*)d_in[1];
  const float* keys   = (const float*)d_in[2];
  const float* se_w1 = (const float*)d_in[3];
  const float* se_b1 = (const float*)d_in[4];
  const float* se_w2 = (const float*)d_in[5];
  const float* se_b2 = (const float*)d_in[6];
  const float* se_w3 = (const float*)d_in[7];
  const float* se_b3 = (const float*)d_in[8];
  const float* se_g  = (const float*)d_in[9];
  const float* se_be = (const float*)d_in[10];
  const float* cc_w1 = (const float*)d_in[11];
  const float* cc_b1 = (const float*)d_in[12];
  const float* cc_w2 = (const float*)d_in[13];
  const float* cc_b2 = (const float*)d_in[14];
  const float* cc_g  = (const float*)d_in[15];
  const float* cc_be = (const float*)d_in[16];
  const float* r_w1 = (const float*)d_in[57];
  const float* r_b1 = (const float*)d_in[58];
  const float* r_w2 = (const float*)d_in[59];
  const float* r_b2 = (const float*)d_in[60];
  const float* r_w3 = (const float*)d_in[61];
  const float* r_b3 = (const float*)d_in[62];
  const float* c_w1 = (const float*)d_in[63];
  const float* c_b1 = (const float*)d_in[64];
  const float* c_w2 = (const float*)d_in[65];
  const float* c_b2 = (const float*)d_in[66];
  const float* c_w3 = (const float*)d_in[67];
  const float* c_b3 = (const float*)d_in[68];

  // ---- workspace layout ----
  float* wsf = (float*)d_ws;
  const size_t qF = (size_t)Bz * Ez;          // 25,165,824 floats
  const size_t uF = (size_t)16777216;         // union region, floats
  float* q = wsf;
  float* U = wsf + qF;
  // U internal (time-multiplexed):
  float* sA  = U;                              // encoder ping   [0, 4.19M)
  float* sB  = U + 4194304;                    // encoder pong   [4.19M, 8.39M)
  ushort_t* sBh  = (ushort_t*)(U + 8388608);   // bf16 hi of sB
  ushort_t* sBl  = (ushort_t*)(U + 10485760);  // bf16 lo of sB
  ushort_t* w3hT = (ushort_t*)(U + 12582912);  // se_w3^T hi (3072x512)
  ushort_t* w3lT = (ushort_t*)(U + 14155776);  // se_w3^T lo
  ushort_t* scoresU = (ushort_t*)U;            // 8192x4096 u16 keys (whole U)
  float* shr = U;                              // 8192x128
  float* x1g = U + 1 * 1048576;                // 4 x 8192x128
  float* x2g = U + 5 * 1048576;                // 4 x 8192x128
  float* cch = U + 9 * 1048576;                // 8192x512 (dies before cr1)
  float* cr1 = U + 9 * 1048576;                // 8192x256
  float* cr2 = U + 11 * 1048576;               // 8192x256
  // fast-path bf16 buffers after U:
  ushort_t* qbf  = (ushort_t*)(wsf + qF + uF);     // 8192x3072
  ushort_t* knbf = qbf + qF;                       // 4096x3072
  ushort_t* w1T  = knbf + (size_t)NEz * Ez;        // 512x3072
  const size_t bfHalves = qF + (size_t)NEz * Ez + (size_t)512 * Ez;
  const size_t baseBytes = (qF + uF) * sizeof(float);
  const size_t tailBytes = 4096 * 4 + (size_t)Bz * 16 * 4;
  const bool fast = ws_size >= baseBytes + bfHalves * 2 + tailBytes;
  float* tailF = (float*)((char*)d_ws + (fast ? baseBytes + bfHalves * 2 : baseBytes));
  float* rk  = tailF;
  int* cand  = (int*)(tailF + 4096);
  ushort_t* ctxb = (ushort_t*)q;               // bf16 ctx overlays dead q tail

  float* outL = (float*)d_out;                 // 8192*23
  float* outA = outL + (size_t)Bz * 23;        // 8192*4
  float* outV = outA + (size_t)Bz * 4;         // 8192*1

  const dim3 blk(256);

  // --- state encoder ---
  gemm128<true, true><<<dim3(4, 64), blk, 0, stream>>>(state, se_w1, se_b1, sA, 512, 115);
  gemm128<true, true><<<dim3(4, 64), blk, 0, stream>>>(sA,    se_w2, se_b2, sB, 512, 512);
  if (fast) {
    // se_w3 via bf16x3 split-precision MFMA (fp32-accurate)
    split_bf<<<dim3(4096), blk, 0, stream>>>(sB, sBh, sBl);
    w3_transpose_split<<<dim3(8, 48), blk, 0, stream>>>(se_w3, w3hT, w3lT);
    mfma3_bt<<<dim3(24, 64), blk, 0, stream>>>(sBh, sBl, w3hT, w3lT, se_b3, q, 3072, 512);
    ln_l2_q<true><<<dim3(Bz), blk, 0, stream>>>(q, se_g, se_be, qbf);
    keys_norm_cvt<<<dim3(NEz), blk, 0, stream>>>(keys, rk, knbf);
    cvt_w1t<<<dim3(6144), blk, 0, stream>>>(cc_w1, w1T);
    mfma_bt<0><<<dim3(32, 64), blk, 0, stream>>>(qbf, knbf, nullptr, scoresU, NEz, Ez);
  } else {
    gemm128<false, true><<<dim3(24, 64), blk, 0, stream>>>(sB, se_w3, se_b3, q, 3072, 512);
    ln_l2_q<false><<<dim3(Bz), blk, 0, stream>>>(q, se_g, se_be, nullptr);
    keynorm<<<dim3(NEz), blk, 0, stream>>>(keys, rk);
    gemm_scores<<<dim3(32, 64), blk, 0, stream>>>(q, keys, rk, scoresU);
  }

  // --- top-16 screen, fused fp64 rescore + top-10 set + context gather ---
  topk16<<<dim3(Bz), blk, 0, stream>>>(scoresU, cand);

  // --- context + compressor ---
  if (fast) {
    rescore_gather<true><<<dim3(Bz), blk, 0, stream>>>(q, keys, rk, cand, ctxb);
    mfma_bt<1><<<dim3(4, 64), blk, 0, stream>>>(ctxb, w1T, cc_b1, cch, 512, Ez);
  } else {
    rescore_gather<false><<<dim3(Bz), blk, 0, stream>>>(q, keys, rk, cand, q);
    gemm128<true, true><<<dim3(4, 64), blk, 0, stream>>>(q, cc_w1, cc_b1, cch, 512, Ez);
  }
  {
    LN4 pcc = {};
    pcc.W[0] = cc_w2; pcc.b[0] = cc_b2; pcc.g[0] = cc_g; pcc.be[0] = cc_be;
    gemm_ln4<false, false><<<dim3(128, 1), blk, 0, stream>>>(cch, 0, 512, nullptr, pcc,
                                                             shr, 0);
  }

  // --- critic ---
  gemm128<true, true><<<dim3(2, 64), blk, 0, stream>>>(state, c_w1, c_b1, cr1, 256, 115);
  gemm128<true, true><<<dim3(2, 64), blk, 0, stream>>>(cr1, c_w2, c_b2, cr2, 256, 256);
  critic_head<<<dim3(32), blk, 0, stream>>>(cr2, c_w3, c_b3, outV);

  // --- router ---
  router_kernel<<<dim3(32), blk, 0, stream>>>(state, gumbel, r_w1, r_b1, r_w2, r_b2,
                                              r_w3, r_b3, outA);

  // --- actors (batched over blockIdx.y) ---
  {
    LN4 p1 = {}, p2 = {};
    HeadP ph = {};
    const int eoffs[4] = {0, 20, 40, 45};
    const int elens[4] = {50, 20, 10, 15};
    for (int a = 0; a < 4; ++a) {
      const int base = 17 + 10 * a;
      p1.W[a]  = (const float*)d_in[base + 0];
      p1.b[a]  = (const float*)d_in[base + 1];
      p1.g[a]  = (const float*)d_in[base + 2];
      p1.be[a] = (const float*)d_in[base + 3];
      p1.eoff[a] = eoffs[a]; p1.elen[a] = elens[a];
      p2.W[a]  = (const float*)d_in[base + 4];
      p2.b[a]  = (const float*)d_in[base + 5];
      p2.g[a]  = (const float*)d_in[base + 6];
      p2.be[a] = (const float*)d_in[base + 7];
      ph.w3[a] = (const float*)d_in[base + 8];
      ph.b3[a] = (const float*)d_in[base + 9];
    }
    gemm_ln4<true, true ><<<dim3(128, 4), blk, 0, stream>>>(shr, 0, 128, state, p1,
                                                            x1g, (size_t)Bz * 128);
    gemm_ln4<true, false><<<dim3(128, 4), blk, 0, stream>>>(x1g, (size_t)Bz * 128, 128,
                                                            nullptr, p2,
                                                            x2g, (size_t)Bz * 128);
    actor_head4<<<dim3(128), blk, 0, stream>>>(x2g, ph, outA, outL);
  }
}

// Round 6
// 1406.434 us; speedup vs baseline: 3.1438x; 1.0217x over previous
//
#include <hip/hip_runtime.h>

// Problem constants (match reference)
constexpr int Bz = 8192;   // batch
constexpr int Sz = 115;    // state dim
constexpr int Ez = 3072;   // embedding dim
constexpr int NEz = 4096;  // num keys
// C=128, A=23, K=10, TAU=1, EPS=1e-5

typedef __attribute__((ext_vector_type(8))) short short8;
typedef __attribute__((ext_vector_type(4))) float floatx4;
typedef unsigned short ushort_t;
typedef unsigned int uint_t;

__device__ __forceinline__ ushort_t f2bf(float f) {
  uint_t u = __float_as_uint(f);
  uint_t r = (u + 0x7FFFu + ((u >> 16) & 1u)) >> 16;   // RNE
  return (ushort_t)r;
}
__device__ __forceinline__ float bf2f(ushort_t b) {
  uint_t u = ((uint_t)b) << 16;
  return __uint_as_float(u);
}
// fp32 -> fp16 -> order-preserving u16 key (monotone total order)
__device__ __forceinline__ ushort_t f2key(float v) {
  _Float16 h = (_Float16)v;
  ushort_t b = __builtin_bit_cast(ushort_t, h);
  return b ^ ((b & 0x8000u) ? 0xFFFFu : 0x8000u);
}
__device__ __forceinline__ uint_t umax_(uint_t a, uint_t b) { return a > b ? a : b; }

// async global->LDS, 16 B per lane; lds dest = wave-uniform base + lane*16
__device__ __forceinline__ void gload16(const ushort_t* g, ushort_t* l) {
  __builtin_amdgcn_global_load_lds(
      (__attribute__((address_space(1))) const void*)g,
      (__attribute__((address_space(3))) void*)l, 16, 0, 0);
}

// =====================================================================
// Generic fp32 tiled GEMM (fallback + cc fallback): C = act(A@B + bias)
// =====================================================================
template<bool RELU, bool BIAS>
__global__ __launch_bounds__(256)
void gemm128(const float* __restrict__ A, const float* __restrict__ Bm,
             const float* __restrict__ bias, float* __restrict__ C,
             int N, int Kd)
{
  __shared__ float As[16][132];
  __shared__ float Bs[16][132];
  const int t  = threadIdx.x;
  const int tx = t & 15, ty = t >> 4;
  const int row0 = blockIdx.y * 128;
  const int col0 = blockIdx.x * 128;
  const int ar = t >> 2, ac = (t & 3) * 4;
  const int bk = t >> 5, bc = (t & 31) * 4;
  const bool a4 = (Kd & 3) == 0;

  float acc[8][8];
#pragma unroll
  for (int i = 0; i < 8; ++i)
#pragma unroll
    for (int j = 0; j < 8; ++j) acc[i][j] = 0.f;

  for (int k0 = 0; k0 < Kd; k0 += 16) {
    const bool fullA = (k0 + 16 <= Kd) && a4;
    {
      const float* ap = A + (size_t)(row0 + ar) * Kd + k0 + ac;
      if (fullA) {
        float4 v0 = *(const float4*)ap;
        float4 v1 = *(const float4*)(ap + (size_t)64 * Kd);
        As[ac + 0][ar] = v0.x; As[ac + 1][ar] = v0.y;
        As[ac + 2][ar] = v0.z; As[ac + 3][ar] = v0.w;
        As[ac + 0][ar + 64] = v1.x; As[ac + 1][ar + 64] = v1.y;
        As[ac + 2][ar + 64] = v1.z; As[ac + 3][ar + 64] = v1.w;
      } else {
#pragma unroll
        for (int e = 0; e < 4; ++e) {
          const int k = k0 + ac + e;
          float v0 = 0.f, v1 = 0.f;
          if (k < Kd) { v0 = ap[e]; v1 = ap[e + (size_t)64 * Kd]; }
          As[ac + e][ar] = v0; As[ac + e][ar + 64] = v1;
        }
      }
    }
    {
      const float* bp = Bm + (size_t)(k0 + bk) * N + col0 + bc;
      if (k0 + 16 <= Kd) {
        *(float4*)&Bs[bk][bc]     = *(const float4*)bp;
        *(float4*)&Bs[bk + 8][bc] = *(const float4*)(bp + (size_t)8 * N);
      } else {
        float4 z; z.x = z.y = z.z = z.w = 0.f;
        *(float4*)&Bs[bk][bc]     = (k0 + bk     < Kd) ? *(const float4*)bp : z;
        *(float4*)&Bs[bk + 8][bc] = (k0 + bk + 8 < Kd) ? *(const float4*)(bp + (size_t)8 * N) : z;
      }
    }
    __syncthreads();
#pragma unroll
    for (int kk = 0; kk < 16; ++kk) {
      float a[8], b[8];
      *(float4*)&a[0] = *(const float4*)&As[kk][ty * 4];
      *(float4*)&a[4] = *(const float4*)&As[kk][64 + ty * 4];
      *(float4*)&b[0] = *(const float4*)&Bs[kk][tx * 4];
      *(float4*)&b[4] = *(const float4*)&Bs[kk][64 + tx * 4];
#pragma unroll
      for (int i = 0; i < 8; ++i)
#pragma unroll
        for (int j = 0; j < 8; ++j)
          acc[i][j] = fmaf(a[i], b[j], acc[i][j]);
    }
    __syncthreads();
  }

  float bv[8];
#pragma unroll
  for (int j = 0; j < 8; ++j) bv[j] = 0.f;
  if (BIAS) {
    *(float4*)&bv[0] = *(const float4*)&bias[col0 + tx * 4];
    *(float4*)&bv[4] = *(const float4*)&bias[col0 + 64 + tx * 4];
  }
#pragma unroll
  for (int i = 0; i < 8; ++i) {
    const int r = row0 + ((i < 4) ? (ty * 4 + i) : (64 + ty * 4 + i - 4));
    float o[8];
#pragma unroll
    for (int j = 0; j < 8; ++j) {
      o[j] = acc[i][j] + bv[j];
      if (RELU) o[j] = fmaxf(o[j], 0.f);
    }
    *(float4*)&C[(size_t)r * N + col0 + tx * 4]      = *(float4*)&o[0];
    *(float4*)&C[(size_t)r * N + col0 + 64 + tx * 4] = *(float4*)&o[4];
  }
}

// =====================================================================
// Dual-part fp32 GEMM+ReLU+bias: two independent GEMMs in one launch.
// Part selected by blockIdx.x. Optional bf16 hi/lo split outputs (Ch/Cl).
// =====================================================================
struct GPart {
  const float* A; const float* Bm; const float* bias;
  float* C; ushort_t* Ch; ushort_t* Cl;
  int N; int Kd; int nbx;
};

__global__ __launch_bounds__(256)
void gemm128_dual(GPart g0, GPart g1)
{
  __shared__ float As[16][132];
  __shared__ float Bs[16][132];
  const int t  = threadIdx.x;
  const int tx = t & 15, ty = t >> 4;
  const bool p0 = (int)blockIdx.x < g0.nbx;
  GPart g = p0 ? g0 : g1;
  const int bx = p0 ? blockIdx.x : (blockIdx.x - g0.nbx);
  const int row0 = blockIdx.y * 128;
  const int col0 = bx * 128;
  const int Kd = g.Kd, N = g.N;
  const int ar = t >> 2, ac = (t & 3) * 4;
  const int bk = t >> 5, bc = (t & 31) * 4;
  const bool a4 = (Kd & 3) == 0;

  float acc[8][8];
#pragma unroll
  for (int i = 0; i < 8; ++i)
#pragma unroll
    for (int j = 0; j < 8; ++j) acc[i][j] = 0.f;

  for (int k0 = 0; k0 < Kd; k0 += 16) {
    const bool fullA = (k0 + 16 <= Kd) && a4;
    {
      const float* ap = g.A + (size_t)(row0 + ar) * Kd + k0 + ac;
      if (fullA) {
        float4 v0 = *(const float4*)ap;
        float4 v1 = *(const float4*)(ap + (size_t)64 * Kd);
        As[ac + 0][ar] = v0.x; As[ac + 1][ar] = v0.y;
        As[ac + 2][ar] = v0.z; As[ac + 3][ar] = v0.w;
        As[ac + 0][ar + 64] = v1.x; As[ac + 1][ar + 64] = v1.y;
        As[ac + 2][ar + 64] = v1.z; As[ac + 3][ar + 64] = v1.w;
      } else {
#pragma unroll
        for (int e = 0; e < 4; ++e) {
          const int k = k0 + ac + e;
          float v0 = 0.f, v1 = 0.f;
          if (k < Kd) { v0 = ap[e]; v1 = ap[e + (size_t)64 * Kd]; }
          As[ac + e][ar] = v0; As[ac + e][ar + 64] = v1;
        }
      }
    }
    {
      const float* bp = g.Bm + (size_t)(k0 + bk) * N + col0 + bc;
      if (k0 + 16 <= Kd) {
        *(float4*)&Bs[bk][bc]     = *(const float4*)bp;
        *(float4*)&Bs[bk + 8][bc] = *(const float4*)(bp + (size_t)8 * N);
      } else {
        float4 z; z.x = z.y = z.z = z.w = 0.f;
        *(float4*)&Bs[bk][bc]     = (k0 + bk     < Kd) ? *(const float4*)bp : z;
        *(float4*)&Bs[bk + 8][bc] = (k0 + bk + 8 < Kd) ? *(const float4*)(bp + (size_t)8 * N) : z;
      }
    }
    __syncthreads();
#pragma unroll
    for (int kk = 0; kk < 16; ++kk) {
      float a[8], b[8];
      *(float4*)&a[0] = *(const float4*)&As[kk][ty * 4];
      *(float4*)&a[4] = *(const float4*)&As[kk][64 + ty * 4];
      *(float4*)&b[0] = *(const float4*)&Bs[kk][tx * 4];
      *(float4*)&b[4] = *(const float4*)&Bs[kk][64 + tx * 4];
#pragma unroll
      for (int i = 0; i < 8; ++i)
#pragma unroll
        for (int j = 0; j < 8; ++j)
          acc[i][j] = fmaf(a[i], b[j], acc[i][j]);
    }
    __syncthreads();
  }

  float bv[8];
  *(float4*)&bv[0] = *(const float4*)&g.bias[col0 + tx * 4];
  *(float4*)&bv[4] = *(const float4*)&g.bias[col0 + 64 + tx * 4];
#pragma unroll
  for (int i = 0; i < 8; ++i) {
    const int r = row0 + ((i < 4) ? (ty * 4 + i) : (64 + ty * 4 + i - 4));
    float o[8];
#pragma unroll
    for (int j = 0; j < 8; ++j) o[j] = fmaxf(acc[i][j] + bv[j], 0.f);
    const size_t i0 = (size_t)r * N + col0 + tx * 4;
    const size_t i1 = i0 + 64;
    *(float4*)&g.C[i0] = *(float4*)&o[0];
    *(float4*)&g.C[i1] = *(float4*)&o[4];
    if (g.Ch) {
      ushort4 h0, l0, h1, l1;
      h0.x = f2bf(o[0]); l0.x = f2bf(o[0] - bf2f(h0.x));
      h0.y = f2bf(o[1]); l0.y = f2bf(o[1] - bf2f(h0.y));
      h0.z = f2bf(o[2]); l0.z = f2bf(o[2] - bf2f(h0.z));
      h0.w = f2bf(o[3]); l0.w = f2bf(o[3] - bf2f(h0.w));
      h1.x = f2bf(o[4]); l1.x = f2bf(o[4] - bf2f(h1.x));
      h1.y = f2bf(o[5]); l1.y = f2bf(o[5] - bf2f(h1.y));
      h1.z = f2bf(o[6]); l1.z = f2bf(o[6] - bf2f(h1.z));
      h1.w = f2bf(o[7]); l1.w = f2bf(o[7] - bf2f(h1.w));
      *(ushort4*)&g.Ch[i0] = h0; *(ushort4*)&g.Cl[i0] = l0;
      *(ushort4*)&g.Ch[i1] = h1; *(ushort4*)&g.Cl[i1] = l1;
    }
  }
}

// =====================================================================
// bf16 MFMA GEMM, A(M x K) @ B(N x K)^T, both row-major bf16 (K-contig).
// EPI=0: u16 score keys, XCD-swizzled linear grid (2048 blocks).
// EPI=1: fp32 + bias + ReLU, 2D grid.
// =====================================================================
template<int EPI>
__global__ __launch_bounds__(256)
void mfma_bt(const ushort_t* __restrict__ A, const ushort_t* __restrict__ B,
             const float* __restrict__ bias, void* __restrict__ Cout,
             int N, int Kd)
{
  __shared__ ushort_t Al[128 * 32];
  __shared__ ushort_t Bl[128 * 32];
  const int t = threadIdx.x;
  const int wid = t >> 6, lane = t & 63;
  const int wr = wid >> 1, wc = wid & 1;
  int row0, col0;
  if (EPI == 0) {
    // XCD-aware swizzle: same q row-block stays on one XCD across col-blocks
    const int L = blockIdx.x;
    row0 = ((L & 7) + (L >> 8) * 8) << 7;
    col0 = ((L >> 3) & 31) << 7;
  } else {
    row0 = blockIdx.y << 7;
    col0 = blockIdx.x << 7;
  }
  const int srow = lane >> 2;
  const int scol = (lane & 3) * 8;

  const ushort_t* ga0 = A + (size_t)(row0 + wid * 16 + srow) * Kd + scol;
  const ushort_t* ga1 = A + (size_t)(row0 + (wid + 4) * 16 + srow) * Kd + scol;
  const ushort_t* gb0 = B + (size_t)(col0 + wid * 16 + srow) * Kd + scol;
  const ushort_t* gb1 = B + (size_t)(col0 + (wid + 4) * 16 + srow) * Kd + scol;
  ushort_t* la0 = &Al[(wid * 16) * 32];
  ushort_t* la1 = &Al[((wid + 4) * 16) * 32];
  ushort_t* lb0 = &Bl[(wid * 16) * 32];
  ushort_t* lb1 = &Bl[((wid + 4) * 16) * 32];

  const int mr = lane & 15, qd = lane >> 4;

  floatx4 acc[4][4];
#pragma unroll
  for (int i = 0; i < 4; ++i)
#pragma unroll
    for (int j = 0; j < 4; ++j) acc[i][j] = (floatx4){0.f, 0.f, 0.f, 0.f};

  for (int kb = 0; kb < Kd; kb += 32) {
    gload16(ga0 + kb, la0);
    gload16(ga1 + kb, la1);
    gload16(gb0 + kb, lb0);
    gload16(gb1 + kb, lb1);
    __syncthreads();
    short8 aF[4], bF[4];
#pragma unroll
    for (int i = 0; i < 4; ++i)
      aF[i] = *(const short8*)&Al[(wr * 64 + i * 16 + mr) * 32 + qd * 8];
#pragma unroll
    for (int j = 0; j < 4; ++j)
      bF[j] = *(const short8*)&Bl[(wc * 64 + j * 16 + mr) * 32 + qd * 8];
#pragma unroll
    for (int i = 0; i < 4; ++i)
#pragma unroll
      for (int j = 0; j < 4; ++j)
        acc[i][j] = __builtin_amdgcn_mfma_f32_16x16x32_bf16(aF[i], bF[j], acc[i][j], 0, 0, 0);
    __syncthreads();
  }

  // C/D layout: col = lane&15, row = (lane>>4)*4 + reg
#pragma unroll
  for (int i = 0; i < 4; ++i) {
#pragma unroll
    for (int j = 0; j < 4; ++j) {
      const int col = col0 + wc * 64 + j * 16 + mr;
#pragma unroll
      for (int r = 0; r < 4; ++r) {
        const int row = row0 + wr * 64 + i * 16 + qd * 4 + r;
        if (EPI == 0) {
          ((ushort_t*)Cout)[(size_t)row * N + col] = f2key(acc[i][j][r]);
        } else {
          float v = acc[i][j][r] + bias[col];
          ((float*)Cout)[(size_t)row * N + col] = fmaxf(v, 0.f);
        }
      }
    }
  }
}

// =====================================================================
// bf16x3 split-precision MFMA GEMM (fp32-accurate): C = A@B^T + bias
// =====================================================================
__global__ __launch_bounds__(256)
void mfma3_bt(const ushort_t* __restrict__ Ah, const ushort_t* __restrict__ Alo,
              const ushort_t* __restrict__ Bh, const ushort_t* __restrict__ Blo,
              const float* __restrict__ bias, float* __restrict__ Cout,
              int N, int Kd)
{
  __shared__ ushort_t AhL[128 * 32];
  __shared__ ushort_t AlL[128 * 32];
  __shared__ ushort_t BhL[128 * 32];
  __shared__ ushort_t BlL[128 * 32];
  const int t = threadIdx.x;
  const int wid = t >> 6, lane = t & 63;
  const int wr = wid >> 1, wc = wid & 1;
  const int row0 = blockIdx.y * 128;
  const int col0 = blockIdx.x * 128;
  const int srow = lane >> 2;
  const int scol = (lane & 3) * 8;

  const size_t aoff0 = (size_t)(row0 + wid * 16 + srow) * Kd + scol;
  const size_t aoff1 = (size_t)(row0 + (wid + 4) * 16 + srow) * Kd + scol;
  const size_t boff0 = (size_t)(col0 + wid * 16 + srow) * Kd + scol;
  const size_t boff1 = (size_t)(col0 + (wid + 4) * 16 + srow) * Kd + scol;
  const int l0 = (wid * 16) * 32;
  const int l1 = ((wid + 4) * 16) * 32;

  const int mr = lane & 15, qd = lane >> 4;

  floatx4 acc[4][4];
#pragma unroll
  for (int i = 0; i < 4; ++i)
#pragma unroll
    for (int j = 0; j < 4; ++j) acc[i][j] = (floatx4){0.f, 0.f, 0.f, 0.f};

  for (int kb = 0; kb < Kd; kb += 32) {
    gload16(Ah + aoff0 + kb, &AhL[l0]);
    gload16(Ah + aoff1 + kb, &AhL[l1]);
    gload16(Alo + aoff0 + kb, &AlL[l0]);
    gload16(Alo + aoff1 + kb, &AlL[l1]);
    gload16(Bh + boff0 + kb, &BhL[l0]);
    gload16(Bh + boff1 + kb, &BhL[l1]);
    gload16(Blo + boff0 + kb, &BlL[l0]);
    gload16(Blo + boff1 + kb, &BlL[l1]);
    __syncthreads();
    short8 ahF[4], alF[4], bhF[4], blF[4];
#pragma unroll
    for (int i = 0; i < 4; ++i) {
      const int o = (wr * 64 + i * 16 + mr) * 32 + qd * 8;
      ahF[i] = *(const short8*)&AhL[o];
      alF[i] = *(const short8*)&AlL[o];
    }
#pragma unroll
    for (int j = 0; j < 4; ++j) {
      const int o = (wc * 64 + j * 16 + mr) * 32 + qd * 8;
      bhF[j] = *(const short8*)&BhL[o];
      blF[j] = *(const short8*)&BlL[o];
    }
#pragma unroll
    for (int i = 0; i < 4; ++i)
#pragma unroll
      for (int j = 0; j < 4; ++j) {
        acc[i][j] = __builtin_amdgcn_mfma_f32_16x16x32_bf16(alF[i], bhF[j], acc[i][j], 0, 0, 0);
        acc[i][j] = __builtin_amdgcn_mfma_f32_16x16x32_bf16(ahF[i], blF[j], acc[i][j], 0, 0, 0);
        acc[i][j] = __builtin_amdgcn_mfma_f32_16x16x32_bf16(ahF[i], bhF[j], acc[i][j], 0, 0, 0);
      }
    __syncthreads();
  }

#pragma unroll
  for (int i = 0; i < 4; ++i) {
#pragma unroll
    for (int j = 0; j < 4; ++j) {
      const int col = col0 + wc * 64 + j * 16 + mr;
#pragma unroll
      for (int r = 0; r < 4; ++r) {
        const int row = row0 + wr * 64 + i * 16 + qd * 4 + r;
        Cout[(size_t)row * N + col] = acc[i][j][r] + bias[col];
      }
    }
  }
}

// =====================================================================
// fp32 scores GEMM (fallback path only) -> u16 score keys
// =====================================================================
__global__ __launch_bounds__(256)
void gemm_scores(const float* __restrict__ A, const float* __restrict__ Bm,
                 const float* __restrict__ rk, ushort_t* __restrict__ S)
{
  __shared__ float As[16][132];
  __shared__ float Bs[16][132];
  const int t  = threadIdx.x;
  const int tx = t & 15, ty = t >> 4;
  const int row0 = blockIdx.y * 128;
  const int col0 = blockIdx.x * 128;
  const int ar = t >> 2, ac = (t & 3) * 4;
  const int Kd = Ez;

  float acc[8][8];
#pragma unroll
  for (int i = 0; i < 8; ++i)
#pragma unroll
    for (int j = 0; j < 8; ++j) acc[i][j] = 0.f;

  for (int k0 = 0; k0 < Kd; k0 += 16) {
    {
      const float* ap = A + (size_t)(row0 + ar) * Kd + k0 + ac;
      float4 v0 = *(const float4*)ap;
      float4 v1 = *(const float4*)(ap + (size_t)64 * Kd);
      As[ac + 0][ar] = v0.x; As[ac + 1][ar] = v0.y;
      As[ac + 2][ar] = v0.z; As[ac + 3][ar] = v0.w;
      As[ac + 0][ar + 64] = v1.x; As[ac + 1][ar + 64] = v1.y;
      As[ac + 2][ar + 64] = v1.z; As[ac + 3][ar + 64] = v1.w;
    }
    {
      const float* bp = Bm + (size_t)(col0 + ar) * Kd + k0 + ac;
      float4 v0 = *(const float4*)bp;
      float4 v1 = *(const float4*)(bp + (size_t)64 * Kd);
      Bs[ac + 0][ar] = v0.x; Bs[ac + 1][ar] = v0.y;
      Bs[ac + 2][ar] = v0.z; Bs[ac + 3][ar] = v0.w;
      Bs[ac + 0][ar + 64] = v1.x; Bs[ac + 1][ar + 64] = v1.y;
      Bs[ac + 2][ar + 64] = v1.z; Bs[ac + 3][ar + 64] = v1.w;
    }
    __syncthreads();
#pragma unroll
    for (int kk = 0; kk < 16; ++kk) {
      float a[8], b[8];
      *(float4*)&a[0] = *(const float4*)&As[kk][ty * 4];
      *(float4*)&a[4] = *(const float4*)&As[kk][64 + ty * 4];
      *(float4*)&b[0] = *(const float4*)&Bs[kk][tx * 4];
      *(float4*)&b[4] = *(const float4*)&Bs[kk][64 + tx * 4];
#pragma unroll
      for (int i = 0; i < 8; ++i)
#pragma unroll
        for (int j = 0; j < 8; ++j)
          acc[i][j] = fmaf(a[i], b[j], acc[i][j]);
    }
    __syncthreads();
  }

  float rk0[8];
  *(float4*)&rk0[0] = *(const float4*)&rk[col0 + tx * 4];
  *(float4*)&rk0[4] = *(const float4*)&rk[col0 + 64 + tx * 4];
#pragma unroll
  for (int i = 0; i < 8; ++i) {
    const int r = row0 + ((i < 4) ? (ty * 4 + i) : (64 + ty * 4 + i - 4));
    ushort4 h0, h1;
    h0.x = f2key(acc[i][0] * rk0[0]); h0.y = f2key(acc[i][1] * rk0[1]);
    h0.z = f2key(acc[i][2] * rk0[2]); h0.w = f2key(acc[i][3] * rk0[3]);
    h1.x = f2key(acc[i][4] * rk0[4]); h1.y = f2key(acc[i][5] * rk0[5]);
    h1.z = f2key(acc[i][6] * rk0[6]); h1.w = f2key(acc[i][7] * rk0[7]);
    *(ushort4*)&S[(size_t)r * NEz + col0 + tx * 4]      = h0;
    *(ushort4*)&S[(size_t)r * NEz + col0 + 64 + tx * 4] = h1;
  }
}

// =====================================================================
// Batched (4-actor) fused GEMM(N=128) + LayerNorm (+ReLU).
// =====================================================================
struct LN4 {
  const float* W[4]; const float* b[4]; const float* g[4]; const float* be[4];
  int eoff[4]; int elen[4];
};

template<bool RELU, bool HASEXT>
__global__ __launch_bounds__(256)
void gemm_ln4(const float* __restrict__ A1base, size_t a1stride, int K1,
              const float* __restrict__ A2, LN4 p,
              float* __restrict__ outbase, size_t ostride)
{
  __shared__ float As[32][68];
  __shared__ float Bs[32][132];
  __shared__ float rsum[64][17];
  __shared__ float rsq[64][17];
  __shared__ float stm[64], str[64];
  const int a = blockIdx.y;
  const float* A1 = A1base + (size_t)a * a1stride;
  float* out = outbase + (size_t)a * ostride;
  const float* W = p.W[a];
  const float* bias = p.b[a];
  const float* g = p.g[a];
  const float* be = p.be[a];
  const int eoff = HASEXT ? p.eoff[a] : 0;
  const int K2 = HASEXT ? p.elen[a] : 0;

  const int t = threadIdx.x;
  const int tx = t & 15, ty = t >> 4;
  const int row0 = blockIdx.x * 64;
  const int Kt = K1 + K2;
  const int ar = t >> 2, ac = (t & 3) * 8;
  const int bk = t >> 3, bc = (t & 7) * 16;

  float acc[4][8];
#pragma unroll
  for (int i = 0; i < 4; ++i)
#pragma unroll
    for (int j = 0; j < 8; ++j) acc[i][j] = 0.f;

  for (int k0 = 0; k0 < Kt; k0 += 32) {
    const int grow = row0 + ar;
#pragma unroll
    for (int e = 0; e < 8; ++e) {
      const int k = k0 + ac + e;
      float v = 0.f;
      if (k < K1)      v = A1[(size_t)grow * K1 + k];
      else if (k < Kt) v = A2[(size_t)grow * 115 + eoff + (k - K1)];
      As[ac + e][ar] = v;
    }
    {
      const int k = k0 + bk;
#pragma unroll
      for (int qd = 0; qd < 4; ++qd) {
        float4 z; z.x = z.y = z.z = z.w = 0.f;
        *(float4*)&Bs[bk][bc + 4 * qd] =
            (k < Kt) ? *(const float4*)&W[(size_t)k * 128 + bc + 4 * qd] : z;
      }
    }
    __syncthreads();
#pragma unroll
    for (int kk = 0; kk < 32; ++kk) {
      float av[4], bv2[8];
      *(float4*)&av[0]  = *(const float4*)&As[kk][ty * 4];
      *(float4*)&bv2[0] = *(const float4*)&Bs[kk][tx * 4];
      *(float4*)&bv2[4] = *(const float4*)&Bs[kk][64 + tx * 4];
#pragma unroll
      for (int i = 0; i < 4; ++i)
#pragma unroll
        for (int j = 0; j < 8; ++j)
          acc[i][j] = fmaf(av[i], bv2[j], acc[i][j]);
    }
    __syncthreads();
  }

  float bv[8];
  *(float4*)&bv[0] = *(const float4*)&bias[tx * 4];
  *(float4*)&bv[4] = *(const float4*)&bias[64 + tx * 4];
#pragma unroll
  for (int i = 0; i < 4; ++i) {
    float s = 0.f, q = 0.f;
#pragma unroll
    for (int j = 0; j < 8; ++j) {
      acc[i][j] += bv[j];
      s += acc[i][j];
      q += acc[i][j] * acc[i][j];
    }
    rsum[ty * 4 + i][tx] = s;
    rsq[ty * 4 + i][tx]  = q;
  }
  __syncthreads();
  if (t < 64) {
    float s = 0.f, q = 0.f;
#pragma unroll
    for (int x = 0; x < 16; ++x) { s += rsum[t][x]; q += rsq[t][x]; }
    const float m = s * (1.f / 128.f);
    const float v = q * (1.f / 128.f) - m * m;
    stm[t] = m;
    str[t] = rsqrtf(v + 1e-5f);
  }
  __syncthreads();
#pragma unroll
  for (int i = 0; i < 4; ++i) {
    const int r = ty * 4 + i;
    const float m = stm[r], rs = str[r];
    float o[8];
#pragma unroll
    for (int j = 0; j < 8; ++j) {
      const int col = (j < 4) ? (tx * 4 + j) : (64 + tx * 4 + (j - 4));
      float y = (acc[i][j] - m) * rs * g[col] + be[col];
      if (RELU) y = fmaxf(y, 0.f);
      o[j] = y;
    }
    *(float4*)&out[(size_t)(row0 + r) * 128 + tx * 4]      = *(float4*)&o[0];
    *(float4*)&out[(size_t)(row0 + r) * 128 + 64 + tx * 4] = *(float4*)&o[4];
  }
}

// =====================================================================
// Block-wide (256 threads) sum helper
// =====================================================================
__device__ __forceinline__ float blockSum256(float v, float* sh)
{
#pragma unroll
  for (int d = 32; d; d >>= 1) v += __shfl_down(v, d, 64);
  __syncthreads();
  if ((threadIdx.x & 63) == 0) sh[threadIdx.x >> 6] = v;
  __syncthreads();
  return sh[0] + sh[1] + sh[2] + sh[3];
}

// Row LN (width 3072) + L2 normalize, in place; optional bf16 copy out
template<bool CVT>
__global__ __launch_bounds__(256)
void ln_l2_q(float* __restrict__ q, const float* __restrict__ g,
             const float* __restrict__ be, ushort_t* __restrict__ qb)
{
  __shared__ float sh[4];
  const int row = blockIdx.x, t = threadIdx.x;
  float* qr = q + (size_t)row * Ez;
  float x[12];
#pragma unroll
  for (int i = 0; i < 12; ++i) x[i] = qr[t + (i << 8)];
  float s = 0.f;
#pragma unroll
  for (int i = 0; i < 12; ++i) s += x[i];
  const float m = blockSum256(s, sh) * (1.f / (float)Ez);
  float vs = 0.f;
#pragma unroll
  for (int i = 0; i < 12; ++i) { const float d = x[i] - m; vs += d * d; }
  const float v = blockSum256(vs, sh) * (1.f / (float)Ez);
  const float rs = rsqrtf(v + 1e-5f);
  float y[12]; float qs = 0.f;
#pragma unroll
  for (int i = 0; i < 12; ++i) {
    const int c = t + (i << 8);
    const float yy = (x[i] - m) * rs * g[c] + be[c];
    y[i] = yy; qs += yy * yy;
  }
  const float tot = blockSum256(qs, sh);
  const float s2 = rsqrtf(tot + 1e-12f);
#pragma unroll
  for (int i = 0; i < 12; ++i) {
    const int c = t + (i << 8);
    const float yn = y[i] * s2;
    qr[c] = yn;
    if (CVT) qb[(size_t)row * Ez + c] = f2bf(yn);
  }
}

// rk[n] only (fallback)
__global__ __launch_bounds__(256)
void keynorm(const float* __restrict__ keys, float* __restrict__ rk)
{
  __shared__ float sh[4];
  const int row = blockIdx.x, t = threadIdx.x;
  const float* xr = keys + (size_t)row * Ez;
  float qs = 0.f;
#pragma unroll
  for (int i = 0; i < 12; ++i) { const float x = xr[t + (i << 8)]; qs += x * x; }
  const float tot = blockSum256(qs, sh);
  if (t == 0) rk[row] = rsqrtf(tot + 1e-12f);
}

// fused: rk[n] + knbf[n,:] = bf16(keys[n,:] * rk[n])
__global__ __launch_bounds__(256)
void keys_norm_cvt(const float* __restrict__ keys, float* __restrict__ rk,
                   ushort_t* __restrict__ knb)
{
  __shared__ float sh[4];
  const int row = blockIdx.x, t = threadIdx.x;
  const float* xr = keys + (size_t)row * Ez;
  float x[12]; float qs = 0.f;
#pragma unroll
  for (int i = 0; i < 12; ++i) { x[i] = xr[t + (i << 8)]; qs += x[i] * x[i]; }
  const float tot = blockSum256(qs, sh);
  const float s = rsqrtf(tot + 1e-12f);
  if (t == 0) rk[row] = s;
#pragma unroll
  for (int i = 0; i < 12; ++i)
    knb[(size_t)row * Ez + t + (i << 8)] = f2bf(x[i] * s);
}

// se_w3 (512 x 3072 fp32) -> transposed hi/lo bf16 (3072 x 512 each)
__global__ __launch_bounds__(256)
void w3_transpose_split(const float* __restrict__ w,
                        ushort_t* __restrict__ hT, ushort_t* __restrict__ lT)
{
  __shared__ float tile[64][65];
  const int k0 = blockIdx.x * 64;
  const int n0 = blockIdx.y * 64;
  const int t = threadIdx.x;
  const int c = t & 63, r4 = t >> 6;
#pragma unroll
  for (int rr = 0; rr < 16; ++rr) {
    const int r = rr * 4 + r4;
    tile[r][c] = w[(size_t)(k0 + r) * 3072 + n0 + c];
  }
  __syncthreads();
#pragma unroll
  for (int rr = 0; rr < 16; ++rr) {
    const int n = rr * 4 + r4;
    const float a = tile[c][n];
    const ushort_t h = f2bf(a);
    hT[(size_t)(n0 + n) * 512 + k0 + c] = h;
    lT[(size_t)(n0 + n) * 512 + k0 + c] = f2bf(a - bf2f(h));
  }
}

// cc_w1 (3072 x 512 fp32) -> transposed bf16 (512 x 3072), coalesced
__global__ __launch_bounds__(256)
void cvt_w1t_t(const float* __restrict__ w, ushort_t* __restrict__ out)
{
  __shared__ float tile[64][65];
  const int k0 = blockIdx.x * 64;   // 48 blocks
  const int n0 = blockIdx.y * 64;   // 8 blocks
  const int t = threadIdx.x;
  const int c = t & 63, r4 = t >> 6;
#pragma unroll
  for (int rr = 0; rr < 16; ++rr) {
    const int r = rr * 4 + r4;
    tile[r][c] = w[(size_t)(k0 + r) * 512 + n0 + c];
  }
  __syncthreads();
#pragma unroll
  for (int rr = 0; rr < 16; ++rr) {
    const int n = rr * 4 + r4;
    out[(size_t)(n0 + n) * Ez + k0 + c] = f2bf(tile[c][n]);
  }
}

// =====================================================================
// Top-16 per row of the 8192 x 4096 u16-key score matrix.
// Packed u32 = (key<<12) | (4095-col): max-reduce == (max score, min col).
// Lane holds 16 contiguous cols (2x b128 loads).
// =====================================================================
__global__ __launch_bounds__(256)
void topk16(const ushort_t* __restrict__ S, int* __restrict__ outIdx)
{
  __shared__ uint_t cand[64];
  const int row = blockIdx.x, t = threadIdx.x;
  const int w = t >> 6, lane = t & 63;
  const int base = (w << 10) + (lane << 4);
  const ushort_t* sr = S + (size_t)row * NEz + base;
  uint4 v0 = *(const uint4*)sr;
  uint4 v1 = *(const uint4*)(sr + 8);
  const uint_t cb = (uint_t)(4095 - base);   // 4095-(base+j) = cb - j
  uint_t p[16];
  p[0]  = ((v0.x & 0xFFFFu) << 12) | (cb - 0);
  p[1]  = ((v0.x >> 16)     << 12) | (cb - 1);
  p[2]  = ((v0.y & 0xFFFFu) << 12) | (cb - 2);
  p[3]  = ((v0.y >> 16)     << 12) | (cb - 3);
  p[4]  = ((v0.z & 0xFFFFu) << 12) | (cb - 4);
  p[5]  = ((v0.z >> 16)     << 12) | (cb - 5);
  p[6]  = ((v0.w & 0xFFFFu) << 12) | (cb - 6);
  p[7]  = ((v0.w >> 16)     << 12) | (cb - 7);
  p[8]  = ((v1.x & 0xFFFFu) << 12) | (cb - 8);
  p[9]  = ((v1.x >> 16)     << 12) | (cb - 9);
  p[10] = ((v1.y & 0xFFFFu) << 12) | (cb - 10);
  p[11] = ((v1.y >> 16)     << 12) | (cb - 11);
  p[12] = ((v1.z & 0xFFFFu) << 12) | (cb - 12);
  p[13] = ((v1.z >> 16)     << 12) | (cb - 13);
  p[14] = ((v1.w & 0xFFFFu) << 12) | (cb - 14);
  p[15] = ((v1.w >> 16)     << 12) | (cb - 15);

  for (int it = 0; it < 16; ++it) {
    uint_t m = p[0];
#pragma unroll
    for (int j = 1; j < 16; ++j) m = umax_(m, p[j]);
#pragma unroll
    for (int d = 1; d < 64; d <<= 1)
      m = umax_(m, (uint_t)__shfl_xor((int)m, d, 64));
    if (lane == it) cand[(w << 4) + it] = m;
#pragma unroll
    for (int j = 0; j < 16; ++j) p[j] = (p[j] == m) ? 0u : p[j];
  }
  __syncthreads();
  if (t < 64) {
    uint_t mine = cand[t];
    for (int it = 0; it < 16; ++it) {
      uint_t m = mine;
#pragma unroll
      for (int d = 1; d < 64; d <<= 1)
        m = umax_(m, (uint_t)__shfl_xor((int)m, d, 64));
      if (t == it) outIdx[(size_t)row * 16 + it] = 4095 - (int)(m & 0xFFFu);
      mine = (mine == m) ? 0u : mine;
    }
  }
}

// =====================================================================
// Fused rescore + gather: one block per batch row (16 candidates).
// =====================================================================
template<bool BFOUT>
__global__ __launch_bounds__(256)
void rescore_gather(const float* __restrict__ qn, const float* __restrict__ keys,
                    const float* __restrict__ rk, const int* __restrict__ cand,
                    void* __restrict__ ctxOut)
{
  __shared__ float qs[Ez];
  __shared__ double sv[16];
  __shared__ int si[16];
  __shared__ int sel10[10];
  const int row = blockIdx.x, t = threadIdx.x;
  const int w = t >> 6, lane = t & 63;

  {
    const float* qr = qn + (size_t)row * Ez;
#pragma unroll
    for (int i = 0; i < 3; ++i) {
      const int c = (t << 2) + (i << 10);
      *(float4*)&qs[c] = *(const float4*)&qr[c];
    }
  }
  __syncthreads();

#pragma unroll
  for (int cc = 0; cc < 4; ++cc) {
    const int slot = w * 4 + cc;
    const int id = cand[(size_t)row * 16 + slot];
    const float* kr = keys + (size_t)id * Ez;
    double s = 0.0;
#pragma unroll
    for (int it = 0; it < 12; ++it) {
      const int c = (lane << 2) + (it << 8);
      float4 k4 = *(const float4*)&kr[c];
      float4 q4 = *(const float4*)&qs[c];
      s += (double)q4.x * (double)k4.x;
      s += (double)q4.y * (double)k4.y;
      s += (double)q4.z * (double)k4.z;
      s += (double)q4.w * (double)k4.w;
    }
#pragma unroll
    for (int d = 32; d; d >>= 1) s += __shfl_down(s, d, 64);
    if (lane == 0) { sv[slot] = s * (double)rk[id]; si[slot] = id; }
  }
  __syncthreads();

  if (t == 0) {
    for (int it = 0; it < 10; ++it) {
      int bj = 0; double bvv = sv[0]; int bi = si[0];
      for (int j = 1; j < 16; ++j) {
        const double v = sv[j]; const int i2 = si[j];
        if (v > bvv || (v == bvv && i2 < bi)) { bj = j; bvv = v; bi = i2; }
      }
      sel10[it] = bi;
      sv[bj] = -1e300;
    }
  }
  __syncthreads();

  int id[10];
#pragma unroll
  for (int j = 0; j < 10; ++j) id[j] = sel10[j];

#pragma unroll
  for (int i = 0; i < 3; ++i) {
    const int c = (t << 2) + (i << 10);
    float4 a = {0.f, 0.f, 0.f, 0.f};
#pragma unroll
    for (int j = 0; j < 10; ++j) {
      float4 v = *(const float4*)&keys[(size_t)id[j] * Ez + c];
      a.x += v.x; a.y += v.y; a.z += v.z; a.w += v.w;
    }
    if (BFOUT) {
      ushort4 o;
      o.x = f2bf(a.x * 0.1f); o.y = f2bf(a.y * 0.1f);
      o.z = f2bf(a.z * 0.1f); o.w = f2bf(a.w * 0.1f);
      *(ushort4*)&((ushort_t*)ctxOut)[(size_t)row * Ez + c] = o;
    } else {
      float4 o;
      o.x = a.x * 0.1f; o.y = a.y * 0.1f; o.z = a.z * 0.1f; o.w = a.w * 0.1f;
      *(float4*)&((float*)ctxOut)[(size_t)row * Ez + c] = o;
    }
  }
}

// =====================================================================
// Router: 115 -> 64 -> 64 -> 4, clip, + gumbel, softmax, straight-through
// =====================================================================
__global__ __launch_bounds__(256)
void router_kernel(const float* __restrict__ state, const float* __restrict__ gn,
                   const float* __restrict__ w1, const float* __restrict__ b1,
                   const float* __restrict__ w2, const float* __restrict__ b2,
                   const float* __restrict__ w3, const float* __restrict__ b3,
                   float* __restrict__ outAlpha)
{
  const int row = blockIdx.x * 256 + threadIdx.x;
  const float* sr = state + (size_t)row * Sz;
  float h1[64];
#pragma unroll
  for (int j = 0; j < 64; ++j) h1[j] = b1[j];
  for (int k = 0; k < Sz; ++k) {
    const float a = sr[k];
    const float* wr = w1 + (size_t)k * 64;
#pragma unroll
    for (int j = 0; j < 64; ++j) h1[j] = fmaf(a, wr[j], h1[j]);
  }
#pragma unroll
  for (int j = 0; j < 64; ++j) h1[j] = fmaxf(h1[j], 0.f);
  float h2[64];
#pragma unroll
  for (int j = 0; j < 64; ++j) h2[j] = b2[j];
#pragma unroll
  for (int k = 0; k < 64; ++k) {
    const float a = h1[k];
    const float* wr = w2 + (size_t)k * 64;
#pragma unroll
    for (int j = 0; j < 64; ++j) h2[j] = fmaf(a, wr[j], h2[j]);
  }
#pragma unroll
  for (int j = 0; j < 64; ++j) h2[j] = fmaxf(h2[j], 0.f);
  float z[4];
#pragma unroll
  for (int a = 0; a < 4; ++a) {
    float s = b3[a];
#pragma unroll
    for (int k = 0; k < 64; ++k) s = fmaf(h2[k], w3[k * 4 + a], s);
    s = fminf(fmaxf(s, -20.f), 20.f);
    z[a] = s + gn[(size_t)row * 4 + a];   // TAU = 1
  }
  float mz = z[0];
#pragma unroll
  for (int a = 1; a < 4; ++a) mz = fmaxf(mz, z[a]);
  float e[4]; float se = 0.f;
#pragma unroll
  for (int a = 0; a < 4; ++a) { e[a] = expf(z[a] - mz); se += e[a]; }
  const float inv = 1.f / se;
  float y[4];
#pragma unroll
  for (int a = 0; a < 4; ++a) y[a] = e[a] * inv;
  int am = 0;
#pragma unroll
  for (int a = 1; a < 4; ++a) if (y[a] > y[am]) am = a;
#pragma unroll
  for (int a = 0; a < 4; ++a) {
    const float hard = (a == am) ? 1.f : 0.f;
    outAlpha[(size_t)row * 4 + a] = y[a] + (hard - y[a]);
  }
}

// critic head
__global__ __launch_bounds__(256)
void critic_head(const float* __restrict__ c2, const float* __restrict__ w3,
                 const float* __restrict__ b3, float* __restrict__ outv)
{
  const int row = blockIdx.x * 256 + threadIdx.x;
  const float* xr = c2 + (size_t)row * 256;
  float s = b3[0];
  for (int k = 0; k < 256; ++k) s = fmaf(xr[k], w3[k], s);
  outv[row] = s;
}

// all-4 actor heads fused; 32 rows/block (256 blocks = full GPU)
struct HeadP { const float* w3[4]; const float* b3[4]; };

__global__ __launch_bounds__(256)
void actor_head4(const float* __restrict__ x2g, HeadP p,
                 const float* __restrict__ alpha, float* __restrict__ outL)
{
  __shared__ float wsm[4][128 * 23];
  __shared__ float bs[4][23];
  const int t = threadIdx.x;
#pragma unroll
  for (int a = 0; a < 4; ++a) {
    for (int i = t; i < 128 * 23; i += 256) wsm[a][i] = p.w3[a][i];
    if (t < 23) bs[a][t] = p.b3[a][t];
  }
  __syncthreads();
  const int row = blockIdx.x * 32 + (t >> 3);
  const int cg = t & 7;
  float sum[3] = {0.f, 0.f, 0.f};
#pragma unroll
  for (int a = 0; a < 4; ++a) {
    const float al = alpha[(size_t)row * 4 + a];
    const float* xr = x2g + (size_t)a * Bz * 128 + (size_t)row * 128;
    float acc[3] = {0.f, 0.f, 0.f};
    for (int kk = 0; kk < 128; ++kk) {
      const float xa = xr[kk];
#pragma unroll
      for (int j = 0; j < 3; ++j) {
        const int col = cg + 8 * j;
        if (col < 23) acc[j] = fmaf(xa, wsm[a][kk * 23 + col], acc[j]);
      }
    }
#pragma unroll
    for (int j = 0; j < 3; ++j) {
      const int col = cg + 8 * j;
      if (col < 23) sum[j] += al * (acc[j] + bs[a][col]);
    }
  }
#pragma unroll
  for (int j = 0; j < 3; ++j) {
    const int col = cg + 8 * j;
    if (col < 23) outL[(size_t)row * 23 + col] = sum[j];
  }
}

// =====================================================================
extern "C" void kernel_launch(void* const* d_in, const int* in_sizes, int n_in,
                              void* d_out, int out_size, void* d_ws, size_t ws_size,
                              hipStream_t stream)
{
  const float* state  = (const float*)d_in[0];
  const float* gumbel = (const float*)d_in[1];
  const float* keys   = (const float*)d_in[2];
  const float* se_w1 = (const float*)d_in[3];
  const float* se_b1 = (const float*)d_in[4];
  const float* se_w2 = (const float*)d_in[5];
  const float* se_b2 = (const float*)d_in[6];
  const float* se_w3 = (const float*)d_in[7];
  const float* se_b3 = (const float*)d_in[8];
  const float* se_g  = (const float*)d_in[9];
  const float* se_be = (const float*)d_in[10];
  const float* cc_w1 = (const float*)d_in[11];
  const float* cc_b1 = (const float*)d_in[12];
  const float* cc_w2 = (const float*)d_in[13];
  const float* cc_b2 = (const float*)d_in[14];
  const float* cc_g  = (const float*)d_in[15];
  const float* cc_be = (const float*)d_in[16];
  const float* r_w1 = (const float*)d_in[57];
  const float* r_b1 = (const float*)d_in[58];
  const float* r_w2 = (const float*)d_in[59];
  const float* r_b2 = (const float*)d_in[60];
  const float* r_w3 = (const float*)d_in[61];
  const float* r_b3 = (const float*)d_in[62];
  const float* c_w1 = (const float*)d_in[63];
  const float* c_b1 = (const float*)d_in[64];
  const float* c_w2 = (const float*)d_in[65];
  const float* c_b2 = (const float*)d_in[66];
  const float* c_w3 = (const float*)d_in[67];
  const float* c_b3 = (const float*)d_in[68];

  // ---- workspace layout ----
  float* wsf = (float*)d_ws;
  const size_t qF = (size_t)Bz * Ez;          // 25,165,824 floats
  const size_t uF = (size_t)16777216;         // union region, floats
  float* q = wsf;
  float* U = wsf + qF;
  // U internal (time-multiplexed):
  float* sA  = U;                              // encoder ping   [0, 4.19M)
  float* sB  = U + 4194304;                    // encoder pong   [4.19M, 8.39M)
  ushort_t* sBh  = (ushort_t*)(U + 8388608);   // bf16 hi of sB
  ushort_t* sBl  = (ushort_t*)(U + 10485760);  // bf16 lo of sB
  ushort_t* w3hT = (ushort_t*)(U + 12582912);  // se_w3^T hi (3072x512)
  ushort_t* w3lT = (ushort_t*)(U + 14155776);  // se_w3^T lo
  ushort_t* scoresU = (ushort_t*)U;            // 8192x4096 u16 keys (whole U)
  float* shr = U;                              // 8192x128
  float* x1g = U + 1 * 1048576;                // 4 x 8192x128
  float* x2g = U + 5 * 1048576;                // 4 x 8192x128
  float* cch = U + 9 * 1048576;                // 8192x512
  // critic temporaries live in the (not yet written) q region:
  float* cr1 = q;                              // 8192x256
  float* cr2 = q + 2097152;                    // 8192x256
  // fast-path bf16 buffers after U:
  ushort_t* qbf  = (ushort_t*)(wsf + qF + uF);     // 8192x3072
  ushort_t* knbf = qbf + qF;                       // 4096x3072
  ushort_t* w1T  = knbf + (size_t)NEz * Ez;        // 512x3072
  const size_t bfHalves = qF + (size_t)NEz * Ez + (size_t)512 * Ez;
  const size_t baseBytes = (qF + uF) * sizeof(float);
  const size_t tailBytes = 4096 * 4 + (size_t)Bz * 16 * 4;
  const bool fast = ws_size >= baseBytes + bfHalves * 2 + tailBytes;
  float* tailF = (float*)((char*)d_ws + (fast ? baseBytes + bfHalves * 2 : baseBytes));
  float* rk  = tailF;
  int* cand  = (int*)(tailF + 4096);
  ushort_t* ctxb = (ushort_t*)q;               // bf16 ctx overlays dead q

  float* outL = (float*)d_out;                 // 8192*23
  float* outA = outL + (size_t)Bz * 23;        // 8192*4
  float* outV = outA + (size_t)Bz * 4;         // 8192*1

  const dim3 blk(256);

  // --- encoder layer 1 + critic layer 1 (horizontal fusion) ---
  {
    GPart e0 = {state, se_w1, se_b1, sA, nullptr, nullptr, 512, 115, 4};
    GPart e1 = {state, c_w1,  c_b1,  cr1, nullptr, nullptr, 256, 115, 2};
    gemm128_dual<<<dim3(6, 64), blk, 0, stream>>>(e0, e1);
  }
  // --- encoder layer 2 (+ fused bf16 hi/lo split on fast path) + critic layer 2 ---
  {
    GPart f0 = {sA, se_w2, se_b2, sB, fast ? sBh : nullptr, fast ? sBl : nullptr,
                512, 512, 4};
    GPart f1 = {cr1, c_w2, c_b2, cr2, nullptr, nullptr, 256, 256, 2};
    gemm128_dual<<<dim3(6, 64), blk, 0, stream>>>(f0, f1);
  }
  // critic head + router now (cr1/cr2 die before q is written)
  critic_head<<<dim3(32), blk, 0, stream>>>(cr2, c_w3, c_b3, outV);
  router_kernel<<<dim3(32), blk, 0, stream>>>(state, gumbel, r_w1, r_b1, r_w2, r_b2,
                                              r_w3, r_b3, outA);

  if (fast) {
    // se_w3 via bf16x3 split-precision MFMA (fp32-accurate)
    w3_transpose_split<<<dim3(8, 48), blk, 0, stream>>>(se_w3, w3hT, w3lT);
    mfma3_bt<<<dim3(24, 64), blk, 0, stream>>>(sBh, sBl, w3hT, w3lT, se_b3, q, 3072, 512);
    ln_l2_q<true><<<dim3(Bz), blk, 0, stream>>>(q, se_g, se_be, qbf);
    keys_norm_cvt<<<dim3(NEz), blk, 0, stream>>>(keys, rk, knbf);
    cvt_w1t_t<<<dim3(48, 8), blk, 0, stream>>>(cc_w1, w1T);
    mfma_bt<0><<<dim3(2048), blk, 0, stream>>>(qbf, knbf, nullptr, scoresU, NEz, Ez);
  } else {
    gemm128<false, true><<<dim3(24, 64), blk, 0, stream>>>(sB, se_w3, se_b3, q, 3072, 512);
    ln_l2_q<false><<<dim3(Bz), blk, 0, stream>>>(q, se_g, se_be, nullptr);
    keynorm<<<dim3(NEz), blk, 0, stream>>>(keys, rk);
    gemm_scores<<<dim3(32, 64), blk, 0, stream>>>(q, keys, rk, scoresU);
  }

  // --- top-16 screen, fused fp64 rescore + top-10 set + context gather ---
  topk16<<<dim3(Bz), blk, 0, stream>>>(scoresU, cand);

  // --- context + compressor ---
  if (fast) {
    rescore_gather<true><<<dim3(Bz), blk, 0, stream>>>(q, keys, rk, cand, ctxb);
    mfma_bt<1><<<dim3(4, 64), blk, 0, stream>>>(ctxb, w1T, cc_b1, cch, 512, Ez);
  } else {
    rescore_gather<false><<<dim3(Bz), blk, 0, stream>>>(q, keys, rk, cand, q);
    gemm128<true, true><<<dim3(4, 64), blk, 0, stream>>>(q, cc_w1, cc_b1, cch, 512, Ez);
  }
  {
    LN4 pcc = {};
    pcc.W[0] = cc_w2; pcc.b[0] = cc_b2; pcc.g[0] = cc_g; pcc.be[0] = cc_be;
    gemm_ln4<false, false><<<dim3(128, 1), blk, 0, stream>>>(cch, 0, 512, nullptr, pcc,
                                                             shr, 0);
  }

  // --- actors (batched over blockIdx.y) ---
  {
    LN4 p1 = {}, p2 = {};
    HeadP ph = {};
    const int eoffs[4] = {0, 20, 40, 45};
    const int elens[4] = {50, 20, 10, 15};
    for (int a = 0; a < 4; ++a) {
      const int base = 17 + 10 * a;
      p1.W[a]  = (const float*)d_in[base + 0];
      p1.b[a]  = (const float*)d_in[base + 1];
      p1.g[a]  = (const float*)d_in[base + 2];
      p1.be[a] = (const float*)d_in[base + 3];
      p1.eoff[a] = eoffs[a]; p1.elen[a] = elens[a];
      p2.W[a]  = (const float*)d_in[base + 4];
      p2.b[a]  = (const float*)d_in[base + 5];
      p2.g[a]  = (const float*)d_in[base + 6];
      p2.be[a] = (const float*)d_in[base + 7];
      ph.w3[a] = (const float*)d_in[base + 8];
      ph.b3[a] = (const float*)d_in[base + 9];
    }
    gemm_ln4<true, true ><<<dim3(128, 4), blk, 0, stream>>>(shr, 0, 128, state, p1,
                                                            x1g, (size_t)Bz * 128);
    gemm_ln4<true, false><<<dim3(128, 4), blk, 0, stream>>>(x1g, (size_t)Bz * 128, 128,
                                                            nullptr, p2,
                                                            x2g, (size_t)Bz * 128);
    actor_head4<<<dim3(256), blk, 0, stream>>>(x2g, ph, outA, outL);
  }
}

// Round 7
// 1325.337 us; speedup vs baseline: 3.3362x; 1.0612x over previous
//
#include <hip/hip_runtime.h>

// Problem constants (match reference)
constexpr int Bz = 8192;   // batch
constexpr int Sz = 115;    // state dim
constexpr int Ez = 3072;   // embedding dim
constexpr int NEz = 4096;  // num keys
// C=128, A=23, K=10, TAU=1, EPS=1e-5

typedef __attribute__((ext_vector_type(8))) short short8;
typedef __attribute__((ext_vector_type(4))) float floatx4;
typedef unsigned short ushort_t;
typedef unsigned int uint_t;

__device__ __forceinline__ ushort_t f2bf(float f) {
  uint_t u = __float_as_uint(f);
  uint_t r = (u + 0x7FFFu + ((u >> 16) & 1u)) >> 16;   // RNE
  return (ushort_t)r;
}
__device__ __forceinline__ float bf2f(ushort_t b) {
  uint_t u = ((uint_t)b) << 16;
  return __uint_as_float(u);
}
// fp32 -> fp16 -> order-preserving u16 key (monotone total order)
__device__ __forceinline__ ushort_t f2key(float v) {
  _Float16 h = (_Float16)v;
  ushort_t b = __builtin_bit_cast(ushort_t, h);
  return b ^ ((b & 0x8000u) ? 0xFFFFu : 0x8000u);
}
__device__ __forceinline__ uint_t umax_(uint_t a, uint_t b) { return a > b ? a : b; }

// async global->LDS, 16 B per lane; lds dest = wave-uniform base + lane*16
__device__ __forceinline__ void gload16(const ushort_t* g, ushort_t* l) {
  __builtin_amdgcn_global_load_lds(
      (__attribute__((address_space(1))) const void*)g,
      (__attribute__((address_space(3))) void*)l, 16, 0, 0);
}

// =====================================================================
// Generic fp32 tiled GEMM (fallback): C = act(A@B + bias)
// =====================================================================
template<bool RELU, bool BIAS>
__global__ __launch_bounds__(256)
void gemm128(const float* __restrict__ A, const float* __restrict__ Bm,
             const float* __restrict__ bias, float* __restrict__ C,
             int N, int Kd)
{
  __shared__ float As[16][132];
  __shared__ float Bs[16][132];
  const int t  = threadIdx.x;
  const int tx = t & 15, ty = t >> 4;
  const int row0 = blockIdx.y * 128;
  const int col0 = blockIdx.x * 128;
  const int ar = t >> 2, ac = (t & 3) * 4;
  const int bk = t >> 5, bc = (t & 31) * 4;
  const bool a4 = (Kd & 3) == 0;

  float acc[8][8];
#pragma unroll
  for (int i = 0; i < 8; ++i)
#pragma unroll
    for (int j = 0; j < 8; ++j) acc[i][j] = 0.f;

  for (int k0 = 0; k0 < Kd; k0 += 16) {
    const bool fullA = (k0 + 16 <= Kd) && a4;
    {
      const float* ap = A + (size_t)(row0 + ar) * Kd + k0 + ac;
      if (fullA) {
        float4 v0 = *(const float4*)ap;
        float4 v1 = *(const float4*)(ap + (size_t)64 * Kd);
        As[ac + 0][ar] = v0.x; As[ac + 1][ar] = v0.y;
        As[ac + 2][ar] = v0.z; As[ac + 3][ar] = v0.w;
        As[ac + 0][ar + 64] = v1.x; As[ac + 1][ar + 64] = v1.y;
        As[ac + 2][ar + 64] = v1.z; As[ac + 3][ar + 64] = v1.w;
      } else {
#pragma unroll
        for (int e = 0; e < 4; ++e) {
          const int k = k0 + ac + e;
          float v0 = 0.f, v1 = 0.f;
          if (k < Kd) { v0 = ap[e]; v1 = ap[e + (size_t)64 * Kd]; }
          As[ac + e][ar] = v0; As[ac + e][ar + 64] = v1;
        }
      }
    }
    {
      const float* bp = Bm + (size_t)(k0 + bk) * N + col0 + bc;
      if (k0 + 16 <= Kd) {
        *(float4*)&Bs[bk][bc]     = *(const float4*)bp;
        *(float4*)&Bs[bk + 8][bc] = *(const float4*)(bp + (size_t)8 * N);
      } else {
        float4 z; z.x = z.y = z.z = z.w = 0.f;
        *(float4*)&Bs[bk][bc]     = (k0 + bk     < Kd) ? *(const float4*)bp : z;
        *(float4*)&Bs[bk + 8][bc] = (k0 + bk + 8 < Kd) ? *(const float4*)(bp + (size_t)8 * N) : z;
      }
    }
    __syncthreads();
#pragma unroll
    for (int kk = 0; kk < 16; ++kk) {
      float a[8], b[8];
      *(float4*)&a[0] = *(const float4*)&As[kk][ty * 4];
      *(float4*)&a[4] = *(const float4*)&As[kk][64 + ty * 4];
      *(float4*)&b[0] = *(const float4*)&Bs[kk][tx * 4];
      *(float4*)&b[4] = *(const float4*)&Bs[kk][64 + tx * 4];
#pragma unroll
      for (int i = 0; i < 8; ++i)
#pragma unroll
        for (int j = 0; j < 8; ++j)
          acc[i][j] = fmaf(a[i], b[j], acc[i][j]);
    }
    __syncthreads();
  }

  float bv[8];
#pragma unroll
  for (int j = 0; j < 8; ++j) bv[j] = 0.f;
  if (BIAS) {
    *(float4*)&bv[0] = *(const float4*)&bias[col0 + tx * 4];
    *(float4*)&bv[4] = *(const float4*)&bias[col0 + 64 + tx * 4];
  }
#pragma unroll
  for (int i = 0; i < 8; ++i) {
    const int r = row0 + ((i < 4) ? (ty * 4 + i) : (64 + ty * 4 + i - 4));
    float o[8];
#pragma unroll
    for (int j = 0; j < 8; ++j) {
      o[j] = acc[i][j] + bv[j];
      if (RELU) o[j] = fmaxf(o[j], 0.f);
    }
    *(float4*)&C[(size_t)r * N + col0 + tx * 4]      = *(float4*)&o[0];
    *(float4*)&C[(size_t)r * N + col0 + 64 + tx * 4] = *(float4*)&o[4];
  }
}

// =====================================================================
// Dual-part fp32 GEMM+ReLU+bias: two independent GEMMs in one launch.
// Optional bf16 hi/lo split outputs (Ch/Cl).
// =====================================================================
struct GPart {
  const float* A; const float* Bm; const float* bias;
  float* C; ushort_t* Ch; ushort_t* Cl;
  int N; int Kd; int nbx;
};

__global__ __launch_bounds__(256)
void gemm128_dual(GPart g0, GPart g1)
{
  __shared__ float As[16][132];
  __shared__ float Bs[16][132];
  const int t  = threadIdx.x;
  const int tx = t & 15, ty = t >> 4;
  const bool p0 = (int)blockIdx.x < g0.nbx;
  GPart g = p0 ? g0 : g1;
  const int bx = p0 ? blockIdx.x : (blockIdx.x - g0.nbx);
  const int row0 = blockIdx.y * 128;
  const int col0 = bx * 128;
  const int Kd = g.Kd, N = g.N;
  const int ar = t >> 2, ac = (t & 3) * 4;
  const int bk = t >> 5, bc = (t & 31) * 4;
  const bool a4 = (Kd & 3) == 0;

  float acc[8][8];
#pragma unroll
  for (int i = 0; i < 8; ++i)
#pragma unroll
    for (int j = 0; j < 8; ++j) acc[i][j] = 0.f;

  for (int k0 = 0; k0 < Kd; k0 += 16) {
    const bool fullA = (k0 + 16 <= Kd) && a4;
    {
      const float* ap = g.A + (size_t)(row0 + ar) * Kd + k0 + ac;
      if (fullA) {
        float4 v0 = *(const float4*)ap;
        float4 v1 = *(const float4*)(ap + (size_t)64 * Kd);
        As[ac + 0][ar] = v0.x; As[ac + 1][ar] = v0.y;
        As[ac + 2][ar] = v0.z; As[ac + 3][ar] = v0.w;
        As[ac + 0][ar + 64] = v1.x; As[ac + 1][ar + 64] = v1.y;
        As[ac + 2][ar + 64] = v1.z; As[ac + 3][ar + 64] = v1.w;
      } else {
#pragma unroll
        for (int e = 0; e < 4; ++e) {
          const int k = k0 + ac + e;
          float v0 = 0.f, v1 = 0.f;
          if (k < Kd) { v0 = ap[e]; v1 = ap[e + (size_t)64 * Kd]; }
          As[ac + e][ar] = v0; As[ac + e][ar + 64] = v1;
        }
      }
    }
    {
      const float* bp = g.Bm + (size_t)(k0 + bk) * N + col0 + bc;
      if (k0 + 16 <= Kd) {
        *(float4*)&Bs[bk][bc]     = *(const float4*)bp;
        *(float4*)&Bs[bk + 8][bc] = *(const float4*)(bp + (size_t)8 * N);
      } else {
        float4 z; z.x = z.y = z.z = z.w = 0.f;
        *(float4*)&Bs[bk][bc]     = (k0 + bk     < Kd) ? *(const float4*)bp : z;
        *(float4*)&Bs[bk + 8][bc] = (k0 + bk + 8 < Kd) ? *(const float4*)(bp + (size_t)8 * N) : z;
      }
    }
    __syncthreads();
#pragma unroll
    for (int kk = 0; kk < 16; ++kk) {
      float a[8], b[8];
      *(float4*)&a[0] = *(const float4*)&As[kk][ty * 4];
      *(float4*)&a[4] = *(const float4*)&As[kk][64 + ty * 4];
      *(float4*)&b[0] = *(const float4*)&Bs[kk][tx * 4];
      *(float4*)&b[4] = *(const float4*)&Bs[kk][64 + tx * 4];
#pragma unroll
      for (int i = 0; i < 8; ++i)
#pragma unroll
        for (int j = 0; j < 8; ++j)
          acc[i][j] = fmaf(a[i], b[j], acc[i][j]);
    }
    __syncthreads();
  }

  float bv[8];
  *(float4*)&bv[0] = *(const float4*)&g.bias[col0 + tx * 4];
  *(float4*)&bv[4] = *(const float4*)&g.bias[col0 + 64 + tx * 4];
#pragma unroll
  for (int i = 0; i < 8; ++i) {
    const int r = row0 + ((i < 4) ? (ty * 4 + i) : (64 + ty * 4 + i - 4));
    float o[8];
#pragma unroll
    for (int j = 0; j < 8; ++j) o[j] = fmaxf(acc[i][j] + bv[j], 0.f);
    const size_t i0 = (size_t)r * N + col0 + tx * 4;
    const size_t i1 = i0 + 64;
    *(float4*)&g.C[i0] = *(float4*)&o[0];
    *(float4*)&g.C[i1] = *(float4*)&o[4];
    if (g.Ch) {
      ushort4 h0, l0, h1, l1;
      h0.x = f2bf(o[0]); l0.x = f2bf(o[0] - bf2f(h0.x));
      h0.y = f2bf(o[1]); l0.y = f2bf(o[1] - bf2f(h0.y));
      h0.z = f2bf(o[2]); l0.z = f2bf(o[2] - bf2f(h0.z));
      h0.w = f2bf(o[3]); l0.w = f2bf(o[3] - bf2f(h0.w));
      h1.x = f2bf(o[4]); l1.x = f2bf(o[4] - bf2f(h1.x));
      h1.y = f2bf(o[5]); l1.y = f2bf(o[5] - bf2f(h1.y));
      h1.z = f2bf(o[6]); l1.z = f2bf(o[6] - bf2f(h1.z));
      h1.w = f2bf(o[7]); l1.w = f2bf(o[7] - bf2f(h1.w));
      *(ushort4*)&g.Ch[i0] = h0; *(ushort4*)&g.Cl[i0] = l0;
      *(ushort4*)&g.Ch[i1] = h1; *(ushort4*)&g.Cl[i1] = l1;
    }
  }
}

// =====================================================================
// bf16 MFMA GEMM, A(M x K) @ B(N x K)^T, both row-major bf16 (K-contig).
// BK=64 as two back-to-back BK=32 sub-tiles (layout per sub-tile keeps
// 64-B row stride = conflict-free, and preserves global_load_lds's
// wave-uniform-base+lane*16 constraint). Halves barrier count vs BK=32.
// Kd must be a multiple of 64.
// EPI=0: u16 score keys. EPI=1: fp32 + bias + ReLU.
// =====================================================================
template<int EPI>
__global__ __launch_bounds__(256)
void mfma_bt(const ushort_t* __restrict__ A, const ushort_t* __restrict__ B,
             const float* __restrict__ bias, void* __restrict__ Cout,
             int N, int Kd)
{
  __shared__ ushort_t Al[2 * 128 * 32];   // two BK=32 sub-tiles
  __shared__ ushort_t Bl[2 * 128 * 32];
  const int t = threadIdx.x;
  const int wid = t >> 6, lane = t & 63;
  const int wr = wid >> 1, wc = wid & 1;
  const int row0 = blockIdx.y << 7;
  const int col0 = blockIdx.x << 7;
  const int srow = lane >> 2;
  const int scol = (lane & 3) * 8;

  const ushort_t* ga0 = A + (size_t)(row0 + wid * 16 + srow) * Kd + scol;
  const ushort_t* ga1 = A + (size_t)(row0 + (wid + 4) * 16 + srow) * Kd + scol;
  const ushort_t* gb0 = B + (size_t)(col0 + wid * 16 + srow) * Kd + scol;
  const ushort_t* gb1 = B + (size_t)(col0 + (wid + 4) * 16 + srow) * Kd + scol;
  ushort_t* la0 = &Al[wid * 512];
  ushort_t* la1 = &Al[(wid + 4) * 512];
  ushort_t* lb0 = &Bl[wid * 512];
  ushort_t* lb1 = &Bl[(wid + 4) * 512];

  const int mr = lane & 15, qd = lane >> 4;

  floatx4 acc[4][4];
#pragma unroll
  for (int i = 0; i < 4; ++i)
#pragma unroll
    for (int j = 0; j < 4; ++j) acc[i][j] = (floatx4){0.f, 0.f, 0.f, 0.f};

  for (int kb = 0; kb < Kd; kb += 64) {
#pragma unroll
    for (int tt = 0; tt < 2; ++tt) {
      const int ko = kb + 32 * tt;
      const int lo = tt * 4096;
      gload16(ga0 + ko, la0 + lo);
      gload16(ga1 + ko, la1 + lo);
      gload16(gb0 + ko, lb0 + lo);
      gload16(gb1 + ko, lb1 + lo);
    }
    __syncthreads();
#pragma unroll
    for (int tt = 0; tt < 2; ++tt) {
      const int lo = tt * 4096;
      short8 aF[4], bF[4];
#pragma unroll
      for (int i = 0; i < 4; ++i)
        aF[i] = *(const short8*)&Al[lo + (wr * 64 + i * 16 + mr) * 32 + qd * 8];
#pragma unroll
      for (int j = 0; j < 4; ++j)
        bF[j] = *(const short8*)&Bl[lo + (wc * 64 + j * 16 + mr) * 32 + qd * 8];
#pragma unroll
      for (int i = 0; i < 4; ++i)
#pragma unroll
        for (int j = 0; j < 4; ++j)
          acc[i][j] = __builtin_amdgcn_mfma_f32_16x16x32_bf16(aF[i], bF[j], acc[i][j], 0, 0, 0);
    }
    __syncthreads();
  }

  // C/D layout: col = lane&15, row = (lane>>4)*4 + reg
#pragma unroll
  for (int i = 0; i < 4; ++i) {
#pragma unroll
    for (int j = 0; j < 4; ++j) {
      const int col = col0 + wc * 64 + j * 16 + mr;
#pragma unroll
      for (int r = 0; r < 4; ++r) {
        const int row = row0 + wr * 64 + i * 16 + qd * 4 + r;
        if (EPI == 0) {
          ((ushort_t*)Cout)[(size_t)row * N + col] = f2key(acc[i][j][r]);
        } else {
          float v = acc[i][j][r] + bias[col];
          ((float*)Cout)[(size_t)row * N + col] = fmaxf(v, 0.f);
        }
      }
    }
  }
}

// =====================================================================
// bf16x3 split-precision MFMA GEMM (fp32-accurate): C = A@B^T + bias
// =====================================================================
__global__ __launch_bounds__(256)
void mfma3_bt(const ushort_t* __restrict__ Ah, const ushort_t* __restrict__ Alo,
              const ushort_t* __restrict__ Bh, const ushort_t* __restrict__ Blo,
              const float* __restrict__ bias, float* __restrict__ Cout,
              int N, int Kd)
{
  __shared__ ushort_t AhL[128 * 32];
  __shared__ ushort_t AlL[128 * 32];
  __shared__ ushort_t BhL[128 * 32];
  __shared__ ushort_t BlL[128 * 32];
  const int t = threadIdx.x;
  const int wid = t >> 6, lane = t & 63;
  const int wr = wid >> 1, wc = wid & 1;
  const int row0 = blockIdx.y * 128;
  const int col0 = blockIdx.x * 128;
  const int srow = lane >> 2;
  const int scol = (lane & 3) * 8;

  const size_t aoff0 = (size_t)(row0 + wid * 16 + srow) * Kd + scol;
  const size_t aoff1 = (size_t)(row0 + (wid + 4) * 16 + srow) * Kd + scol;
  const size_t boff0 = (size_t)(col0 + wid * 16 + srow) * Kd + scol;
  const size_t boff1 = (size_t)(col0 + (wid + 4) * 16 + srow) * Kd + scol;
  const int l0 = (wid * 16) * 32;
  const int l1 = ((wid + 4) * 16) * 32;

  const int mr = lane & 15, qd = lane >> 4;

  floatx4 acc[4][4];
#pragma unroll
  for (int i = 0; i < 4; ++i)
#pragma unroll
    for (int j = 0; j < 4; ++j) acc[i][j] = (floatx4){0.f, 0.f, 0.f, 0.f};

  for (int kb = 0; kb < Kd; kb += 32) {
    gload16(Ah + aoff0 + kb, &AhL[l0]);
    gload16(Ah + aoff1 + kb, &AhL[l1]);
    gload16(Alo + aoff0 + kb, &AlL[l0]);
    gload16(Alo + aoff1 + kb, &AlL[l1]);
    gload16(Bh + boff0 + kb, &BhL[l0]);
    gload16(Bh + boff1 + kb, &BhL[l1]);
    gload16(Blo + boff0 + kb, &BlL[l0]);
    gload16(Blo + boff1 + kb, &BlL[l1]);
    __syncthreads();
    short8 ahF[4], alF[4], bhF[4], blF[4];
#pragma unroll
    for (int i = 0; i < 4; ++i) {
      const int o = (wr * 64 + i * 16 + mr) * 32 + qd * 8;
      ahF[i] = *(const short8*)&AhL[o];
      alF[i] = *(const short8*)&AlL[o];
    }
#pragma unroll
    for (int j = 0; j < 4; ++j) {
      const int o = (wc * 64 + j * 16 + mr) * 32 + qd * 8;
      bhF[j] = *(const short8*)&BhL[o];
      blF[j] = *(const short8*)&BlL[o];
    }
#pragma unroll
    for (int i = 0; i < 4; ++i)
#pragma unroll
      for (int j = 0; j < 4; ++j) {
        acc[i][j] = __builtin_amdgcn_mfma_f32_16x16x32_bf16(alF[i], bhF[j], acc[i][j], 0, 0, 0);
        acc[i][j] = __builtin_amdgcn_mfma_f32_16x16x32_bf16(ahF[i], blF[j], acc[i][j], 0, 0, 0);
        acc[i][j] = __builtin_amdgcn_mfma_f32_16x16x32_bf16(ahF[i], bhF[j], acc[i][j], 0, 0, 0);
      }
    __syncthreads();
  }

#pragma unroll
  for (int i = 0; i < 4; ++i) {
#pragma unroll
    for (int j = 0; j < 4; ++j) {
      const int col = col0 + wc * 64 + j * 16 + mr;
#pragma unroll
      for (int r = 0; r < 4; ++r) {
        const int row = row0 + wr * 64 + i * 16 + qd * 4 + r;
        Cout[(size_t)row * N + col] = acc[i][j][r] + bias[col];
      }
    }
  }
}

// =====================================================================
// fp32 scores GEMM (fallback path only) -> u16 score keys
// =====================================================================
__global__ __launch_bounds__(256)
void gemm_scores(const float* __restrict__ A, const float* __restrict__ Bm,
                 const float* __restrict__ rk, ushort_t* __restrict__ S)
{
  __shared__ float As[16][132];
  __shared__ float Bs[16][132];
  const int t  = threadIdx.x;
  const int tx = t & 15, ty = t >> 4;
  const int row0 = blockIdx.y * 128;
  const int col0 = blockIdx.x * 128;
  const int ar = t >> 2, ac = (t & 3) * 4;
  const int Kd = Ez;

  float acc[8][8];
#pragma unroll
  for (int i = 0; i < 8; ++i)
#pragma unroll
    for (int j = 0; j < 8; ++j) acc[i][j] = 0.f;

  for (int k0 = 0; k0 < Kd; k0 += 16) {
    {
      const float* ap = A + (size_t)(row0 + ar) * Kd + k0 + ac;
      float4 v0 = *(const float4*)ap;
      float4 v1 = *(const float4*)(ap + (size_t)64 * Kd);
      As[ac + 0][ar] = v0.x; As[ac + 1][ar] = v0.y;
      As[ac + 2][ar] = v0.z; As[ac + 3][ar] = v0.w;
      As[ac + 0][ar + 64] = v1.x; As[ac + 1][ar + 64] = v1.y;
      As[ac + 2][ar + 64] = v1.z; As[ac + 3][ar + 64] = v1.w;
    }
    {
      const float* bp = Bm + (size_t)(col0 + ar) * Kd + k0 + ac;
      float4 v0 = *(const float4*)bp;
      float4 v1 = *(const float4*)(bp + (size_t)64 * Kd);
      Bs[ac + 0][ar] = v0.x; Bs[ac + 1][ar] = v0.y;
      Bs[ac + 2][ar] = v0.z; Bs[ac + 3][ar] = v0.w;
      Bs[ac + 0][ar + 64] = v1.x; Bs[ac + 1][ar + 64] = v1.y;
      Bs[ac + 2][ar + 64] = v1.z; Bs[ac + 3][ar + 64] = v1.w;
    }
    __syncthreads();
#pragma unroll
    for (int kk = 0; kk < 16; ++kk) {
      float a[8], b[8];
      *(float4*)&a[0] = *(const float4*)&As[kk][ty * 4];
      *(float4*)&a[4] = *(const float4*)&As[kk][64 + ty * 4];
      *(float4*)&b[0] = *(const float4*)&Bs[kk][tx * 4];
      *(float4*)&b[4] = *(const float4*)&Bs[kk][64 + tx * 4];
#pragma unroll
      for (int i = 0; i < 8; ++i)
#pragma unroll
        for (int j = 0; j < 8; ++j)
          acc[i][j] = fmaf(a[i], b[j], acc[i][j]);
    }
    __syncthreads();
  }

  float rk0[8];
  *(float4*)&rk0[0] = *(const float4*)&rk[col0 + tx * 4];
  *(float4*)&rk0[4] = *(const float4*)&rk[col0 + 64 + tx * 4];
#pragma unroll
  for (int i = 0; i < 8; ++i) {
    const int r = row0 + ((i < 4) ? (ty * 4 + i) : (64 + ty * 4 + i - 4));
    ushort4 h0, h1;
    h0.x = f2key(acc[i][0] * rk0[0]); h0.y = f2key(acc[i][1] * rk0[1]);
    h0.z = f2key(acc[i][2] * rk0[2]); h0.w = f2key(acc[i][3] * rk0[3]);
    h1.x = f2key(acc[i][4] * rk0[4]); h1.y = f2key(acc[i][5] * rk0[5]);
    h1.z = f2key(acc[i][6] * rk0[6]); h1.w = f2key(acc[i][7] * rk0[7]);
    *(ushort4*)&S[(size_t)r * NEz + col0 + tx * 4]      = h0;
    *(ushort4*)&S[(size_t)r * NEz + col0 + 64 + tx * 4] = h1;
  }
}

// =====================================================================
// Batched (4-actor) fused GEMM(N=128) + LayerNorm (+ReLU).
// =====================================================================
struct LN4 {
  const float* W[4]; const float* b[4]; const float* g[4]; const float* be[4];
  int eoff[4]; int elen[4];
};

template<bool RELU, bool HASEXT>
__global__ __launch_bounds__(256)
void gemm_ln4(const float* __restrict__ A1base, size_t a1stride, int K1,
              const float* __restrict__ A2, LN4 p,
              float* __restrict__ outbase, size_t ostride)
{
  __shared__ float As[32][68];
  __shared__ float Bs[32][132];
  __shared__ float rsum[64][17];
  __shared__ float rsq[64][17];
  __shared__ float stm[64], str[64];
  const int a = blockIdx.y;
  const float* A1 = A1base + (size_t)a * a1stride;
  float* out = outbase + (size_t)a * ostride;
  const float* W = p.W[a];
  const float* bias = p.b[a];
  const float* g = p.g[a];
  const float* be = p.be[a];
  const int eoff = HASEXT ? p.eoff[a] : 0;
  const int K2 = HASEXT ? p.elen[a] : 0;

  const int t = threadIdx.x;
  const int tx = t & 15, ty = t >> 4;
  const int row0 = blockIdx.x * 64;
  const int Kt = K1 + K2;
  const int ar = t >> 2, ac = (t & 3) * 8;
  const int bk = t >> 3, bc = (t & 7) * 16;

  float acc[4][8];
#pragma unroll
  for (int i = 0; i < 4; ++i)
#pragma unroll
    for (int j = 0; j < 8; ++j) acc[i][j] = 0.f;

  for (int k0 = 0; k0 < Kt; k0 += 32) {
    const int grow = row0 + ar;
#pragma unroll
    for (int e = 0; e < 8; ++e) {
      const int k = k0 + ac + e;
      float v = 0.f;
      if (k < K1)      v = A1[(size_t)grow * K1 + k];
      else if (k < Kt) v = A2[(size_t)grow * 115 + eoff + (k - K1)];
      As[ac + e][ar] = v;
    }
    {
      const int k = k0 + bk;
#pragma unroll
      for (int qd = 0; qd < 4; ++qd) {
        float4 z; z.x = z.y = z.z = z.w = 0.f;
        *(float4*)&Bs[bk][bc + 4 * qd] =
            (k < Kt) ? *(const float4*)&W[(size_t)k * 128 + bc + 4 * qd] : z;
      }
    }
    __syncthreads();
#pragma unroll
    for (int kk = 0; kk < 32; ++kk) {
      float av[4], bv2[8];
      *(float4*)&av[0]  = *(const float4*)&As[kk][ty * 4];
      *(float4*)&bv2[0] = *(const float4*)&Bs[kk][tx * 4];
      *(float4*)&bv2[4] = *(const float4*)&Bs[kk][64 + tx * 4];
#pragma unroll
      for (int i = 0; i < 4; ++i)
#pragma unroll
        for (int j = 0; j < 8; ++j)
          acc[i][j] = fmaf(av[i], bv2[j], acc[i][j]);
    }
    __syncthreads();
  }

  float bv[8];
  *(float4*)&bv[0] = *(const float4*)&bias[tx * 4];
  *(float4*)&bv[4] = *(const float4*)&bias[64 + tx * 4];
#pragma unroll
  for (int i = 0; i < 4; ++i) {
    float s = 0.f, q = 0.f;
#pragma unroll
    for (int j = 0; j < 8; ++j) {
      acc[i][j] += bv[j];
      s += acc[i][j];
      q += acc[i][j] * acc[i][j];
    }
    rsum[ty * 4 + i][tx] = s;
    rsq[ty * 4 + i][tx]  = q;
  }
  __syncthreads();
  if (t < 64) {
    float s = 0.f, q = 0.f;
#pragma unroll
    for (int x = 0; x < 16; ++x) { s += rsum[t][x]; q += rsq[t][x]; }
    const float m = s * (1.f / 128.f);
    const float v = q * (1.f / 128.f) - m * m;
    stm[t] = m;
    str[t] = rsqrtf(v + 1e-5f);
  }
  __syncthreads();
#pragma unroll
  for (int i = 0; i < 4; ++i) {
    const int r = ty * 4 + i;
    const float m = stm[r], rs = str[r];
    float o[8];
#pragma unroll
    for (int j = 0; j < 8; ++j) {
      const int col = (j < 4) ? (tx * 4 + j) : (64 + tx * 4 + (j - 4));
      float y = (acc[i][j] - m) * rs * g[col] + be[col];
      if (RELU) y = fmaxf(y, 0.f);
      o[j] = y;
    }
    *(float4*)&out[(size_t)(row0 + r) * 128 + tx * 4]      = *(float4*)&o[0];
    *(float4*)&out[(size_t)(row0 + r) * 128 + 64 + tx * 4] = *(float4*)&o[4];
  }
}

// =====================================================================
// Block-wide (256 threads) sum helper
// =====================================================================
__device__ __forceinline__ float blockSum256(float v, float* sh)
{
#pragma unroll
  for (int d = 32; d; d >>= 1) v += __shfl_down(v, d, 64);
  __syncthreads();
  if ((threadIdx.x & 63) == 0) sh[threadIdx.x >> 6] = v;
  __syncthreads();
  return sh[0] + sh[1] + sh[2] + sh[3];
}

// Row LN (width 3072) + L2 normalize, in place; optional bf16 copy out
template<bool CVT>
__global__ __launch_bounds__(256)
void ln_l2_q(float* __restrict__ q, const float* __restrict__ g,
             const float* __restrict__ be, ushort_t* __restrict__ qb)
{
  __shared__ float sh[4];
  const int row = blockIdx.x, t = threadIdx.x;
  float* qr = q + (size_t)row * Ez;
  float x[12];
#pragma unroll
  for (int i = 0; i < 12; ++i) x[i] = qr[t + (i << 8)];
  float s = 0.f;
#pragma unroll
  for (int i = 0; i < 12; ++i) s += x[i];
  const float m = blockSum256(s, sh) * (1.f / (float)Ez);
  float vs = 0.f;
#pragma unroll
  for (int i = 0; i < 12; ++i) { const float d = x[i] - m; vs += d * d; }
  const float v = blockSum256(vs, sh) * (1.f / (float)Ez);
  const float rs = rsqrtf(v + 1e-5f);
  float y[12]; float qs = 0.f;
#pragma unroll
  for (int i = 0; i < 12; ++i) {
    const int c = t + (i << 8);
    const float yy = (x[i] - m) * rs * g[c] + be[c];
    y[i] = yy; qs += yy * yy;
  }
  const float tot = blockSum256(qs, sh);
  const float s2 = rsqrtf(tot + 1e-12f);
#pragma unroll
  for (int i = 0; i < 12; ++i) {
    const int c = t + (i << 8);
    const float yn = y[i] * s2;
    qr[c] = yn;
    if (CVT) qb[(size_t)row * Ez + c] = f2bf(yn);
  }
}

// rk[n] only (fallback)
__global__ __launch_bounds__(256)
void keynorm(const float* __restrict__ keys, float* __restrict__ rk)
{
  __shared__ float sh[4];
  const int row = blockIdx.x, t = threadIdx.x;
  const float* xr = keys + (size_t)row * Ez;
  float qs = 0.f;
#pragma unroll
  for (int i = 0; i < 12; ++i) { const float x = xr[t + (i << 8)]; qs += x * x; }
  const float tot = blockSum256(qs, sh);
  if (t == 0) rk[row] = rsqrtf(tot + 1e-12f);
}

// fused: rk[n] + knbf[n,:] = bf16(keys[n,:] * rk[n])
__global__ __launch_bounds__(256)
void keys_norm_cvt(const float* __restrict__ keys, float* __restrict__ rk,
                   ushort_t* __restrict__ knb)
{
  __shared__ float sh[4];
  const int row = blockIdx.x, t = threadIdx.x;
  const float* xr = keys + (size_t)row * Ez;
  float x[12]; float qs = 0.f;
#pragma unroll
  for (int i = 0; i < 12; ++i) { x[i] = xr[t + (i << 8)]; qs += x[i] * x[i]; }
  const float tot = blockSum256(qs, sh);
  const float s = rsqrtf(tot + 1e-12f);
  if (t == 0) rk[row] = s;
#pragma unroll
  for (int i = 0; i < 12; ++i)
    knb[(size_t)row * Ez + t + (i << 8)] = f2bf(x[i] * s);
}

// se_w3 (512 x 3072 fp32) -> transposed hi/lo bf16 (3072 x 512 each)
__global__ __launch_bounds__(256)
void w3_transpose_split(const float* __restrict__ w,
                        ushort_t* __restrict__ hT, ushort_t* __restrict__ lT)
{
  __shared__ float tile[64][65];
  const int k0 = blockIdx.x * 64;
  const int n0 = blockIdx.y * 64;
  const int t = threadIdx.x;
  const int c = t & 63, r4 = t >> 6;
#pragma unroll
  for (int rr = 0; rr < 16; ++rr) {
    const int r = rr * 4 + r4;
    tile[r][c] = w[(size_t)(k0 + r) * 3072 + n0 + c];
  }
  __syncthreads();
#pragma unroll
  for (int rr = 0; rr < 16; ++rr) {
    const int n = rr * 4 + r4;
    const float a = tile[c][n];
    const ushort_t h = f2bf(a);
    hT[(size_t)(n0 + n) * 512 + k0 + c] = h;
    lT[(size_t)(n0 + n) * 512 + k0 + c] = f2bf(a - bf2f(h));
  }
}

// cc_w1 (3072 x 512 fp32) -> transposed bf16 (512 x 3072), coalesced
__global__ __launch_bounds__(256)
void cvt_w1t_t(const float* __restrict__ w, ushort_t* __restrict__ out)
{
  __shared__ float tile[64][65];
  const int k0 = blockIdx.x * 64;   // 48 blocks
  const int n0 = blockIdx.y * 64;   // 8 blocks
  const int t = threadIdx.x;
  const int c = t & 63, r4 = t >> 6;
#pragma unroll
  for (int rr = 0; rr < 16; ++rr) {
    const int r = rr * 4 + r4;
    tile[r][c] = w[(size_t)(k0 + r) * 512 + n0 + c];
  }
  __syncthreads();
#pragma unroll
  for (int rr = 0; rr < 16; ++rr) {
    const int n = rr * 4 + r4;
    out[(size_t)(n0 + n) * Ez + k0 + c] = f2bf(tile[c][n]);
  }
}

// =====================================================================
// Top-16 per row of the 8192 x 4096 u16-key score matrix.
// Packed u32 = (key<<12) | (4095-col): max-reduce == (max score, min col).
// =====================================================================
__global__ __launch_bounds__(256)
void topk16(const ushort_t* __restrict__ S, int* __restrict__ outIdx)
{
  __shared__ uint_t cand[64];
  const int row = blockIdx.x, t = threadIdx.x;
  const int w = t >> 6, lane = t & 63;
  const int base = (w << 10) + (lane << 4);
  const ushort_t* sr = S + (size_t)row * NEz + base;
  uint4 v0 = *(const uint4*)sr;
  uint4 v1 = *(const uint4*)(sr + 8);
  const uint_t cb = (uint_t)(4095 - base);
  uint_t p[16];
  p[0]  = ((v0.x & 0xFFFFu) << 12) | (cb - 0);
  p[1]  = ((v0.x >> 16)     << 12) | (cb - 1);
  p[2]  = ((v0.y & 0xFFFFu) << 12) | (cb - 2);
  p[3]  = ((v0.y >> 16)     << 12) | (cb - 3);
  p[4]  = ((v0.z & 0xFFFFu) << 12) | (cb - 4);
  p[5]  = ((v0.z >> 16)     << 12) | (cb - 5);
  p[6]  = ((v0.w & 0xFFFFu) << 12) | (cb - 6);
  p[7]  = ((v0.w >> 16)     << 12) | (cb - 7);
  p[8]  = ((v1.x & 0xFFFFu) << 12) | (cb - 8);
  p[9]  = ((v1.x >> 16)     << 12) | (cb - 9);
  p[10] = ((v1.y & 0xFFFFu) << 12) | (cb - 10);
  p[11] = ((v1.y >> 16)     << 12) | (cb - 11);
  p[12] = ((v1.z & 0xFFFFu) << 12) | (cb - 12);
  p[13] = ((v1.z >> 16)     << 12) | (cb - 13);
  p[14] = ((v1.w & 0xFFFFu) << 12) | (cb - 14);
  p[15] = ((v1.w >> 16)     << 12) | (cb - 15);

  for (int it = 0; it < 16; ++it) {
    uint_t m = p[0];
#pragma unroll
    for (int j = 1; j < 16; ++j) m = umax_(m, p[j]);
#pragma unroll
    for (int d = 1; d < 64; d <<= 1)
      m = umax_(m, (uint_t)__shfl_xor((int)m, d, 64));
    if (lane == it) cand[(w << 4) + it] = m;
#pragma unroll
    for (int j = 0; j < 16; ++j) p[j] = (p[j] == m) ? 0u : p[j];
  }
  __syncthreads();
  if (t < 64) {
    uint_t mine = cand[t];
    for (int it = 0; it < 16; ++it) {
      uint_t m = mine;
#pragma unroll
      for (int d = 1; d < 64; d <<= 1)
        m = umax_(m, (uint_t)__shfl_xor((int)m, d, 64));
      if (t == it) outIdx[(size_t)row * 16 + it] = 4095 - (int)(m & 0xFFFu);
      mine = (mine == m) ? 0u : mine;
    }
  }
}

// =====================================================================
// Fused rescore + gather: one block per batch row (16 candidates).
// =====================================================================
template<bool BFOUT>
__global__ __launch_bounds__(256)
void rescore_gather(const float* __restrict__ qn, const float* __restrict__ keys,
                    const float* __restrict__ rk, const int* __restrict__ cand,
                    void* __restrict__ ctxOut)
{
  __shared__ float qs[Ez];
  __shared__ double sv[16];
  __shared__ int si[16];
  __shared__ int sel10[10];
  const int row = blockIdx.x, t = threadIdx.x;
  const int w = t >> 6, lane = t & 63;

  {
    const float* qr = qn + (size_t)row * Ez;
#pragma unroll
    for (int i = 0; i < 3; ++i) {
      const int c = (t << 2) + (i << 10);
      *(float4*)&qs[c] = *(const float4*)&qr[c];
    }
  }
  __syncthreads();

#pragma unroll
  for (int cc = 0; cc < 4; ++cc) {
    const int slot = w * 4 + cc;
    const int id = cand[(size_t)row * 16 + slot];
    const float* kr = keys + (size_t)id * Ez;
    double s = 0.0;
#pragma unroll
    for (int it = 0; it < 12; ++it) {
      const int c = (lane << 2) + (it << 8);
      float4 k4 = *(const float4*)&kr[c];
      float4 q4 = *(const float4*)&qs[c];
      s += (double)q4.x * (double)k4.x;
      s += (double)q4.y * (double)k4.y;
      s += (double)q4.z * (double)k4.z;
      s += (double)q4.w * (double)k4.w;
    }
#pragma unroll
    for (int d = 32; d; d >>= 1) s += __shfl_down(s, d, 64);
    if (lane == 0) { sv[slot] = s * (double)rk[id]; si[slot] = id; }
  }
  __syncthreads();

  if (t == 0) {
    for (int it = 0; it < 10; ++it) {
      int bj = 0; double bvv = sv[0]; int bi = si[0];
      for (int j = 1; j < 16; ++j) {
        const double v = sv[j]; const int i2 = si[j];
        if (v > bvv || (v == bvv && i2 < bi)) { bj = j; bvv = v; bi = i2; }
      }
      sel10[it] = bi;
      sv[bj] = -1e300;
    }
  }
  __syncthreads();

  int id[10];
#pragma unroll
  for (int j = 0; j < 10; ++j) id[j] = sel10[j];

#pragma unroll
  for (int i = 0; i < 3; ++i) {
    const int c = (t << 2) + (i << 10);
    float4 a = {0.f, 0.f, 0.f, 0.f};
#pragma unroll
    for (int j = 0; j < 10; ++j) {
      float4 v = *(const float4*)&keys[(size_t)id[j] * Ez + c];
      a.x += v.x; a.y += v.y; a.z += v.z; a.w += v.w;
    }
    if (BFOUT) {
      ushort4 o;
      o.x = f2bf(a.x * 0.1f); o.y = f2bf(a.y * 0.1f);
      o.z = f2bf(a.z * 0.1f); o.w = f2bf(a.w * 0.1f);
      *(ushort4*)&((ushort_t*)ctxOut)[(size_t)row * Ez + c] = o;
    } else {
      float4 o;
      o.x = a.x * 0.1f; o.y = a.y * 0.1f; o.z = a.z * 0.1f; o.w = a.w * 0.1f;
      *(float4*)&((float*)ctxOut)[(size_t)row * Ez + c] = o;
    }
  }
}

// =====================================================================
// Router: 115 -> 64 -> 64 -> 4, clip, + gumbel, softmax, straight-through
// =====================================================================
__global__ __launch_bounds__(256)
void router_kernel(const float* __restrict__ state, const float* __restrict__ gn,
                   const float* __restrict__ w1, const float* __restrict__ b1,
                   const float* __restrict__ w2, const float* __restrict__ b2,
                   const float* __restrict__ w3, const float* __restrict__ b3,
                   float* __restrict__ outAlpha)
{
  const int row = blockIdx.x * 256 + threadIdx.x;
  const float* sr = state + (size_t)row * Sz;
  float h1[64];
#pragma unroll
  for (int j = 0; j < 64; ++j) h1[j] = b1[j];
  for (int k = 0; k < Sz; ++k) {
    const float a = sr[k];
    const float* wr = w1 + (size_t)k * 64;
#pragma unroll
    for (int j = 0; j < 64; ++j) h1[j] = fmaf(a, wr[j], h1[j]);
  }
#pragma unroll
  for (int j = 0; j < 64; ++j) h1[j] = fmaxf(h1[j], 0.f);
  float h2[64];
#pragma unroll
  for (int j = 0; j < 64; ++j) h2[j] = b2[j];
#pragma unroll
  for (int k = 0; k < 64; ++k) {
    const float a = h1[k];
    const float* wr = w2 + (size_t)k * 64;
#pragma unroll
    for (int j = 0; j < 64; ++j) h2[j] = fmaf(a, wr[j], h2[j]);
  }
#pragma unroll
  for (int j = 0; j < 64; ++j) h2[j] = fmaxf(h2[j], 0.f);
  float z[4];
#pragma unroll
  for (int a = 0; a < 4; ++a) {
    float s = b3[a];
#pragma unroll
    for (int k = 0; k < 64; ++k) s = fmaf(h2[k], w3[k * 4 + a], s);
    s = fminf(fmaxf(s, -20.f), 20.f);
    z[a] = s + gn[(size_t)row * 4 + a];   // TAU = 1
  }
  float mz = z[0];
#pragma unroll
  for (int a = 1; a < 4; ++a) mz = fmaxf(mz, z[a]);
  float e[4]; float se = 0.f;
#pragma unroll
  for (int a = 0; a < 4; ++a) { e[a] = expf(z[a] - mz); se += e[a]; }
  const float inv = 1.f / se;
  float y[4];
#pragma unroll
  for (int a = 0; a < 4; ++a) y[a] = e[a] * inv;
  int am = 0;
#pragma unroll
  for (int a = 1; a < 4; ++a) if (y[a] > y[am]) am = a;
#pragma unroll
  for (int a = 0; a < 4; ++a) {
    const float hard = (a == am) ? 1.f : 0.f;
    outAlpha[(size_t)row * 4 + a] = y[a] + (hard - y[a]);
  }
}

// critic head
__global__ __launch_bounds__(256)
void critic_head(const float* __restrict__ c2, const float* __restrict__ w3,
                 const float* __restrict__ b3, float* __restrict__ outv)
{
  const int row = blockIdx.x * 256 + threadIdx.x;
  const float* xr = c2 + (size_t)row * 256;
  float s = b3[0];
  for (int k = 0; k < 256; ++k) s = fmaf(xr[k], w3[k], s);
  outv[row] = s;
}

// all-4 actor heads fused; 32 rows/block (256 blocks = full GPU)
struct HeadP { const float* w3[4]; const float* b3[4]; };

__global__ __launch_bounds__(256)
void actor_head4(const float* __restrict__ x2g, HeadP p,
                 const float* __restrict__ alpha, float* __restrict__ outL)
{
  __shared__ float wsm[4][128 * 23];
  __shared__ float bs[4][23];
  const int t = threadIdx.x;
#pragma unroll
  for (int a = 0; a < 4; ++a) {
    for (int i = t; i < 128 * 23; i += 256) wsm[a][i] = p.w3[a][i];
    if (t < 23) bs[a][t] = p.b3[a][t];
  }
  __syncthreads();
  const int row = blockIdx.x * 32 + (t >> 3);
  const int cg = t & 7;
  float sum[3] = {0.f, 0.f, 0.f};
#pragma unroll
  for (int a = 0; a < 4; ++a) {
    const float al = alpha[(size_t)row * 4 + a];
    const float* xr = x2g + (size_t)a * Bz * 128 + (size_t)row * 128;
    float acc[3] = {0.f, 0.f, 0.f};
    for (int kk = 0; kk < 128; ++kk) {
      const float xa = xr[kk];
#pragma unroll
      for (int j = 0; j < 3; ++j) {
        const int col = cg + 8 * j;
        if (col < 23) acc[j] = fmaf(xa, wsm[a][kk * 23 + col], acc[j]);
      }
    }
#pragma unroll
    for (int j = 0; j < 3; ++j) {
      const int col = cg + 8 * j;
      if (col < 23) sum[j] += al * (acc[j] + bs[a][col]);
    }
  }
#pragma unroll
  for (int j = 0; j < 3; ++j) {
    const int col = cg + 8 * j;
    if (col < 23) outL[(size_t)row * 23 + col] = sum[j];
  }
}

// =====================================================================
extern "C" void kernel_launch(void* const* d_in, const int* in_sizes, int n_in,
                              void* d_out, int out_size, void* d_ws, size_t ws_size,
                              hipStream_t stream)
{
  const float* state  = (const float*)d_in[0];
  const float* gumbel = (const float*)d_in[1];
  const float* keys   = (const float*)d_in[2];
  const float* se_w1 = (const float*)d_in[3];
  const float* se_b1 = (const float*)d_in[4];
  const float* se_w2 = (const float*)d_in[5];
  const float* se_b2 = (const float*)d_in[6];
  const float* se_w3 = (const float*)d_in[7];
  const float* se_b3 = (const float*)d_in[8];
  const float* se_g  = (const float*)d_in[9];
  const float* se_be = (const float*)d_in[10];
  const float* cc_w1 = (const float*)d_in[11];
  const float* cc_b1 = (const float*)d_in[12];
  const float* cc_w2 = (const float*)d_in[13];
  const float* cc_b2 = (const float*)d_in[14];
  const float* cc_g  = (const float*)d_in[15];
  const float* cc_be = (const float*)d_in[16];
  const float* r_w1 = (const float*)d_in[57];
  const float* r_b1 = (const float*)d_in[58];
  const float* r_w2 = (const float*)d_in[59];
  const float* r_b2 = (const float*)d_in[60];
  const float* r_w3 = (const float*)d_in[61];
  const float* r_b3 = (const float*)d_in[62];
  const float* c_w1 = (const float*)d_in[63];
  const float* c_b1 = (const float*)d_in[64];
  const float* c_w2 = (const float*)d_in[65];
  const float* c_b2 = (const float*)d_in[66];
  const float* c_w3 = (const float*)d_in[67];
  const float* c_b3 = (const float*)d_in[68];

  // ---- workspace layout ----
  float* wsf = (float*)d_ws;
  const size_t qF = (size_t)Bz * Ez;          // 25,165,824 floats
  const size_t uF = (size_t)16777216;         // union region, floats
  float* q = wsf;
  float* U = wsf + qF;
  // U internal (time-multiplexed):
  float* sA  = U;                              // encoder ping   [0, 4.19M)
  float* sB  = U + 4194304;                    // encoder pong   [4.19M, 8.39M)
  ushort_t* sBh  = (ushort_t*)(U + 8388608);   // bf16 hi of sB
  ushort_t* sBl  = (ushort_t*)(U + 10485760);  // bf16 lo of sB
  ushort_t* w3hT = (ushort_t*)(U + 12582912);  // se_w3^T hi (3072x512)
  ushort_t* w3lT = (ushort_t*)(U + 14155776);  // se_w3^T lo
  ushort_t* scoresU = (ushort_t*)U;            // 8192x4096 u16 keys (whole U)
  float* shr = U;                              // 8192x128
  float* x1g = U + 1 * 1048576;                // 4 x 8192x128
  float* x2g = U + 5 * 1048576;                // 4 x 8192x128
  float* cch = U + 9 * 1048576;                // 8192x512
  // critic temporaries live in the (not yet written) q region:
  float* cr1 = q;                              // 8192x256
  float* cr2 = q + 2097152;                    // 8192x256
  // fast-path bf16 buffers after U:
  ushort_t* qbf  = (ushort_t*)(wsf + qF + uF);     // 8192x3072
  ushort_t* knbf = qbf + qF;                       // 4096x3072
  ushort_t* w1T  = knbf + (size_t)NEz * Ez;        // 512x3072
  const size_t bfHalves = qF + (size_t)NEz * Ez + (size_t)512 * Ez;
  const size_t baseBytes = (qF + uF) * sizeof(float);
  const size_t tailBytes = 4096 * 4 + (size_t)Bz * 16 * 4;
  const bool fast = ws_size >= baseBytes + bfHalves * 2 + tailBytes;
  float* tailF = (float*)((char*)d_ws + (fast ? baseBytes + bfHalves * 2 : baseBytes));
  float* rk  = tailF;
  int* cand  = (int*)(tailF + 4096);
  ushort_t* ctxb = (ushort_t*)q;               // bf16 ctx overlays dead q

  float* outL = (float*)d_out;                 // 8192*23
  float* outA = outL + (size_t)Bz * 23;        // 8192*4
  float* outV = outA + (size_t)Bz * 4;         // 8192*1

  const dim3 blk(256);

  // --- encoder layer 1 + critic layer 1 (horizontal fusion) ---
  {
    GPart e0 = {state, se_w1, se_b1, sA, nullptr, nullptr, 512, 115, 4};
    GPart e1 = {state, c_w1,  c_b1,  cr1, nullptr, nullptr, 256, 115, 2};
    gemm128_dual<<<dim3(6, 64), blk, 0, stream>>>(e0, e1);
  }
  // --- encoder layer 2 (+ fused bf16 hi/lo split) + critic layer 2 ---
  {
    GPart f0 = {sA, se_w2, se_b2, sB, fast ? sBh : nullptr, fast ? sBl : nullptr,
                512, 512, 4};
    GPart f1 = {cr1, c_w2, c_b2, cr2, nullptr, nullptr, 256, 256, 2};
    gemm128_dual<<<dim3(6, 64), blk, 0, stream>>>(f0, f1);
  }
  // critic head + router now (cr1/cr2 die before q is written)
  critic_head<<<dim3(32), blk, 0, stream>>>(cr2, c_w3, c_b3, outV);
  router_kernel<<<dim3(32), blk, 0, stream>>>(state, gumbel, r_w1, r_b1, r_w2, r_b2,
                                              r_w3, r_b3, outA);

  if (fast) {
    // se_w3 via bf16x3 split-precision MFMA (fp32-accurate)
    w3_transpose_split<<<dim3(8, 48), blk, 0, stream>>>(se_w3, w3hT, w3lT);
    mfma3_bt<<<dim3(24, 64), blk, 0, stream>>>(sBh, sBl, w3hT, w3lT, se_b3, q, 3072, 512);
    ln_l2_q<true><<<dim3(Bz), blk, 0, stream>>>(q, se_g, se_be, qbf);
    keys_norm_cvt<<<dim3(NEz), blk, 0, stream>>>(keys, rk, knbf);
    cvt_w1t_t<<<dim3(48, 8), blk, 0, stream>>>(cc_w1, w1T);
    mfma_bt<0><<<dim3(32, 64), blk, 0, stream>>>(qbf, knbf, nullptr, scoresU, NEz, Ez);
  } else {
    gemm128<false, true><<<dim3(24, 64), blk, 0, stream>>>(sB, se_w3, se_b3, q, 3072, 512);
    ln_l2_q<false><<<dim3(Bz), blk, 0, stream>>>(q, se_g, se_be, nullptr);
    keynorm<<<dim3(NEz), blk, 0, stream>>>(keys, rk);
    gemm_scores<<<dim3(32, 64), blk, 0, stream>>>(q, keys, rk, scoresU);
  }

  // --- top-16 screen, fused fp64 rescore + top-10 set + context gather ---
  topk16<<<dim3(Bz), blk, 0, stream>>>(scoresU, cand);

  // --- context + compressor ---
  if (fast) {
    rescore_gather<true><<<dim3(Bz), blk, 0, stream>>>(q, keys, rk, cand, ctxb);
    mfma_bt<1><<<dim3(4, 64), blk, 0, stream>>>(ctxb, w1T, cc_b1, cch, 512, Ez);
  } else {
    rescore_gather<false><<<dim3(Bz), blk, 0, stream>>>(q, keys, rk, cand, q);
    gemm128<true, true><<<dim3(4, 64), blk, 0, stream>>>(q, cc_w1, cc_b1, cch, 512, Ez);
  }
  {
    LN4 pcc = {};
    pcc.W[0] = cc_w2; pcc.b[0] = cc_b2; pcc.g[0] = cc_g; pcc.be[0] = cc_be;
    gemm_ln4<false, false><<<dim3(128, 1), blk, 0, stream>>>(cch, 0, 512, nullptr, pcc,
                                                             shr, 0);
  }

  // --- actors (batched over blockIdx.y) ---
  {
    LN4 p1 = {}, p2 = {};
    HeadP ph = {};
    const int eoffs[4] = {0, 20, 40, 45};
    const int elens[4] = {50, 20, 10, 15};
    for (int a = 0; a < 4; ++a) {
      const int base = 17 + 10 * a;
      p1.W[a]  = (const float*)d_in[base + 0];
      p1.b[a]  = (const float*)d_in[base + 1];
      p1.g[a]  = (const float*)d_in[base + 2];
      p1.be[a] = (const float*)d_in[base + 3];
      p1.eoff[a] = eoffs[a]; p1.elen[a] = elens[a];
      p2.W[a]  = (const float*)d_in[base + 4];
      p2.b[a]  = (const float*)d_in[base + 5];
      p2.g[a]  = (const float*)d_in[base + 6];
      p2.be[a] = (const float*)d_in[base + 7];
      ph.w3[a] = (const float*)d_in[base + 8];
      ph.b3[a] = (const float*)d_in[base + 9];
    }
    gemm_ln4<true, true ><<<dim3(128, 4), blk, 0, stream>>>(shr, 0, 128, state, p1,
                                                            x1g, (size_t)Bz * 128);
    gemm_ln4<true, false><<<dim3(128, 4), blk, 0, stream>>>(x1g, (size_t)Bz * 128, 128,
                                                            nullptr, p2,
                                                            x2g, (size_t)Bz * 128);
    actor_head4<<<dim3(256), blk, 0, stream>>>(x2g, ph, outA, outL);
  }
}

// Round 8
// 1311.839 us; speedup vs baseline: 3.3705x; 1.0103x over previous
//
#include <hip/hip_runtime.h>

// Problem constants (match reference)
constexpr int Bz = 8192;   // batch
constexpr int Sz = 115;    // state dim
constexpr int Ez = 3072;   // embedding dim
constexpr int NEz = 4096;  // num keys
// C=128, A=23, K=10, TAU=1, EPS=1e-5

typedef __attribute__((ext_vector_type(8))) short short8;
typedef __attribute__((ext_vector_type(4))) float floatx4;
typedef unsigned short ushort_t;
typedef unsigned int uint_t;

__device__ __forceinline__ ushort_t f2bf(float f) {
  uint_t u = __float_as_uint(f);
  uint_t r = (u + 0x7FFFu + ((u >> 16) & 1u)) >> 16;   // RNE
  return (ushort_t)r;
}
__device__ __forceinline__ float bf2f(ushort_t b) {
  uint_t u = ((uint_t)b) << 16;
  return __uint_as_float(u);
}
// fp32 -> fp16 -> order-preserving u16 key (monotone total order)
__device__ __forceinline__ ushort_t f2key(float v) {
  _Float16 h = (_Float16)v;
  ushort_t b = __builtin_bit_cast(ushort_t, h);
  return b ^ ((b & 0x8000u) ? 0xFFFFu : 0x8000u);
}
__device__ __forceinline__ uint_t umax_(uint_t a, uint_t b) { return a > b ? a : b; }

// async global->LDS, 16 B per lane; lds dest = wave-uniform base + lane*16
__device__ __forceinline__ void gload16(const ushort_t* g, ushort_t* l) {
  __builtin_amdgcn_global_load_lds(
      (__attribute__((address_space(1))) const void*)g,
      (__attribute__((address_space(3))) void*)l, 16, 0, 0);
}

// =====================================================================
// Generic fp32 tiled GEMM: C = act(A@B + bias). Used for critic L2 + fallback.
// =====================================================================
template<bool RELU, bool BIAS>
__global__ __launch_bounds__(256)
void gemm128(const float* __restrict__ A, const float* __restrict__ Bm,
             const float* __restrict__ bias, float* __restrict__ C,
             int N, int Kd)
{
  __shared__ float As[16][132];
  __shared__ float Bs[16][132];
  const int t  = threadIdx.x;
  const int tx = t & 15, ty = t >> 4;
  const int row0 = blockIdx.y * 128;
  const int col0 = blockIdx.x * 128;
  const int ar = t >> 2, ac = (t & 3) * 4;
  const int bk = t >> 5, bc = (t & 31) * 4;
  const bool a4 = (Kd & 3) == 0;

  float acc[8][8];
#pragma unroll
  for (int i = 0; i < 8; ++i)
#pragma unroll
    for (int j = 0; j < 8; ++j) acc[i][j] = 0.f;

  for (int k0 = 0; k0 < Kd; k0 += 16) {
    const bool fullA = (k0 + 16 <= Kd) && a4;
    {
      const float* ap = A + (size_t)(row0 + ar) * Kd + k0 + ac;
      if (fullA) {
        float4 v0 = *(const float4*)ap;
        float4 v1 = *(const float4*)(ap + (size_t)64 * Kd);
        As[ac + 0][ar] = v0.x; As[ac + 1][ar] = v0.y;
        As[ac + 2][ar] = v0.z; As[ac + 3][ar] = v0.w;
        As[ac + 0][ar + 64] = v1.x; As[ac + 1][ar + 64] = v1.y;
        As[ac + 2][ar + 64] = v1.z; As[ac + 3][ar + 64] = v1.w;
      } else {
#pragma unroll
        for (int e = 0; e < 4; ++e) {
          const int k = k0 + ac + e;
          float v0 = 0.f, v1 = 0.f;
          if (k < Kd) { v0 = ap[e]; v1 = ap[e + (size_t)64 * Kd]; }
          As[ac + e][ar] = v0; As[ac + e][ar + 64] = v1;
        }
      }
    }
    {
      const float* bp = Bm + (size_t)(k0 + bk) * N + col0 + bc;
      if (k0 + 16 <= Kd) {
        *(float4*)&Bs[bk][bc]     = *(const float4*)bp;
        *(float4*)&Bs[bk + 8][bc] = *(const float4*)(bp + (size_t)8 * N);
      } else {
        float4 z; z.x = z.y = z.z = z.w = 0.f;
        *(float4*)&Bs[bk][bc]     = (k0 + bk     < Kd) ? *(const float4*)bp : z;
        *(float4*)&Bs[bk + 8][bc] = (k0 + bk + 8 < Kd) ? *(const float4*)(bp + (size_t)8 * N) : z;
      }
    }
    __syncthreads();
#pragma unroll
    for (int kk = 0; kk < 16; ++kk) {
      float a[8], b[8];
      *(float4*)&a[0] = *(const float4*)&As[kk][ty * 4];
      *(float4*)&a[4] = *(const float4*)&As[kk][64 + ty * 4];
      *(float4*)&b[0] = *(const float4*)&Bs[kk][tx * 4];
      *(float4*)&b[4] = *(const float4*)&Bs[kk][64 + tx * 4];
#pragma unroll
      for (int i = 0; i < 8; ++i)
#pragma unroll
        for (int j = 0; j < 8; ++j)
          acc[i][j] = fmaf(a[i], b[j], acc[i][j]);
    }
    __syncthreads();
  }

  float bv[8];
#pragma unroll
  for (int j = 0; j < 8; ++j) bv[j] = 0.f;
  if (BIAS) {
    *(float4*)&bv[0] = *(const float4*)&bias[col0 + tx * 4];
    *(float4*)&bv[4] = *(const float4*)&bias[col0 + 64 + tx * 4];
  }
#pragma unroll
  for (int i = 0; i < 8; ++i) {
    const int r = row0 + ((i < 4) ? (ty * 4 + i) : (64 + ty * 4 + i - 4));
    float o[8];
#pragma unroll
    for (int j = 0; j < 8; ++j) {
      o[j] = acc[i][j] + bv[j];
      if (RELU) o[j] = fmaxf(o[j], 0.f);
    }
    *(float4*)&C[(size_t)r * N + col0 + tx * 4]      = *(float4*)&o[0];
    *(float4*)&C[(size_t)r * N + col0 + 64 + tx * 4] = *(float4*)&o[4];
  }
}

// =====================================================================
// Dual-part fp32 GEMM+ReLU+bias. Optional fp32 out (C) and bf16 hi/lo
// split outputs (Ch/Cl) — either may be null.
// =====================================================================
struct GPart {
  const float* A; const float* Bm; const float* bias;
  float* C; ushort_t* Ch; ushort_t* Cl;
  int N; int Kd; int nbx;
};

__global__ __launch_bounds__(256)
void gemm128_dual(GPart g0, GPart g1)
{
  __shared__ float As[16][132];
  __shared__ float Bs[16][132];
  const int t  = threadIdx.x;
  const int tx = t & 15, ty = t >> 4;
  const bool p0 = (int)blockIdx.x < g0.nbx;
  GPart g = p0 ? g0 : g1;
  const int bx = p0 ? blockIdx.x : (blockIdx.x - g0.nbx);
  const int row0 = blockIdx.y * 128;
  const int col0 = bx * 128;
  const int Kd = g.Kd, N = g.N;
  const int ar = t >> 2, ac = (t & 3) * 4;
  const int bk = t >> 5, bc = (t & 31) * 4;
  const bool a4 = (Kd & 3) == 0;

  float acc[8][8];
#pragma unroll
  for (int i = 0; i < 8; ++i)
#pragma unroll
    for (int j = 0; j < 8; ++j) acc[i][j] = 0.f;

  for (int k0 = 0; k0 < Kd; k0 += 16) {
    const bool fullA = (k0 + 16 <= Kd) && a4;
    {
      const float* ap = g.A + (size_t)(row0 + ar) * Kd + k0 + ac;
      if (fullA) {
        float4 v0 = *(const float4*)ap;
        float4 v1 = *(const float4*)(ap + (size_t)64 * Kd);
        As[ac + 0][ar] = v0.x; As[ac + 1][ar] = v0.y;
        As[ac + 2][ar] = v0.z; As[ac + 3][ar] = v0.w;
        As[ac + 0][ar + 64] = v1.x; As[ac + 1][ar + 64] = v1.y;
        As[ac + 2][ar + 64] = v1.z; As[ac + 3][ar + 64] = v1.w;
      } else {
#pragma unroll
        for (int e = 0; e < 4; ++e) {
          const int k = k0 + ac + e;
          float v0 = 0.f, v1 = 0.f;
          if (k < Kd) { v0 = ap[e]; v1 = ap[e + (size_t)64 * Kd]; }
          As[ac + e][ar] = v0; As[ac + e][ar + 64] = v1;
        }
      }
    }
    {
      const float* bp = g.Bm + (size_t)(k0 + bk) * N + col0 + bc;
      if (k0 + 16 <= Kd) {
        *(float4*)&Bs[bk][bc]     = *(const float4*)bp;
        *(float4*)&Bs[bk + 8][bc] = *(const float4*)(bp + (size_t)8 * N);
      } else {
        float4 z; z.x = z.y = z.z = z.w = 0.f;
        *(float4*)&Bs[bk][bc]     = (k0 + bk     < Kd) ? *(const float4*)bp : z;
        *(float4*)&Bs[bk + 8][bc] = (k0 + bk + 8 < Kd) ? *(const float4*)(bp + (size_t)8 * N) : z;
      }
    }
    __syncthreads();
#pragma unroll
    for (int kk = 0; kk < 16; ++kk) {
      float a[8], b[8];
      *(float4*)&a[0] = *(const float4*)&As[kk][ty * 4];
      *(float4*)&a[4] = *(const float4*)&As[kk][64 + ty * 4];
      *(float4*)&b[0] = *(const float4*)&Bs[kk][tx * 4];
      *(float4*)&b[4] = *(const float4*)&Bs[kk][64 + tx * 4];
#pragma unroll
      for (int i = 0; i < 8; ++i)
#pragma unroll
        for (int j = 0; j < 8; ++j)
          acc[i][j] = fmaf(a[i], b[j], acc[i][j]);
    }
    __syncthreads();
  }

  float bv[8];
  *(float4*)&bv[0] = *(const float4*)&g.bias[col0 + tx * 4];
  *(float4*)&bv[4] = *(const float4*)&g.bias[col0 + 64 + tx * 4];
#pragma unroll
  for (int i = 0; i < 8; ++i) {
    const int r = row0 + ((i < 4) ? (ty * 4 + i) : (64 + ty * 4 + i - 4));
    float o[8];
#pragma unroll
    for (int j = 0; j < 8; ++j) o[j] = fmaxf(acc[i][j] + bv[j], 0.f);
    const size_t i0 = (size_t)r * N + col0 + tx * 4;
    const size_t i1 = i0 + 64;
    if (g.C) {
      *(float4*)&g.C[i0] = *(float4*)&o[0];
      *(float4*)&g.C[i1] = *(float4*)&o[4];
    }
    if (g.Ch) {
      ushort4 h0, l0, h1, l1;
      h0.x = f2bf(o[0]); l0.x = f2bf(o[0] - bf2f(h0.x));
      h0.y = f2bf(o[1]); l0.y = f2bf(o[1] - bf2f(h0.y));
      h0.z = f2bf(o[2]); l0.z = f2bf(o[2] - bf2f(h0.z));
      h0.w = f2bf(o[3]); l0.w = f2bf(o[3] - bf2f(h0.w));
      h1.x = f2bf(o[4]); l1.x = f2bf(o[4] - bf2f(h1.x));
      h1.y = f2bf(o[5]); l1.y = f2bf(o[5] - bf2f(h1.y));
      h1.z = f2bf(o[6]); l1.z = f2bf(o[6] - bf2f(h1.z));
      h1.w = f2bf(o[7]); l1.w = f2bf(o[7] - bf2f(h1.w));
      *(ushort4*)&g.Ch[i0] = h0; *(ushort4*)&g.Cl[i0] = l0;
      *(ushort4*)&g.Ch[i1] = h1; *(ushort4*)&g.Cl[i1] = l1;
    }
  }
}

// =====================================================================
// bf16 MFMA screen GEMM, A(M x K) @ B(N x K)^T -> u16 score keys.
// BK = 32*NSUB sub-tiles (conflict-free per-sub-tile layout preserved).
// Kd must be a multiple of 32*NSUB.
// =====================================================================
template<int NSUB>
__global__ __launch_bounds__(256)
void mfma_bt(const ushort_t* __restrict__ A, const ushort_t* __restrict__ B,
             ushort_t* __restrict__ Cout, int N, int Kd)
{
  __shared__ ushort_t Al[NSUB * 4096];
  __shared__ ushort_t Bl[NSUB * 4096];
  const int t = threadIdx.x;
  const int wid = t >> 6, lane = t & 63;
  const int wr = wid >> 1, wc = wid & 1;
  const int row0 = blockIdx.y << 7;
  const int col0 = blockIdx.x << 7;
  const int srow = lane >> 2;
  const int scol = (lane & 3) * 8;

  const ushort_t* ga0 = A + (size_t)(row0 + wid * 16 + srow) * Kd + scol;
  const ushort_t* ga1 = A + (size_t)(row0 + (wid + 4) * 16 + srow) * Kd + scol;
  const ushort_t* gb0 = B + (size_t)(col0 + wid * 16 + srow) * Kd + scol;
  const ushort_t* gb1 = B + (size_t)(col0 + (wid + 4) * 16 + srow) * Kd + scol;
  ushort_t* la0 = &Al[wid * 512];
  ushort_t* la1 = &Al[(wid + 4) * 512];
  ushort_t* lb0 = &Bl[wid * 512];
  ushort_t* lb1 = &Bl[(wid + 4) * 512];

  const int mr = lane & 15, qd = lane >> 4;

  floatx4 acc[4][4];
#pragma unroll
  for (int i = 0; i < 4; ++i)
#pragma unroll
    for (int j = 0; j < 4; ++j) acc[i][j] = (floatx4){0.f, 0.f, 0.f, 0.f};

  for (int kb = 0; kb < Kd; kb += 32 * NSUB) {
#pragma unroll
    for (int tt = 0; tt < NSUB; ++tt) {
      const int ko = kb + 32 * tt;
      const int lo = tt * 4096;
      gload16(ga0 + ko, la0 + lo);
      gload16(ga1 + ko, la1 + lo);
      gload16(gb0 + ko, lb0 + lo);
      gload16(gb1 + ko, lb1 + lo);
    }
    __syncthreads();
#pragma unroll
    for (int tt = 0; tt < NSUB; ++tt) {
      const int lo = tt * 4096;
      short8 aF[4], bF[4];
#pragma unroll
      for (int i = 0; i < 4; ++i)
        aF[i] = *(const short8*)&Al[lo + (wr * 64 + i * 16 + mr) * 32 + qd * 8];
#pragma unroll
      for (int j = 0; j < 4; ++j)
        bF[j] = *(const short8*)&Bl[lo + (wc * 64 + j * 16 + mr) * 32 + qd * 8];
#pragma unroll
      for (int i = 0; i < 4; ++i)
#pragma unroll
        for (int j = 0; j < 4; ++j)
          acc[i][j] = __builtin_amdgcn_mfma_f32_16x16x32_bf16(aF[i], bF[j], acc[i][j], 0, 0, 0);
    }
    __syncthreads();
  }

#pragma unroll
  for (int i = 0; i < 4; ++i) {
#pragma unroll
    for (int j = 0; j < 4; ++j) {
      const int col = col0 + wc * 64 + j * 16 + mr;
#pragma unroll
      for (int r = 0; r < 4; ++r) {
        const int row = row0 + wr * 64 + i * 16 + qd * 4 + r;
        Cout[(size_t)row * N + col] = f2key(acc[i][j][r]);
      }
    }
  }
}

// =====================================================================
// bf16x3 split-precision MFMA GEMM (fp32-accurate): A@B^T + bias
// EPI=0: fp32 out (se_w3). EPI=1: relu then bf16 hi/lo split out (se_w2).
// =====================================================================
template<int EPI>
__global__ __launch_bounds__(256)
void mfma3_bt(const ushort_t* __restrict__ Ah, const ushort_t* __restrict__ Alo,
              const ushort_t* __restrict__ Bh, const ushort_t* __restrict__ Blo,
              const float* __restrict__ bias, float* __restrict__ Cout,
              ushort_t* __restrict__ Ch, ushort_t* __restrict__ Cl,
              int N, int Kd)
{
  __shared__ ushort_t AhL[128 * 32];
  __shared__ ushort_t AlL[128 * 32];
  __shared__ ushort_t BhL[128 * 32];
  __shared__ ushort_t BlL[128 * 32];
  const int t = threadIdx.x;
  const int wid = t >> 6, lane = t & 63;
  const int wr = wid >> 1, wc = wid & 1;
  const int row0 = blockIdx.y * 128;
  const int col0 = blockIdx.x * 128;
  const int srow = lane >> 2;
  const int scol = (lane & 3) * 8;

  const size_t aoff0 = (size_t)(row0 + wid * 16 + srow) * Kd + scol;
  const size_t aoff1 = (size_t)(row0 + (wid + 4) * 16 + srow) * Kd + scol;
  const size_t boff0 = (size_t)(col0 + wid * 16 + srow) * Kd + scol;
  const size_t boff1 = (size_t)(col0 + (wid + 4) * 16 + srow) * Kd + scol;
  const int l0 = (wid * 16) * 32;
  const int l1 = ((wid + 4) * 16) * 32;

  const int mr = lane & 15, qd = lane >> 4;

  floatx4 acc[4][4];
#pragma unroll
  for (int i = 0; i < 4; ++i)
#pragma unroll
    for (int j = 0; j < 4; ++j) acc[i][j] = (floatx4){0.f, 0.f, 0.f, 0.f};

  for (int kb = 0; kb < Kd; kb += 32) {
    gload16(Ah + aoff0 + kb, &AhL[l0]);
    gload16(Ah + aoff1 + kb, &AhL[l1]);
    gload16(Alo + aoff0 + kb, &AlL[l0]);
    gload16(Alo + aoff1 + kb, &AlL[l1]);
    gload16(Bh + boff0 + kb, &BhL[l0]);
    gload16(Bh + boff1 + kb, &BhL[l1]);
    gload16(Blo + boff0 + kb, &BlL[l0]);
    gload16(Blo + boff1 + kb, &BlL[l1]);
    __syncthreads();
    short8 ahF[4], alF[4], bhF[4], blF[4];
#pragma unroll
    for (int i = 0; i < 4; ++i) {
      const int o = (wr * 64 + i * 16 + mr) * 32 + qd * 8;
      ahF[i] = *(const short8*)&AhL[o];
      alF[i] = *(const short8*)&AlL[o];
    }
#pragma unroll
    for (int j = 0; j < 4; ++j) {
      const int o = (wc * 64 + j * 16 + mr) * 32 + qd * 8;
      bhF[j] = *(const short8*)&BhL[o];
      blF[j] = *(const short8*)&BlL[o];
    }
#pragma unroll
    for (int i = 0; i < 4; ++i)
#pragma unroll
      for (int j = 0; j < 4; ++j) {
        acc[i][j] = __builtin_amdgcn_mfma_f32_16x16x32_bf16(alF[i], bhF[j], acc[i][j], 0, 0, 0);
        acc[i][j] = __builtin_amdgcn_mfma_f32_16x16x32_bf16(ahF[i], blF[j], acc[i][j], 0, 0, 0);
        acc[i][j] = __builtin_amdgcn_mfma_f32_16x16x32_bf16(ahF[i], bhF[j], acc[i][j], 0, 0, 0);
      }
    __syncthreads();
  }

#pragma unroll
  for (int i = 0; i < 4; ++i) {
#pragma unroll
    for (int j = 0; j < 4; ++j) {
      const int col = col0 + wc * 64 + j * 16 + mr;
#pragma unroll
      for (int r = 0; r < 4; ++r) {
        const int row = row0 + wr * 64 + i * 16 + qd * 4 + r;
        const float v = acc[i][j][r] + bias[col];
        if (EPI == 0) {
          Cout[(size_t)row * N + col] = v;
        } else {
          const float y = fmaxf(v, 0.f);
          const ushort_t h = f2bf(y);
          Ch[(size_t)row * N + col] = h;
          Cl[(size_t)row * N + col] = f2bf(y - bf2f(h));
        }
      }
    }
  }
}

// =====================================================================
// bf16 MFMA GEMM, 64x128 tile (2 blocks/CU for cc_w1's small grid).
// A(M x K) bf16, B(N x K)^T bf16, out fp32 = relu(acc + bias).
// BK=64 (two BK=32 sub-tiles). Grid (N/128, M/64).
// =====================================================================
__global__ __launch_bounds__(256)
void mfma_bt64(const ushort_t* __restrict__ A, const ushort_t* __restrict__ B,
               const float* __restrict__ bias, float* __restrict__ Cout,
               int N, int Kd)
{
  __shared__ ushort_t Al[2 * 64 * 32];    // [sub][row][col]
  __shared__ ushort_t Bl[2 * 128 * 32];
  const int t = threadIdx.x;
  const int wid = t >> 6, lane = t & 63;
  const int row0 = blockIdx.y << 6;
  const int col0 = blockIdx.x << 7;
  const int srow = lane >> 2;
  const int scol = (lane & 3) * 8;
  const int mr = lane & 15, qd = lane >> 4;

  // precompute this wave's 6 staging chunks (chunk ids wid*6 .. wid*6+5)
  const ushort_t* gsrc[6];
  ushort_t* ldst[6];
#pragma unroll
  for (int m = 0; m < 6; ++m) {
    const int c = wid * 6 + m;
    if (c < 8) {        // A chunks: sub = c>>2, grp = c&3
      const int sub = c >> 2, grp = c & 3;
      gsrc[m] = A + (size_t)(row0 + grp * 16 + srow) * Kd + sub * 32 + scol;
      ldst[m] = &Al[sub * 2048 + (grp * 16 + srow) * 32];
    } else {            // B chunks: b = c-8, sub = b>>3, grp = b&7
      const int b = c - 8, sub = b >> 3, grp = b & 7;
      gsrc[m] = B + (size_t)(col0 + grp * 16 + srow) * Kd + sub * 32 + scol;
      ldst[m] = &Bl[sub * 4096 + (grp * 16 + srow) * 32];
    }
  }

  floatx4 acc[4][2];
#pragma unroll
  for (int i = 0; i < 4; ++i)
#pragma unroll
    for (int j = 0; j < 2; ++j) acc[i][j] = (floatx4){0.f, 0.f, 0.f, 0.f};

  for (int kb = 0; kb < Kd; kb += 64) {
#pragma unroll
    for (int m = 0; m < 6; ++m) gload16(gsrc[m] + kb, ldst[m]);
    __syncthreads();
#pragma unroll
    for (int sub = 0; sub < 2; ++sub) {
      short8 aF[4], bF[2];
#pragma unroll
      for (int i = 0; i < 4; ++i)
        aF[i] = *(const short8*)&Al[sub * 2048 + (i * 16 + mr) * 32 + qd * 8];
#pragma unroll
      for (int j = 0; j < 2; ++j)
        bF[j] = *(const short8*)&Bl[sub * 4096 + (wid * 32 + j * 16 + mr) * 32 + qd * 8];
#pragma unroll
      for (int i = 0; i < 4; ++i)
#pragma unroll
        for (int j = 0; j < 2; ++j)
          acc[i][j] = __builtin_amdgcn_mfma_f32_16x16x32_bf16(aF[i], bF[j], acc[i][j], 0, 0, 0);
    }
    __syncthreads();
  }

#pragma unroll
  for (int i = 0; i < 4; ++i) {
#pragma unroll
    for (int j = 0; j < 2; ++j) {
      const int col = col0 + wid * 32 + j * 16 + mr;
#pragma unroll
      for (int r = 0; r < 4; ++r) {
        const int row = row0 + i * 16 + qd * 4 + r;
        Cout[(size_t)row * N + col] = fmaxf(acc[i][j][r] + bias[col], 0.f);
      }
    }
  }
}

// =====================================================================
// fp32 scores GEMM (fallback path only) -> u16 score keys
// =====================================================================
__global__ __launch_bounds__(256)
void gemm_scores(const float* __restrict__ A, const float* __restrict__ Bm,
                 const float* __restrict__ rk, ushort_t* __restrict__ S)
{
  __shared__ float As[16][132];
  __shared__ float Bs[16][132];
  const int t  = threadIdx.x;
  const int tx = t & 15, ty = t >> 4;
  const int row0 = blockIdx.y * 128;
  const int col0 = blockIdx.x * 128;
  const int ar = t >> 2, ac = (t & 3) * 4;
  const int Kd = Ez;

  float acc[8][8];
#pragma unroll
  for (int i = 0; i < 8; ++i)
#pragma unroll
    for (int j = 0; j < 8; ++j) acc[i][j] = 0.f;

  for (int k0 = 0; k0 < Kd; k0 += 16) {
    {
      const float* ap = A + (size_t)(row0 + ar) * Kd + k0 + ac;
      float4 v0 = *(const float4*)ap;
      float4 v1 = *(const float4*)(ap + (size_t)64 * Kd);
      As[ac + 0][ar] = v0.x; As[ac + 1][ar] = v0.y;
      As[ac + 2][ar] = v0.z; As[ac + 3][ar] = v0.w;
      As[ac + 0][ar + 64] = v1.x; As[ac + 1][ar + 64] = v1.y;
      As[ac + 2][ar + 64] = v1.z; As[ac + 3][ar + 64] = v1.w;
    }
    {
      const float* bp = Bm + (size_t)(col0 + ar) * Kd + k0 + ac;
      float4 v0 = *(const float4*)bp;
      float4 v1 = *(const float4*)(bp + (size_t)64 * Kd);
      Bs[ac + 0][ar] = v0.x; Bs[ac + 1][ar] = v0.y;
      Bs[ac + 2][ar] = v0.z; Bs[ac + 3][ar] = v0.w;
      Bs[ac + 0][ar + 64] = v1.x; Bs[ac + 1][ar + 64] = v1.y;
      Bs[ac + 2][ar + 64] = v1.z; Bs[ac + 3][ar + 64] = v1.w;
    }
    __syncthreads();
#pragma unroll
    for (int kk = 0; kk < 16; ++kk) {
      float a[8], b[8];
      *(float4*)&a[0] = *(const float4*)&As[kk][ty * 4];
      *(float4*)&a[4] = *(const float4*)&As[kk][64 + ty * 4];
      *(float4*)&b[0] = *(const float4*)&Bs[kk][tx * 4];
      *(float4*)&b[4] = *(const float4*)&Bs[kk][64 + tx * 4];
#pragma unroll
      for (int i = 0; i < 8; ++i)
#pragma unroll
        for (int j = 0; j < 8; ++j)
          acc[i][j] = fmaf(a[i], b[j], acc[i][j]);
    }
    __syncthreads();
  }

  float rk0[8];
  *(float4*)&rk0[0] = *(const float4*)&rk[col0 + tx * 4];
  *(float4*)&rk0[4] = *(const float4*)&rk[col0 + 64 + tx * 4];
#pragma unroll
  for (int i = 0; i < 8; ++i) {
    const int r = row0 + ((i < 4) ? (ty * 4 + i) : (64 + ty * 4 + i - 4));
    ushort4 h0, h1;
    h0.x = f2key(acc[i][0] * rk0[0]); h0.y = f2key(acc[i][1] * rk0[1]);
    h0.z = f2key(acc[i][2] * rk0[2]); h0.w = f2key(acc[i][3] * rk0[3]);
    h1.x = f2key(acc[i][4] * rk0[4]); h1.y = f2key(acc[i][5] * rk0[5]);
    h1.z = f2key(acc[i][6] * rk0[6]); h1.w = f2key(acc[i][7] * rk0[7]);
    *(ushort4*)&S[(size_t)r * NEz + col0 + tx * 4]      = h0;
    *(ushort4*)&S[(size_t)r * NEz + col0 + 64 + tx * 4] = h1;
  }
}

// =====================================================================
// Batched (4-actor) fused GEMM(N=128) + LayerNorm (+ReLU).
// =====================================================================
struct LN4 {
  const float* W[4]; const float* b[4]; const float* g[4]; const float* be[4];
  int eoff[4]; int elen[4];
};

template<bool RELU, bool HASEXT>
__global__ __launch_bounds__(256)
void gemm_ln4(const float* __restrict__ A1base, size_t a1stride, int K1,
              const float* __restrict__ A2, LN4 p,
              float* __restrict__ outbase, size_t ostride)
{
  __shared__ float As[32][68];
  __shared__ float Bs[32][132];
  __shared__ float rsum[64][17];
  __shared__ float rsq[64][17];
  __shared__ float stm[64], str[64];
  const int a = blockIdx.y;
  const float* A1 = A1base + (size_t)a * a1stride;
  float* out = outbase + (size_t)a * ostride;
  const float* W = p.W[a];
  const float* bias = p.b[a];
  const float* g = p.g[a];
  const float* be = p.be[a];
  const int eoff = HASEXT ? p.eoff[a] : 0;
  const int K2 = HASEXT ? p.elen[a] : 0;

  const int t = threadIdx.x;
  const int tx = t & 15, ty = t >> 4;
  const int row0 = blockIdx.x * 64;
  const int Kt = K1 + K2;
  const int ar = t >> 2, ac = (t & 3) * 8;
  const int bk = t >> 3, bc = (t & 7) * 16;

  float acc[4][8];
#pragma unroll
  for (int i = 0; i < 4; ++i)
#pragma unroll
    for (int j = 0; j < 8; ++j) acc[i][j] = 0.f;

  for (int k0 = 0; k0 < Kt; k0 += 32) {
    const int grow = row0 + ar;
#pragma unroll
    for (int e = 0; e < 8; ++e) {
      const int k = k0 + ac + e;
      float v = 0.f;
      if (k < K1)      v = A1[(size_t)grow * K1 + k];
      else if (k < Kt) v = A2[(size_t)grow * 115 + eoff + (k - K1)];
      As[ac + e][ar] = v;
    }
    {
      const int k = k0 + bk;
#pragma unroll
      for (int qd = 0; qd < 4; ++qd) {
        float4 z; z.x = z.y = z.z = z.w = 0.f;
        *(float4*)&Bs[bk][bc + 4 * qd] =
            (k < Kt) ? *(const float4*)&W[(size_t)k * 128 + bc + 4 * qd] : z;
      }
    }
    __syncthreads();
#pragma unroll
    for (int kk = 0; kk < 32; ++kk) {
      float av[4], bv2[8];
      *(float4*)&av[0]  = *(const float4*)&As[kk][ty * 4];
      *(float4*)&bv2[0] = *(const float4*)&Bs[kk][tx * 4];
      *(float4*)&bv2[4] = *(const float4*)&Bs[kk][64 + tx * 4];
#pragma unroll
      for (int i = 0; i < 4; ++i)
#pragma unroll
        for (int j = 0; j < 8; ++j)
          acc[i][j] = fmaf(av[i], bv2[j], acc[i][j]);
    }
    __syncthreads();
  }

  float bv[8];
  *(float4*)&bv[0] = *(const float4*)&bias[tx * 4];
  *(float4*)&bv[4] = *(const float4*)&bias[64 + tx * 4];
#pragma unroll
  for (int i = 0; i < 4; ++i) {
    float s = 0.f, q = 0.f;
#pragma unroll
    for (int j = 0; j < 8; ++j) {
      acc[i][j] += bv[j];
      s += acc[i][j];
      q += acc[i][j] * acc[i][j];
    }
    rsum[ty * 4 + i][tx] = s;
    rsq[ty * 4 + i][tx]  = q;
  }
  __syncthreads();
  if (t < 64) {
    float s = 0.f, q = 0.f;
#pragma unroll
    for (int x = 0; x < 16; ++x) { s += rsum[t][x]; q += rsq[t][x]; }
    const float m = s * (1.f / 128.f);
    const float v = q * (1.f / 128.f) - m * m;
    stm[t] = m;
    str[t] = rsqrtf(v + 1e-5f);
  }
  __syncthreads();
#pragma unroll
  for (int i = 0; i < 4; ++i) {
    const int r = ty * 4 + i;
    const float m = stm[r], rs = str[r];
    float o[8];
#pragma unroll
    for (int j = 0; j < 8; ++j) {
      const int col = (j < 4) ? (tx * 4 + j) : (64 + tx * 4 + (j - 4));
      float y = (acc[i][j] - m) * rs * g[col] + be[col];
      if (RELU) y = fmaxf(y, 0.f);
      o[j] = y;
    }
    *(float4*)&out[(size_t)(row0 + r) * 128 + tx * 4]      = *(float4*)&o[0];
    *(float4*)&out[(size_t)(row0 + r) * 128 + 64 + tx * 4] = *(float4*)&o[4];
  }
}

// =====================================================================
// Block-wide (256 threads) sum helper
// =====================================================================
__device__ __forceinline__ float blockSum256(float v, float* sh)
{
#pragma unroll
  for (int d = 32; d; d >>= 1) v += __shfl_down(v, d, 64);
  __syncthreads();
  if ((threadIdx.x & 63) == 0) sh[threadIdx.x >> 6] = v;
  __syncthreads();
  return sh[0] + sh[1] + sh[2] + sh[3];
}

// Row LN (width 3072) + L2 normalize, in place; optional bf16 copy out
template<bool CVT>
__global__ __launch_bounds__(256)
void ln_l2_q(float* __restrict__ q, const float* __restrict__ g,
             const float* __restrict__ be, ushort_t* __restrict__ qb)
{
  __shared__ float sh[4];
  const int row = blockIdx.x, t = threadIdx.x;
  float* qr = q + (size_t)row * Ez;
  float x[12];
#pragma unroll
  for (int i = 0; i < 12; ++i) x[i] = qr[t + (i << 8)];
  float s = 0.f;
#pragma unroll
  for (int i = 0; i < 12; ++i) s += x[i];
  const float m = blockSum256(s, sh) * (1.f / (float)Ez);
  float vs = 0.f;
#pragma unroll
  for (int i = 0; i < 12; ++i) { const float d = x[i] - m; vs += d * d; }
  const float v = blockSum256(vs, sh) * (1.f / (float)Ez);
  const float rs = rsqrtf(v + 1e-5f);
  float y[12]; float qs = 0.f;
#pragma unroll
  for (int i = 0; i < 12; ++i) {
    const int c = t + (i << 8);
    const float yy = (x[i] - m) * rs * g[c] + be[c];
    y[i] = yy; qs += yy * yy;
  }
  const float tot = blockSum256(qs, sh);
  const float s2 = rsqrtf(tot + 1e-12f);
#pragma unroll
  for (int i = 0; i < 12; ++i) {
    const int c = t + (i << 8);
    const float yn = y[i] * s2;
    qr[c] = yn;
    if (CVT) qb[(size_t)row * Ez + c] = f2bf(yn);
  }
}

// rk[n] only (fallback)
__global__ __launch_bounds__(256)
void keynorm(const float* __restrict__ keys, float* __restrict__ rk)
{
  __shared__ float sh[4];
  const int row = blockIdx.x, t = threadIdx.x;
  const float* xr = keys + (size_t)row * Ez;
  float qs = 0.f;
#pragma unroll
  for (int i = 0; i < 12; ++i) { const float x = xr[t + (i << 8)]; qs += x * x; }
  const float tot = blockSum256(qs, sh);
  if (t == 0) rk[row] = rsqrtf(tot + 1e-12f);
}

// fused: rk[n] + knbf[n,:] = bf16(keys[n,:] * rk[n])
__global__ __launch_bounds__(256)
void keys_norm_cvt(const float* __restrict__ keys, float* __restrict__ rk,
                   ushort_t* __restrict__ knb)
{
  __shared__ float sh[4];
  const int row = blockIdx.x, t = threadIdx.x;
  const float* xr = keys + (size_t)row * Ez;
  float x[12]; float qs = 0.f;
#pragma unroll
  for (int i = 0; i < 12; ++i) { x[i] = xr[t + (i << 8)]; qs += x[i] * x[i]; }
  const float tot = blockSum256(qs, sh);
  const float s = rsqrtf(tot + 1e-12f);
  if (t == 0) rk[row] = s;
#pragma unroll
  for (int i = 0; i < 12; ++i)
    knb[(size_t)row * Ez + t + (i << 8)] = f2bf(x[i] * s);
}

// W (512 x C fp32) -> transposed hi/lo bf16 (C x 512 each). Grid (8, C/64).
__global__ __launch_bounds__(256)
void wt_split(const float* __restrict__ w, ushort_t* __restrict__ hT,
              ushort_t* __restrict__ lT, int C)
{
  __shared__ float tile[64][65];
  const int k0 = blockIdx.x * 64;
  const int n0 = blockIdx.y * 64;
  const int t = threadIdx.x;
  const int c = t & 63, r4 = t >> 6;
#pragma unroll
  for (int rr = 0; rr < 16; ++rr) {
    const int r = rr * 4 + r4;
    tile[r][c] = w[(size_t)(k0 + r) * C + n0 + c];
  }
  __syncthreads();
#pragma unroll
  for (int rr = 0; rr < 16; ++rr) {
    const int n = rr * 4 + r4;
    const float a = tile[c][n];
    const ushort_t h = f2bf(a);
    hT[(size_t)(n0 + n) * 512 + k0 + c] = h;
    lT[(size_t)(n0 + n) * 512 + k0 + c] = f2bf(a - bf2f(h));
  }
}

// cc_w1 (3072 x 512 fp32) -> transposed bf16 (512 x 3072), coalesced
__global__ __launch_bounds__(256)
void cvt_w1t_t(const float* __restrict__ w, ushort_t* __restrict__ out)
{
  __shared__ float tile[64][65];
  const int k0 = blockIdx.x * 64;   // 48 blocks
  const int n0 = blockIdx.y * 64;   // 8 blocks
  const int t = threadIdx.x;
  const int c = t & 63, r4 = t >> 6;
#pragma unroll
  for (int rr = 0; rr < 16; ++rr) {
    const int r = rr * 4 + r4;
    tile[r][c] = w[(size_t)(k0 + r) * 512 + n0 + c];
  }
  __syncthreads();
#pragma unroll
  for (int rr = 0; rr < 16; ++rr) {
    const int n = rr * 4 + r4;
    out[(size_t)(n0 + n) * Ez + k0 + c] = f2bf(tile[c][n]);
  }
}

// =====================================================================
// Top-16 per row of the 8192 x 4096 u16-key score matrix.
// =====================================================================
__global__ __launch_bounds__(256)
void topk16(const ushort_t* __restrict__ S, int* __restrict__ outIdx)
{
  __shared__ uint_t cand[64];
  const int row = blockIdx.x, t = threadIdx.x;
  const int w = t >> 6, lane = t & 63;
  const int base = (w << 10) + (lane << 4);
  const ushort_t* sr = S + (size_t)row * NEz + base;
  uint4 v0 = *(const uint4*)sr;
  uint4 v1 = *(const uint4*)(sr + 8);
  const uint_t cb = (uint_t)(4095 - base);
  uint_t p[16];
  p[0]  = ((v0.x & 0xFFFFu) << 12) | (cb - 0);
  p[1]  = ((v0.x >> 16)     << 12) | (cb - 1);
  p[2]  = ((v0.y & 0xFFFFu) << 12) | (cb - 2);
  p[3]  = ((v0.y >> 16)     << 12) | (cb - 3);
  p[4]  = ((v0.z & 0xFFFFu) << 12) | (cb - 4);
  p[5]  = ((v0.z >> 16)     << 12) | (cb - 5);
  p[6]  = ((v0.w & 0xFFFFu) << 12) | (cb - 6);
  p[7]  = ((v0.w >> 16)     << 12) | (cb - 7);
  p[8]  = ((v1.x & 0xFFFFu) << 12) | (cb - 8);
  p[9]  = ((v1.x >> 16)     << 12) | (cb - 9);
  p[10] = ((v1.y & 0xFFFFu) << 12) | (cb - 10);
  p[11] = ((v1.y >> 16)     << 12) | (cb - 11);
  p[12] = ((v1.z & 0xFFFFu) << 12) | (cb - 12);
  p[13] = ((v1.z >> 16)     << 12) | (cb - 13);
  p[14] = ((v1.w & 0xFFFFu) << 12) | (cb - 14);
  p[15] = ((v1.w >> 16)     << 12) | (cb - 15);

  for (int it = 0; it < 16; ++it) {
    uint_t m = p[0];
#pragma unroll
    for (int j = 1; j < 16; ++j) m = umax_(m, p[j]);
#pragma unroll
    for (int d = 1; d < 64; d <<= 1)
      m = umax_(m, (uint_t)__shfl_xor((int)m, d, 64));
    if (lane == it) cand[(w << 4) + it] = m;
#pragma unroll
    for (int j = 0; j < 16; ++j) p[j] = (p[j] == m) ? 0u : p[j];
  }
  __syncthreads();
  if (t < 64) {
    uint_t mine = cand[t];
    for (int it = 0; it < 16; ++it) {
      uint_t m = mine;
#pragma unroll
      for (int d = 1; d < 64; d <<= 1)
        m = umax_(m, (uint_t)__shfl_xor((int)m, d, 64));
      if (t == it) outIdx[(size_t)row * 16 + it] = 4095 - (int)(m & 0xFFFu);
      mine = (mine == m) ? 0u : mine;
    }
  }
}

// =====================================================================
// Fused rescore + gather: one block per batch row (16 candidates).
// ctxOut must NOT alias qn (fast path uses separate region).
// =====================================================================
template<bool BFOUT>
__global__ __launch_bounds__(256)
void rescore_gather(const float* __restrict__ qn, const float* __restrict__ keys,
                    const float* __restrict__ rk, const int* __restrict__ cand,
                    void* __restrict__ ctxOut)
{
  __shared__ float qs[Ez];
  __shared__ double sv[16];
  __shared__ int si[16];
  __shared__ int sel10[10];
  const int row = blockIdx.x, t = threadIdx.x;
  const int w = t >> 6, lane = t & 63;

  {
    const float* qr = qn + (size_t)row * Ez;
#pragma unroll
    for (int i = 0; i < 3; ++i) {
      const int c = (t << 2) + (i << 10);
      *(float4*)&qs[c] = *(const float4*)&qr[c];
    }
  }
  __syncthreads();

#pragma unroll
  for (int cc = 0; cc < 4; ++cc) {
    const int slot = w * 4 + cc;
    const int id = cand[(size_t)row * 16 + slot];
    const float* kr = keys + (size_t)id * Ez;
    double s = 0.0;
#pragma unroll
    for (int it = 0; it < 12; ++it) {
      const int c = (lane << 2) + (it << 8);
      float4 k4 = *(const float4*)&kr[c];
      float4 q4 = *(const float4*)&qs[c];
      s += (double)q4.x * (double)k4.x;
      s += (double)q4.y * (double)k4.y;
      s += (double)q4.z * (double)k4.z;
      s += (double)q4.w * (double)k4.w;
    }
#pragma unroll
    for (int d = 32; d; d >>= 1) s += __shfl_down(s, d, 64);
    if (lane == 0) { sv[slot] = s * (double)rk[id]; si[slot] = id; }
  }
  __syncthreads();

  if (t == 0) {
    for (int it = 0; it < 10; ++it) {
      int bj = 0; double bvv = sv[0]; int bi = si[0];
      for (int j = 1; j < 16; ++j) {
        const double v = sv[j]; const int i2 = si[j];
        if (v > bvv || (v == bvv && i2 < bi)) { bj = j; bvv = v; bi = i2; }
      }
      sel10[it] = bi;
      sv[bj] = -1e300;
    }
  }
  __syncthreads();

  int id[10];
#pragma unroll
  for (int j = 0; j < 10; ++j) id[j] = sel10[j];

#pragma unroll
  for (int i = 0; i < 3; ++i) {
    const int c = (t << 2) + (i << 10);
    float4 a = {0.f, 0.f, 0.f, 0.f};
#pragma unroll
    for (int j = 0; j < 10; ++j) {
      float4 v = *(const float4*)&keys[(size_t)id[j] * Ez + c];
      a.x += v.x; a.y += v.y; a.z += v.z; a.w += v.w;
    }
    if (BFOUT) {
      ushort4 o;
      o.x = f2bf(a.x * 0.1f); o.y = f2bf(a.y * 0.1f);
      o.z = f2bf(a.z * 0.1f); o.w = f2bf(a.w * 0.1f);
      *(ushort4*)&((ushort_t*)ctxOut)[(size_t)row * Ez + c] = o;
    } else {
      float4 o;
      o.x = a.x * 0.1f; o.y = a.y * 0.1f; o.z = a.z * 0.1f; o.w = a.w * 0.1f;
      *(float4*)&((float*)ctxOut)[(size_t)row * Ez + c] = o;
    }
  }
}

// =====================================================================
// Router: 115 -> 64 -> 64 -> 4, clip, + gumbel, softmax, straight-through
// =====================================================================
__global__ __launch_bounds__(256)
void router_kernel(const float* __restrict__ state, const float* __restrict__ gn,
                   const float* __restrict__ w1, const float* __restrict__ b1,
                   const float* __restrict__ w2, const float* __restrict__ b2,
                   const float* __restrict__ w3, const float* __restrict__ b3,
                   float* __restrict__ outAlpha)
{
  const int row = blockIdx.x * 256 + threadIdx.x;
  const float* sr = state + (size_t)row * Sz;
  float h1[64];
#pragma unroll
  for (int j = 0; j < 64; ++j) h1[j] = b1[j];
  for (int k = 0; k < Sz; ++k) {
    const float a = sr[k];
    const float* wr = w1 + (size_t)k * 64;
#pragma unroll
    for (int j = 0; j < 64; ++j) h1[j] = fmaf(a, wr[j], h1[j]);
  }
#pragma unroll
  for (int j = 0; j < 64; ++j) h1[j] = fmaxf(h1[j], 0.f);
  float h2[64];
#pragma unroll
  for (int j = 0; j < 64; ++j) h2[j] = b2[j];
#pragma unroll
  for (int k = 0; k < 64; ++k) {
    const float a = h1[k];
    const float* wr = w2 + (size_t)k * 64;
#pragma unroll
    for (int j = 0; j < 64; ++j) h2[j] = fmaf(a, wr[j], h2[j]);
  }
#pragma unroll
  for (int j = 0; j < 64; ++j) h2[j] = fmaxf(h2[j], 0.f);
  float z[4];
#pragma unroll
  for (int a = 0; a < 4; ++a) {
    float s = b3[a];
#pragma unroll
    for (int k = 0; k < 64; ++k) s = fmaf(h2[k], w3[k * 4 + a], s);
    s = fminf(fmaxf(s, -20.f), 20.f);
    z[a] = s + gn[(size_t)row * 4 + a];   // TAU = 1
  }
  float mz = z[0];
#pragma unroll
  for (int a = 1; a < 4; ++a) mz = fmaxf(mz, z[a]);
  float e[4]; float se = 0.f;
#pragma unroll
  for (int a = 0; a < 4; ++a) { e[a] = expf(z[a] - mz); se += e[a]; }
  const float inv = 1.f / se;
  float y[4];
#pragma unroll
  for (int a = 0; a < 4; ++a) y[a] = e[a] * inv;
  int am = 0;
#pragma unroll
  for (int a = 1; a < 4; ++a) if (y[a] > y[am]) am = a;
#pragma unroll
  for (int a = 0; a < 4; ++a) {
    const float hard = (a == am) ? 1.f : 0.f;
    outAlpha[(size_t)row * 4 + a] = y[a] + (hard - y[a]);
  }
}

// critic head, coalesced: 128 blocks, wave handles 16 rows, lane = 4 cols
__global__ __launch_bounds__(256)
void critic_head(const float* __restrict__ c2, const float* __restrict__ w3,
                 const float* __restrict__ b3, float* __restrict__ outv)
{
  const int t = threadIdx.x;
  const int w = t >> 6, lane = t & 63;
  const int row0 = blockIdx.x * 64 + w * 16;
  float wv[4];
  *(float4*)&wv[0] = *(const float4*)&w3[lane * 4];
  const float b0 = b3[0];
#pragma unroll
  for (int rr = 0; rr < 16; ++rr) {
    const int row = row0 + rr;
    float4 x = *(const float4*)&c2[(size_t)row * 256 + lane * 4];
    float s = x.x * wv[0] + x.y * wv[1] + x.z * wv[2] + x.w * wv[3];
#pragma unroll
    for (int d = 32; d; d >>= 1) s += __shfl_down(s, d, 64);
    if (lane == 0) outv[row] = s + b0;
  }
}

// all-4 actor heads fused; 32 rows/block (256 blocks = full GPU)
struct HeadP { const float* w3[4]; const float* b3[4]; };

__global__ __launch_bounds__(256)
void actor_head4(const float* __restrict__ x2g, HeadP p,
                 const float* __restrict__ alpha, float* __restrict__ outL)
{
  __shared__ float wsm[4][128 * 23];
  __shared__ float bs[4][23];
  const int t = threadIdx.x;
#pragma unroll
  for (int a = 0; a < 4; ++a) {
    for (int i = t; i < 128 * 23; i += 256) wsm[a][i] = p.w3[a][i];
    if (t < 23) bs[a][t] = p.b3[a][t];
  }
  __syncthreads();
  const int row = blockIdx.x * 32 + (t >> 3);
  const int cg = t & 7;
  float sum[3] = {0.f, 0.f, 0.f};
#pragma unroll
  for (int a = 0; a < 4; ++a) {
    const float al = alpha[(size_t)row * 4 + a];
    const float* xr = x2g + (size_t)a * Bz * 128 + (size_t)row * 128;
    float acc[3] = {0.f, 0.f, 0.f};
    for (int kk = 0; kk < 128; ++kk) {
      const float xa = xr[kk];
#pragma unroll
      for (int j = 0; j < 3; ++j) {
        const int col = cg + 8 * j;
        if (col < 23) acc[j] = fmaf(xa, wsm[a][kk * 23 + col], acc[j]);
      }
    }
#pragma unroll
    for (int j = 0; j < 3; ++j) {
      const int col = cg + 8 * j;
      if (col < 23) sum[j] += al * (acc[j] + bs[a][col]);
    }
  }
#pragma unroll
  for (int j = 0; j < 3; ++j) {
    const int col = cg + 8 * j;
    if (col < 23) outL[(size_t)row * 23 + col] = sum[j];
  }
}

// =====================================================================
extern "C" void kernel_launch(void* const* d_in, const int* in_sizes, int n_in,
                              void* d_out, int out_size, void* d_ws, size_t ws_size,
                              hipStream_t stream)
{
  const float* state  = (const float*)d_in[0];
  const float* gumbel = (const float*)d_in[1];
  const float* keys   = (const float*)d_in[2];
  const float* se_w1 = (const float*)d_in[3];
  const float* se_b1 = (const float*)d_in[4];
  const float* se_w2 = (const float*)d_in[5];
  const float* se_b2 = (const float*)d_in[6];
  const float* se_w3 = (const float*)d_in[7];
  const float* se_b3 = (const float*)d_in[8];
  const float* se_g  = (const float*)d_in[9];
  const float* se_be = (const float*)d_in[10];
  const float* cc_w1 = (const float*)d_in[11];
  const float* cc_b1 = (const float*)d_in[12];
  const float* cc_w2 = (const float*)d_in[13];
  const float* cc_b2 = (const float*)d_in[14];
  const float* cc_g  = (const float*)d_in[15];
  const float* cc_be = (const float*)d_in[16];
  const float* r_w1 = (const float*)d_in[57];
  const float* r_b1 = (const float*)d_in[58];
  const float* r_w2 = (const float*)d_in[59];
  const float* r_b2 = (const float*)d_in[60];
  const float* r_w3 = (const float*)d_in[61];
  const float* r_b3 = (const float*)d_in[62];
  const float* c_w1 = (const float*)d_in[63];
  const float* c_b1 = (const float*)d_in[64];
  const float* c_w2 = (const float*)d_in[65];
  const float* c_b2 = (const float*)d_in[66];
  const float* c_w3 = (const float*)d_in[67];
  const float* c_b3 = (const float*)d_in[68];

  // ---- workspace layout ----
  float* wsf = (float*)d_ws;
  const size_t qF = (size_t)Bz * Ez;          // 25,165,824 floats
  const size_t uF = (size_t)16777216;         // union region, floats
  float* q = wsf;
  float* U = wsf + qF;
  // U internal (time-multiplexed), float offsets:
  ushort_t* sAh  = (ushort_t*)(U + 0);          // 8192x512 halves
  ushort_t* sAl  = (ushort_t*)(U + 2097152);
  ushort_t* sBh  = (ushort_t*)(U + 4194304);
  ushort_t* sBl  = (ushort_t*)(U + 6291456);
  ushort_t* w3hT = (ushort_t*)(U + 8388608);    // 3072x512 halves
  ushort_t* w3lT = (ushort_t*)(U + 9175040);
  ushort_t* w2hT = (ushort_t*)(U + 9961472);    // 512x512 halves
  ushort_t* w2lT = (ushort_t*)(U + 10092544);
  // fallback path fp32 buffers (same region, stream-ordered):
  float* sA = U;                                 // 8192x512 fp32 (fallback)
  float* sB = U + 4194304;                       // 8192x512 fp32 (fallback)
  ushort_t* scoresU = (ushort_t*)U;              // 8192x4096 u16 (whole U)
  ushort_t* ctxb = (ushort_t*)U;                 // bf16 ctx (8192x3072 halves),
                                                 // overlays dead scores post-topk
  float* cch = U + 12582912;                     // 8192x512 fp32
  float* shr = U;                                // 8192x128 (post-ctx phase)
  float* x1g = U + 1 * 1048576;                  // 4 x 8192x128
  float* x2g = U + 5 * 1048576;                  // 4 x 8192x128
  // critic temporaries in the (not yet written) q region:
  float* cr1 = q;                                // 8192x256
  float* cr2 = q + 2097152;                      // 8192x256
  // fast-path bf16 buffers after U:
  ushort_t* qbf  = (ushort_t*)(wsf + qF + uF);   // 8192x3072
  ushort_t* knbf = qbf + qF;                     // 4096x3072
  ushort_t* w1T  = knbf + (size_t)NEz * Ez;      // 512x3072
  const size_t bfHalves = qF + (size_t)NEz * Ez + (size_t)512 * Ez;
  const size_t baseBytes = (qF + uF) * sizeof(float);
  const size_t tailBytes = 4096 * 4 + (size_t)Bz * 16 * 4;
  const bool fast = ws_size >= baseBytes + bfHalves * 2 + tailBytes;
  float* tailF = (float*)((char*)d_ws + (fast ? baseBytes + bfHalves * 2 : baseBytes));
  float* rk  = tailF;
  int* cand  = (int*)(tailF + 4096);

  float* outL = (float*)d_out;                 // 8192*23
  float* outA = outL + (size_t)Bz * 23;        // 8192*4
  float* outV = outA + (size_t)Bz * 4;         // 8192*1

  const dim3 blk(256);

  // --- encoder L1 (hi/lo split out on fast path) + critic L1 ---
  {
    GPart e0 = {state, se_w1, se_b1, fast ? nullptr : sA,
                fast ? sAh : nullptr, fast ? sAl : nullptr, 512, 115, 4};
    GPart e1 = {state, c_w1, c_b1, cr1, nullptr, nullptr, 256, 115, 2};
    gemm128_dual<<<dim3(6, 64), blk, 0, stream>>>(e0, e1);
  }
  // --- critic L2 (fp32) ---
  gemm128<true, true><<<dim3(2, 64), blk, 0, stream>>>(cr1, c_w2, c_b2, cr2, 256, 256);

  if (fast) {
    // weight preps
    wt_split<<<dim3(8, 8),  blk, 0, stream>>>(se_w2, w2hT, w2lT, 512);
    wt_split<<<dim3(8, 48), blk, 0, stream>>>(se_w3, w3hT, w3lT, 3072);
    // encoder L2 via bf16x3 MFMA: relu + hi/lo split out
    mfma3_bt<1><<<dim3(4, 64), blk, 0, stream>>>(sAh, sAl, w2hT, w2lT, se_b2,
                                                 nullptr, sBh, sBl, 512, 512);
  } else {
    gemm128<true, true><<<dim3(4, 64), blk, 0, stream>>>(sA, se_w2, se_b2, sB, 512, 512);
  }

  // critic head + router (cr1/cr2 die before q is written)
  critic_head<<<dim3(128), blk, 0, stream>>>(cr2, c_w3, c_b3, outV);
  router_kernel<<<dim3(32), blk, 0, stream>>>(state, gumbel, r_w1, r_b1, r_w2, r_b2,
                                              r_w3, r_b3, outA);

  if (fast) {
    // encoder L3 (se_w3) via bf16x3 MFMA -> q fp32
    mfma3_bt<0><<<dim3(24, 64), blk, 0, stream>>>(sBh, sBl, w3hT, w3lT, se_b3,
                                                  q, nullptr, nullptr, 3072, 512);
    ln_l2_q<true><<<dim3(Bz), blk, 0, stream>>>(q, se_g, se_be, qbf);
    keys_norm_cvt<<<dim3(NEz), blk, 0, stream>>>(keys, rk, knbf);
    cvt_w1t_t<<<dim3(48, 8), blk, 0, stream>>>(cc_w1, w1T);
    // screen: BK=96 (3 sub-tiles)
    mfma_bt<3><<<dim3(32, 64), blk, 0, stream>>>(qbf, knbf, scoresU, NEz, Ez);
  } else {
    gemm128<false, true><<<dim3(24, 64), blk, 0, stream>>>(sB, se_w3, se_b3, q, 3072, 512);
    ln_l2_q<false><<<dim3(Bz), blk, 0, stream>>>(q, se_g, se_be, nullptr);
    keynorm<<<dim3(NEz), blk, 0, stream>>>(keys, rk);
    gemm_scores<<<dim3(32, 64), blk, 0, stream>>>(q, keys, rk, scoresU);
  }

  // --- top-16 screen, fused fp64 rescore + top-10 set + context gather ---
  topk16<<<dim3(Bz), blk, 0, stream>>>(scoresU, cand);

  // --- context + compressor ---
  if (fast) {
    // ctx -> ctxb in U (scores dead after topk; NO aliasing with q)
    rescore_gather<true><<<dim3(Bz), blk, 0, stream>>>(q, keys, rk, cand, ctxb);
    mfma_bt64<<<dim3(4, 128), blk, 0, stream>>>(ctxb, w1T, cc_b1, cch, 512, Ez);
  } else {
    // fallback: ctx fp32 overlays q row-for-row (self-row only: safe)
    rescore_gather<false><<<dim3(Bz), blk, 0, stream>>>(q, keys, rk, cand, q);
    gemm128<true, true><<<dim3(4, 64), blk, 0, stream>>>(q, cc_w1, cc_b1, cch, 512, Ez);
  }
  {
    LN4 pcc = {};
    pcc.W[0] = cc_w2; pcc.b[0] = cc_b2; pcc.g[0] = cc_g; pcc.be[0] = cc_be;
    gemm_ln4<false, false><<<dim3(128, 1), blk, 0, stream>>>(cch, 0, 512, nullptr, pcc,
                                                             shr, 0);
  }

  // --- actors (batched over blockIdx.y) ---
  {
    LN4 p1 = {}, p2 = {};
    HeadP ph = {};
    const int eoffs[4] = {0, 20, 40, 45};
    const int elens[4] = {50, 20, 10, 15};
    for (int a = 0; a < 4; ++a) {
      const int base = 17 + 10 * a;
      p1.W[a]  = (const float*)d_in[base + 0];
      p1.b[a]  = (const float*)d_in[base + 1];
      p1.g[a]  = (const float*)d_in[base + 2];
      p1.be[a] = (const float*)d_in[base + 3];
      p1.eoff[a] = eoffs[a]; p1.elen[a] = elens[a];
      p2.W[a]  = (const float*)d_in[base + 4];
      p2.b[a]  = (const float*)d_in[base + 5];
      p2.g[a]  = (const float*)d_in[base + 6];
      p2.be[a] = (const float*)d_in[base + 7];
      ph.w3[a] = (const float*)d_in[base + 8];
      ph.b3[a] = (const float*)d_in[base + 9];
    }
    gemm_ln4<true, true ><<<dim3(128, 4), blk, 0, stream>>>(shr, 0, 128, state, p1,
                                                            x1g, (size_t)Bz * 128);
    gemm_ln4<true, false><<<dim3(128, 4), blk, 0, stream>>>(x1g, (size_t)Bz * 128, 128,
                                                            nullptr, p2,
                                                            x2g, (size_t)Bz * 128);
    actor_head4<<<dim3(256), blk, 0, stream>>>(x2g, ph, outA, outL);
  }
}

// Round 9
// 1281.278 us; speedup vs baseline: 3.4509x; 1.0239x over previous
//
#include <hip/hip_runtime.h>

// Problem constants (match reference)
constexpr int Bz = 8192;   // batch
constexpr int Sz = 115;    // state dim
constexpr int Ez = 3072;   // embedding dim
constexpr int NEz = 4096;  // num keys
// C=128, A=23, K=10, TAU=1, EPS=1e-5

typedef __attribute__((ext_vector_type(8))) short short8;
typedef __attribute__((ext_vector_type(4))) float floatx4;
typedef unsigned short ushort_t;
typedef unsigned int uint_t;

__device__ __forceinline__ ushort_t f2bf(float f) {
  uint_t u = __float_as_uint(f);
  uint_t r = (u + 0x7FFFu + ((u >> 16) & 1u)) >> 16;   // RNE
  return (ushort_t)r;
}
__device__ __forceinline__ float bf2f(ushort_t b) {
  uint_t u = ((uint_t)b) << 16;
  return __uint_as_float(u);
}
// fp32 -> fp16 -> order-preserving u16 key (monotone total order)
__device__ __forceinline__ ushort_t f2key(float v) {
  _Float16 h = (_Float16)v;
  ushort_t b = __builtin_bit_cast(ushort_t, h);
  return b ^ ((b & 0x8000u) ? 0xFFFFu : 0x8000u);
}
__device__ __forceinline__ uint_t umax_(uint_t a, uint_t b) { return a > b ? a : b; }

// async global->LDS, 16 B per lane; lds dest = wave-uniform base + lane*16
__device__ __forceinline__ void gload16(const ushort_t* g, ushort_t* l) {
  __builtin_amdgcn_global_load_lds(
      (__attribute__((address_space(1))) const void*)g,
      (__attribute__((address_space(3))) void*)l, 16, 0, 0);
}

// =====================================================================
// Generic fp32 tiled GEMM: C = act(A@B + bias). Used for critic L2 + fallback.
// =====================================================================
template<bool RELU, bool BIAS>
__global__ __launch_bounds__(256)
void gemm128(const float* __restrict__ A, const float* __restrict__ Bm,
             const float* __restrict__ bias, float* __restrict__ C,
             int N, int Kd)
{
  __shared__ float As[16][132];
  __shared__ float Bs[16][132];
  const int t  = threadIdx.x;
  const int tx = t & 15, ty = t >> 4;
  const int row0 = blockIdx.y * 128;
  const int col0 = blockIdx.x * 128;
  const int ar = t >> 2, ac = (t & 3) * 4;
  const int bk = t >> 5, bc = (t & 31) * 4;
  const bool a4 = (Kd & 3) == 0;

  float acc[8][8];
#pragma unroll
  for (int i = 0; i < 8; ++i)
#pragma unroll
    for (int j = 0; j < 8; ++j) acc[i][j] = 0.f;

  for (int k0 = 0; k0 < Kd; k0 += 16) {
    const bool fullA = (k0 + 16 <= Kd) && a4;
    {
      const float* ap = A + (size_t)(row0 + ar) * Kd + k0 + ac;
      if (fullA) {
        float4 v0 = *(const float4*)ap;
        float4 v1 = *(const float4*)(ap + (size_t)64 * Kd);
        As[ac + 0][ar] = v0.x; As[ac + 1][ar] = v0.y;
        As[ac + 2][ar] = v0.z; As[ac + 3][ar] = v0.w;
        As[ac + 0][ar + 64] = v1.x; As[ac + 1][ar + 64] = v1.y;
        As[ac + 2][ar + 64] = v1.z; As[ac + 3][ar + 64] = v1.w;
      } else {
#pragma unroll
        for (int e = 0; e < 4; ++e) {
          const int k = k0 + ac + e;
          float v0 = 0.f, v1 = 0.f;
          if (k < Kd) { v0 = ap[e]; v1 = ap[e + (size_t)64 * Kd]; }
          As[ac + e][ar] = v0; As[ac + e][ar + 64] = v1;
        }
      }
    }
    {
      const float* bp = Bm + (size_t)(k0 + bk) * N + col0 + bc;
      if (k0 + 16 <= Kd) {
        *(float4*)&Bs[bk][bc]     = *(const float4*)bp;
        *(float4*)&Bs[bk + 8][bc] = *(const float4*)(bp + (size_t)8 * N);
      } else {
        float4 z; z.x = z.y = z.z = z.w = 0.f;
        *(float4*)&Bs[bk][bc]     = (k0 + bk     < Kd) ? *(const float4*)bp : z;
        *(float4*)&Bs[bk + 8][bc] = (k0 + bk + 8 < Kd) ? *(const float4*)(bp + (size_t)8 * N) : z;
      }
    }
    __syncthreads();
#pragma unroll
    for (int kk = 0; kk < 16; ++kk) {
      float a[8], b[8];
      *(float4*)&a[0] = *(const float4*)&As[kk][ty * 4];
      *(float4*)&a[4] = *(const float4*)&As[kk][64 + ty * 4];
      *(float4*)&b[0] = *(const float4*)&Bs[kk][tx * 4];
      *(float4*)&b[4] = *(const float4*)&Bs[kk][64 + tx * 4];
#pragma unroll
      for (int i = 0; i < 8; ++i)
#pragma unroll
        for (int j = 0; j < 8; ++j)
          acc[i][j] = fmaf(a[i], b[j], acc[i][j]);
    }
    __syncthreads();
  }

  float bv[8];
#pragma unroll
  for (int j = 0; j < 8; ++j) bv[j] = 0.f;
  if (BIAS) {
    *(float4*)&bv[0] = *(const float4*)&bias[col0 + tx * 4];
    *(float4*)&bv[4] = *(const float4*)&bias[col0 + 64 + tx * 4];
  }
#pragma unroll
  for (int i = 0; i < 8; ++i) {
    const int r = row0 + ((i < 4) ? (ty * 4 + i) : (64 + ty * 4 + i - 4));
    float o[8];
#pragma unroll
    for (int j = 0; j < 8; ++j) {
      o[j] = acc[i][j] + bv[j];
      if (RELU) o[j] = fmaxf(o[j], 0.f);
    }
    *(float4*)&C[(size_t)r * N + col0 + tx * 4]      = *(float4*)&o[0];
    *(float4*)&C[(size_t)r * N + col0 + 64 + tx * 4] = *(float4*)&o[4];
  }
}

// =====================================================================
// Dual-part fp32 GEMM+ReLU+bias. Optional fp32 out (C) and bf16 hi/lo
// split outputs (Ch/Cl) — either may be null.
// =====================================================================
struct GPart {
  const float* A; const float* Bm; const float* bias;
  float* C; ushort_t* Ch; ushort_t* Cl;
  int N; int Kd; int nbx;
};

__global__ __launch_bounds__(256)
void gemm128_dual(GPart g0, GPart g1)
{
  __shared__ float As[16][132];
  __shared__ float Bs[16][132];
  const int t  = threadIdx.x;
  const int tx = t & 15, ty = t >> 4;
  const bool p0 = (int)blockIdx.x < g0.nbx;
  GPart g = p0 ? g0 : g1;
  const int bx = p0 ? blockIdx.x : (blockIdx.x - g0.nbx);
  const int row0 = blockIdx.y * 128;
  const int col0 = bx * 128;
  const int Kd = g.Kd, N = g.N;
  const int ar = t >> 2, ac = (t & 3) * 4;
  const int bk = t >> 5, bc = (t & 31) * 4;
  const bool a4 = (Kd & 3) == 0;

  float acc[8][8];
#pragma unroll
  for (int i = 0; i < 8; ++i)
#pragma unroll
    for (int j = 0; j < 8; ++j) acc[i][j] = 0.f;

  for (int k0 = 0; k0 < Kd; k0 += 16) {
    const bool fullA = (k0 + 16 <= Kd) && a4;
    {
      const float* ap = g.A + (size_t)(row0 + ar) * Kd + k0 + ac;
      if (fullA) {
        float4 v0 = *(const float4*)ap;
        float4 v1 = *(const float4*)(ap + (size_t)64 * Kd);
        As[ac + 0][ar] = v0.x; As[ac + 1][ar] = v0.y;
        As[ac + 2][ar] = v0.z; As[ac + 3][ar] = v0.w;
        As[ac + 0][ar + 64] = v1.x; As[ac + 1][ar + 64] = v1.y;
        As[ac + 2][ar + 64] = v1.z; As[ac + 3][ar + 64] = v1.w;
      } else {
#pragma unroll
        for (int e = 0; e < 4; ++e) {
          const int k = k0 + ac + e;
          float v0 = 0.f, v1 = 0.f;
          if (k < Kd) { v0 = ap[e]; v1 = ap[e + (size_t)64 * Kd]; }
          As[ac + e][ar] = v0; As[ac + e][ar + 64] = v1;
        }
      }
    }
    {
      const float* bp = g.Bm + (size_t)(k0 + bk) * N + col0 + bc;
      if (k0 + 16 <= Kd) {
        *(float4*)&Bs[bk][bc]     = *(const float4*)bp;
        *(float4*)&Bs[bk + 8][bc] = *(const float4*)(bp + (size_t)8 * N);
      } else {
        float4 z; z.x = z.y = z.z = z.w = 0.f;
        *(float4*)&Bs[bk][bc]     = (k0 + bk     < Kd) ? *(const float4*)bp : z;
        *(float4*)&Bs[bk + 8][bc] = (k0 + bk + 8 < Kd) ? *(const float4*)(bp + (size_t)8 * N) : z;
      }
    }
    __syncthreads();
#pragma unroll
    for (int kk = 0; kk < 16; ++kk) {
      float a[8], b[8];
      *(float4*)&a[0] = *(const float4*)&As[kk][ty * 4];
      *(float4*)&a[4] = *(const float4*)&As[kk][64 + ty * 4];
      *(float4*)&b[0] = *(const float4*)&Bs[kk][tx * 4];
      *(float4*)&b[4] = *(const float4*)&Bs[kk][64 + tx * 4];
#pragma unroll
      for (int i = 0; i < 8; ++i)
#pragma unroll
        for (int j = 0; j < 8; ++j)
          acc[i][j] = fmaf(a[i], b[j], acc[i][j]);
    }
    __syncthreads();
  }

  float bv[8];
  *(float4*)&bv[0] = *(const float4*)&g.bias[col0 + tx * 4];
  *(float4*)&bv[4] = *(const float4*)&g.bias[col0 + 64 + tx * 4];
#pragma unroll
  for (int i = 0; i < 8; ++i) {
    const int r = row0 + ((i < 4) ? (ty * 4 + i) : (64 + ty * 4 + i - 4));
    float o[8];
#pragma unroll
    for (int j = 0; j < 8; ++j) o[j] = fmaxf(acc[i][j] + bv[j], 0.f);
    const size_t i0 = (size_t)r * N + col0 + tx * 4;
    const size_t i1 = i0 + 64;
    if (g.C) {
      *(float4*)&g.C[i0] = *(float4*)&o[0];
      *(float4*)&g.C[i1] = *(float4*)&o[4];
    }
    if (g.Ch) {
      ushort4 h0, l0, h1, l1;
      h0.x = f2bf(o[0]); l0.x = f2bf(o[0] - bf2f(h0.x));
      h0.y = f2bf(o[1]); l0.y = f2bf(o[1] - bf2f(h0.y));
      h0.z = f2bf(o[2]); l0.z = f2bf(o[2] - bf2f(h0.z));
      h0.w = f2bf(o[3]); l0.w = f2bf(o[3] - bf2f(h0.w));
      h1.x = f2bf(o[4]); l1.x = f2bf(o[4] - bf2f(h1.x));
      h1.y = f2bf(o[5]); l1.y = f2bf(o[5] - bf2f(h1.y));
      h1.z = f2bf(o[6]); l1.z = f2bf(o[6] - bf2f(h1.z));
      h1.w = f2bf(o[7]); l1.w = f2bf(o[7] - bf2f(h1.w));
      *(ushort4*)&g.Ch[i0] = h0; *(ushort4*)&g.Cl[i0] = l0;
      *(ushort4*)&g.Ch[i1] = h1; *(ushort4*)&g.Cl[i1] = l1;
    }
  }
}

// =====================================================================
// bf16 MFMA screen GEMM, A(M x K) @ B(N x K)^T -> u16 score keys.
// BK = 32*NSUB sub-tiles (conflict-free per-sub-tile layout preserved).
// NSUB=2 (BK=64) is the measured optimum: 32 KB LDS keeps ~5 blocks/CU.
// =====================================================================
template<int NSUB>
__global__ __launch_bounds__(256)
void mfma_bt(const ushort_t* __restrict__ A, const ushort_t* __restrict__ B,
             ushort_t* __restrict__ Cout, int N, int Kd)
{
  __shared__ ushort_t Al[NSUB * 4096];
  __shared__ ushort_t Bl[NSUB * 4096];
  const int t = threadIdx.x;
  const int wid = t >> 6, lane = t & 63;
  const int wr = wid >> 1, wc = wid & 1;
  const int row0 = blockIdx.y << 7;
  const int col0 = blockIdx.x << 7;
  const int srow = lane >> 2;
  const int scol = (lane & 3) * 8;

  const ushort_t* ga0 = A + (size_t)(row0 + wid * 16 + srow) * Kd + scol;
  const ushort_t* ga1 = A + (size_t)(row0 + (wid + 4) * 16 + srow) * Kd + scol;
  const ushort_t* gb0 = B + (size_t)(col0 + wid * 16 + srow) * Kd + scol;
  const ushort_t* gb1 = B + (size_t)(col0 + (wid + 4) * 16 + srow) * Kd + scol;
  ushort_t* la0 = &Al[wid * 512];
  ushort_t* la1 = &Al[(wid + 4) * 512];
  ushort_t* lb0 = &Bl[wid * 512];
  ushort_t* lb1 = &Bl[(wid + 4) * 512];

  const int mr = lane & 15, qd = lane >> 4;

  floatx4 acc[4][4];
#pragma unroll
  for (int i = 0; i < 4; ++i)
#pragma unroll
    for (int j = 0; j < 4; ++j) acc[i][j] = (floatx4){0.f, 0.f, 0.f, 0.f};

  for (int kb = 0; kb < Kd; kb += 32 * NSUB) {
#pragma unroll
    for (int tt = 0; tt < NSUB; ++tt) {
      const int ko = kb + 32 * tt;
      const int lo = tt * 4096;
      gload16(ga0 + ko, la0 + lo);
      gload16(ga1 + ko, la1 + lo);
      gload16(gb0 + ko, lb0 + lo);
      gload16(gb1 + ko, lb1 + lo);
    }
    __syncthreads();
#pragma unroll
    for (int tt = 0; tt < NSUB; ++tt) {
      const int lo = tt * 4096;
      short8 aF[4], bF[4];
#pragma unroll
      for (int i = 0; i < 4; ++i)
        aF[i] = *(const short8*)&Al[lo + (wr * 64 + i * 16 + mr) * 32 + qd * 8];
#pragma unroll
      for (int j = 0; j < 4; ++j)
        bF[j] = *(const short8*)&Bl[lo + (wc * 64 + j * 16 + mr) * 32 + qd * 8];
#pragma unroll
      for (int i = 0; i < 4; ++i)
#pragma unroll
        for (int j = 0; j < 4; ++j)
          acc[i][j] = __builtin_amdgcn_mfma_f32_16x16x32_bf16(aF[i], bF[j], acc[i][j], 0, 0, 0);
    }
    __syncthreads();
  }

#pragma unroll
  for (int i = 0; i < 4; ++i) {
#pragma unroll
    for (int j = 0; j < 4; ++j) {
      const int col = col0 + wc * 64 + j * 16 + mr;
#pragma unroll
      for (int r = 0; r < 4; ++r) {
        const int row = row0 + wr * 64 + i * 16 + qd * 4 + r;
        Cout[(size_t)row * N + col] = f2key(acc[i][j][r]);
      }
    }
  }
}

// =====================================================================
// bf16x3 split-precision MFMA GEMM (fp32-accurate): A@B^T + bias
// EPI=0: fp32 out (se_w3). EPI=1: relu then bf16 hi/lo split out (se_w2).
// =====================================================================
template<int EPI>
__global__ __launch_bounds__(256)
void mfma3_bt(const ushort_t* __restrict__ Ah, const ushort_t* __restrict__ Alo,
              const ushort_t* __restrict__ Bh, const ushort_t* __restrict__ Blo,
              const float* __restrict__ bias, float* __restrict__ Cout,
              ushort_t* __restrict__ Ch, ushort_t* __restrict__ Cl,
              int N, int Kd)
{
  __shared__ ushort_t AhL[128 * 32];
  __shared__ ushort_t AlL[128 * 32];
  __shared__ ushort_t BhL[128 * 32];
  __shared__ ushort_t BlL[128 * 32];
  const int t = threadIdx.x;
  const int wid = t >> 6, lane = t & 63;
  const int wr = wid >> 1, wc = wid & 1;
  const int row0 = blockIdx.y * 128;
  const int col0 = blockIdx.x * 128;
  const int srow = lane >> 2;
  const int scol = (lane & 3) * 8;

  const size_t aoff0 = (size_t)(row0 + wid * 16 + srow) * Kd + scol;
  const size_t aoff1 = (size_t)(row0 + (wid + 4) * 16 + srow) * Kd + scol;
  const size_t boff0 = (size_t)(col0 + wid * 16 + srow) * Kd + scol;
  const size_t boff1 = (size_t)(col0 + (wid + 4) * 16 + srow) * Kd + scol;
  const int l0 = (wid * 16) * 32;
  const int l1 = ((wid + 4) * 16) * 32;

  const int mr = lane & 15, qd = lane >> 4;

  floatx4 acc[4][4];
#pragma unroll
  for (int i = 0; i < 4; ++i)
#pragma unroll
    for (int j = 0; j < 4; ++j) acc[i][j] = (floatx4){0.f, 0.f, 0.f, 0.f};

  for (int kb = 0; kb < Kd; kb += 32) {
    gload16(Ah + aoff0 + kb, &AhL[l0]);
    gload16(Ah + aoff1 + kb, &AhL[l1]);
    gload16(Alo + aoff0 + kb, &AlL[l0]);
    gload16(Alo + aoff1 + kb, &AlL[l1]);
    gload16(Bh + boff0 + kb, &BhL[l0]);
    gload16(Bh + boff1 + kb, &BhL[l1]);
    gload16(Blo + boff0 + kb, &BlL[l0]);
    gload16(Blo + boff1 + kb, &BlL[l1]);
    __syncthreads();
    short8 ahF[4], alF[4], bhF[4], blF[4];
#pragma unroll
    for (int i = 0; i < 4; ++i) {
      const int o = (wr * 64 + i * 16 + mr) * 32 + qd * 8;
      ahF[i] = *(const short8*)&AhL[o];
      alF[i] = *(const short8*)&AlL[o];
    }
#pragma unroll
    for (int j = 0; j < 4; ++j) {
      const int o = (wc * 64 + j * 16 + mr) * 32 + qd * 8;
      bhF[j] = *(const short8*)&BhL[o];
      blF[j] = *(const short8*)&BlL[o];
    }
#pragma unroll
    for (int i = 0; i < 4; ++i)
#pragma unroll
      for (int j = 0; j < 4; ++j) {
        acc[i][j] = __builtin_amdgcn_mfma_f32_16x16x32_bf16(alF[i], bhF[j], acc[i][j], 0, 0, 0);
        acc[i][j] = __builtin_amdgcn_mfma_f32_16x16x32_bf16(ahF[i], blF[j], acc[i][j], 0, 0, 0);
        acc[i][j] = __builtin_amdgcn_mfma_f32_16x16x32_bf16(ahF[i], bhF[j], acc[i][j], 0, 0, 0);
      }
    __syncthreads();
  }

#pragma unroll
  for (int i = 0; i < 4; ++i) {
#pragma unroll
    for (int j = 0; j < 4; ++j) {
      const int col = col0 + wc * 64 + j * 16 + mr;
#pragma unroll
      for (int r = 0; r < 4; ++r) {
        const int row = row0 + wr * 64 + i * 16 + qd * 4 + r;
        const float v = acc[i][j][r] + bias[col];
        if (EPI == 0) {
          Cout[(size_t)row * N + col] = v;
        } else {
          const float y = fmaxf(v, 0.f);
          const ushort_t h = f2bf(y);
          Ch[(size_t)row * N + col] = h;
          Cl[(size_t)row * N + col] = f2bf(y - bf2f(h));
        }
      }
    }
  }
}

// =====================================================================
// bf16 MFMA GEMM, 64x128 tile (for cc_w1's small-M grid).
// A(M x K) bf16, B(N x K)^T bf16, out fp32 = relu(acc + bias). BK=64.
// =====================================================================
__global__ __launch_bounds__(256)
void mfma_bt64(const ushort_t* __restrict__ A, const ushort_t* __restrict__ B,
               const float* __restrict__ bias, float* __restrict__ Cout,
               int N, int Kd)
{
  __shared__ ushort_t Al[2 * 64 * 32];    // [sub][row][col]
  __shared__ ushort_t Bl[2 * 128 * 32];
  const int t = threadIdx.x;
  const int wid = t >> 6, lane = t & 63;
  const int row0 = blockIdx.y << 6;
  const int col0 = blockIdx.x << 7;
  const int srow = lane >> 2;
  const int scol = (lane & 3) * 8;
  const int mr = lane & 15, qd = lane >> 4;

  const ushort_t* gsrc[6];
  ushort_t* ldst[6];
#pragma unroll
  for (int m = 0; m < 6; ++m) {
    const int c = wid * 6 + m;
    if (c < 8) {        // A chunks: sub = c>>2, grp = c&3
      const int sub = c >> 2, grp = c & 3;
      gsrc[m] = A + (size_t)(row0 + grp * 16 + srow) * Kd + sub * 32 + scol;
      ldst[m] = &Al[sub * 2048 + (grp * 16 + srow) * 32];
    } else {            // B chunks: b = c-8, sub = b>>3, grp = b&7
      const int b = c - 8, sub = b >> 3, grp = b & 7;
      gsrc[m] = B + (size_t)(col0 + grp * 16 + srow) * Kd + sub * 32 + scol;
      ldst[m] = &Bl[sub * 4096 + (grp * 16 + srow) * 32];
    }
  }

  floatx4 acc[4][2];
#pragma unroll
  for (int i = 0; i < 4; ++i)
#pragma unroll
    for (int j = 0; j < 2; ++j) acc[i][j] = (floatx4){0.f, 0.f, 0.f, 0.f};

  for (int kb = 0; kb < Kd; kb += 64) {
#pragma unroll
    for (int m = 0; m < 6; ++m) gload16(gsrc[m] + kb, ldst[m]);
    __syncthreads();
#pragma unroll
    for (int sub = 0; sub < 2; ++sub) {
      short8 aF[4], bF[2];
#pragma unroll
      for (int i = 0; i < 4; ++i)
        aF[i] = *(const short8*)&Al[sub * 2048 + (i * 16 + mr) * 32 + qd * 8];
#pragma unroll
      for (int j = 0; j < 2; ++j)
        bF[j] = *(const short8*)&Bl[sub * 4096 + (wid * 32 + j * 16 + mr) * 32 + qd * 8];
#pragma unroll
      for (int i = 0; i < 4; ++i)
#pragma unroll
        for (int j = 0; j < 2; ++j)
          acc[i][j] = __builtin_amdgcn_mfma_f32_16x16x32_bf16(aF[i], bF[j], acc[i][j], 0, 0, 0);
    }
    __syncthreads();
  }

#pragma unroll
  for (int i = 0; i < 4; ++i) {
#pragma unroll
    for (int j = 0; j < 2; ++j) {
      const int col = col0 + wid * 32 + j * 16 + mr;
#pragma unroll
      for (int r = 0; r < 4; ++r) {
        const int row = row0 + i * 16 + qd * 4 + r;
        Cout[(size_t)row * N + col] = fmaxf(acc[i][j][r] + bias[col], 0.f);
      }
    }
  }
}

// =====================================================================
// fp32 scores GEMM (fallback path only) -> u16 score keys
// =====================================================================
__global__ __launch_bounds__(256)
void gemm_scores(const float* __restrict__ A, const float* __restrict__ Bm,
                 const float* __restrict__ rk, ushort_t* __restrict__ S)
{
  __shared__ float As[16][132];
  __shared__ float Bs[16][132];
  const int t  = threadIdx.x;
  const int tx = t & 15, ty = t >> 4;
  const int row0 = blockIdx.y * 128;
  const int col0 = blockIdx.x * 128;
  const int ar = t >> 2, ac = (t & 3) * 4;
  const int Kd = Ez;

  float acc[8][8];
#pragma unroll
  for (int i = 0; i < 8; ++i)
#pragma unroll
    for (int j = 0; j < 8; ++j) acc[i][j] = 0.f;

  for (int k0 = 0; k0 < Kd; k0 += 16) {
    {
      const float* ap = A + (size_t)(row0 + ar) * Kd + k0 + ac;
      float4 v0 = *(const float4*)ap;
      float4 v1 = *(const float4*)(ap + (size_t)64 * Kd);
      As[ac + 0][ar] = v0.x; As[ac + 1][ar] = v0.y;
      As[ac + 2][ar] = v0.z; As[ac + 3][ar] = v0.w;
      As[ac + 0][ar + 64] = v1.x; As[ac + 1][ar + 64] = v1.y;
      As[ac + 2][ar + 64] = v1.z; As[ac + 3][ar + 64] = v1.w;
    }
    {
      const float* bp = Bm + (size_t)(col0 + ar) * Kd + k0 + ac;
      float4 v0 = *(const float4*)bp;
      float4 v1 = *(const float4*)(bp + (size_t)64 * Kd);
      Bs[ac + 0][ar] = v0.x; Bs[ac + 1][ar] = v0.y;
      Bs[ac + 2][ar] = v0.z; Bs[ac + 3][ar] = v0.w;
      Bs[ac + 0][ar + 64] = v1.x; Bs[ac + 1][ar + 64] = v1.y;
      Bs[ac + 2][ar + 64] = v1.z; Bs[ac + 3][ar + 64] = v1.w;
    }
    __syncthreads();
#pragma unroll
    for (int kk = 0; kk < 16; ++kk) {
      float a[8], b[8];
      *(float4*)&a[0] = *(const float4*)&As[kk][ty * 4];
      *(float4*)&a[4] = *(const float4*)&As[kk][64 + ty * 4];
      *(float4*)&b[0] = *(const float4*)&Bs[kk][tx * 4];
      *(float4*)&b[4] = *(const float4*)&Bs[kk][64 + tx * 4];
#pragma unroll
      for (int i = 0; i < 8; ++i)
#pragma unroll
        for (int j = 0; j < 8; ++j)
          acc[i][j] = fmaf(a[i], b[j], acc[i][j]);
    }
    __syncthreads();
  }

  float rk0[8];
  *(float4*)&rk0[0] = *(const float4*)&rk[col0 + tx * 4];
  *(float4*)&rk0[4] = *(const float4*)&rk[col0 + 64 + tx * 4];
#pragma unroll
  for (int i = 0; i < 8; ++i) {
    const int r = row0 + ((i < 4) ? (ty * 4 + i) : (64 + ty * 4 + i - 4));
    ushort4 h0, h1;
    h0.x = f2key(acc[i][0] * rk0[0]); h0.y = f2key(acc[i][1] * rk0[1]);
    h0.z = f2key(acc[i][2] * rk0[2]); h0.w = f2key(acc[i][3] * rk0[3]);
    h1.x = f2key(acc[i][4] * rk0[4]); h1.y = f2key(acc[i][5] * rk0[5]);
    h1.z = f2key(acc[i][6] * rk0[6]); h1.w = f2key(acc[i][7] * rk0[7]);
    *(ushort4*)&S[(size_t)r * NEz + col0 + tx * 4]      = h0;
    *(ushort4*)&S[(size_t)r * NEz + col0 + 64 + tx * 4] = h1;
  }
}

// =====================================================================
// Batched (4-actor) fused GEMM(N=128) + LayerNorm (+ReLU).
// =====================================================================
struct LN4 {
  const float* W[4]; const float* b[4]; const float* g[4]; const float* be[4];
  int eoff[4]; int elen[4];
};

template<bool RELU, bool HASEXT>
__global__ __launch_bounds__(256)
void gemm_ln4(const float* __restrict__ A1base, size_t a1stride, int K1,
              const float* __restrict__ A2, LN4 p,
              float* __restrict__ outbase, size_t ostride)
{
  __shared__ float As[32][68];
  __shared__ float Bs[32][132];
  __shared__ float rsum[64][17];
  __shared__ float rsq[64][17];
  __shared__ float stm[64], str[64];
  const int a = blockIdx.y;
  const float* A1 = A1base + (size_t)a * a1stride;
  float* out = outbase + (size_t)a * ostride;
  const float* W = p.W[a];
  const float* bias = p.b[a];
  const float* g = p.g[a];
  const float* be = p.be[a];
  const int eoff = HASEXT ? p.eoff[a] : 0;
  const int K2 = HASEXT ? p.elen[a] : 0;

  const int t = threadIdx.x;
  const int tx = t & 15, ty = t >> 4;
  const int row0 = blockIdx.x * 64;
  const int Kt = K1 + K2;
  const int ar = t >> 2, ac = (t & 3) * 8;
  const int bk = t >> 3, bc = (t & 7) * 16;

  float acc[4][8];
#pragma unroll
  for (int i = 0; i < 4; ++i)
#pragma unroll
    for (int j = 0; j < 8; ++j) acc[i][j] = 0.f;

  for (int k0 = 0; k0 < Kt; k0 += 32) {
    const int grow = row0 + ar;
#pragma unroll
    for (int e = 0; e < 8; ++e) {
      const int k = k0 + ac + e;
      float v = 0.f;
      if (k < K1)      v = A1[(size_t)grow * K1 + k];
      else if (k < Kt) v = A2[(size_t)grow * 115 + eoff + (k - K1)];
      As[ac + e][ar] = v;
    }
    {
      const int k = k0 + bk;
#pragma unroll
      for (int qd = 0; qd < 4; ++qd) {
        float4 z; z.x = z.y = z.z = z.w = 0.f;
        *(float4*)&Bs[bk][bc + 4 * qd] =
            (k < Kt) ? *(const float4*)&W[(size_t)k * 128 + bc + 4 * qd] : z;
      }
    }
    __syncthreads();
#pragma unroll
    for (int kk = 0; kk < 32; ++kk) {
      float av[4], bv2[8];
      *(float4*)&av[0]  = *(const float4*)&As[kk][ty * 4];
      *(float4*)&bv2[0] = *(const float4*)&Bs[kk][tx * 4];
      *(float4*)&bv2[4] = *(const float4*)&Bs[kk][64 + tx * 4];
#pragma unroll
      for (int i = 0; i < 4; ++i)
#pragma unroll
        for (int j = 0; j < 8; ++j)
          acc[i][j] = fmaf(av[i], bv2[j], acc[i][j]);
    }
    __syncthreads();
  }

  float bv[8];
  *(float4*)&bv[0] = *(const float4*)&bias[tx * 4];
  *(float4*)&bv[4] = *(const float4*)&bias[64 + tx * 4];
#pragma unroll
  for (int i = 0; i < 4; ++i) {
    float s = 0.f, q = 0.f;
#pragma unroll
    for (int j = 0; j < 8; ++j) {
      acc[i][j] += bv[j];
      s += acc[i][j];
      q += acc[i][j] * acc[i][j];
    }
    rsum[ty * 4 + i][tx] = s;
    rsq[ty * 4 + i][tx]  = q;
  }
  __syncthreads();
  if (t < 64) {
    float s = 0.f, q = 0.f;
#pragma unroll
    for (int x = 0; x < 16; ++x) { s += rsum[t][x]; q += rsq[t][x]; }
    const float m = s * (1.f / 128.f);
    const float v = q * (1.f / 128.f) - m * m;
    stm[t] = m;
    str[t] = rsqrtf(v + 1e-5f);
  }
  __syncthreads();
#pragma unroll
  for (int i = 0; i < 4; ++i) {
    const int r = ty * 4 + i;
    const float m = stm[r], rs = str[r];
    float o[8];
#pragma unroll
    for (int j = 0; j < 8; ++j) {
      const int col = (j < 4) ? (tx * 4 + j) : (64 + tx * 4 + (j - 4));
      float y = (acc[i][j] - m) * rs * g[col] + be[col];
      if (RELU) y = fmaxf(y, 0.f);
      o[j] = y;
    }
    *(float4*)&out[(size_t)(row0 + r) * 128 + tx * 4]      = *(float4*)&o[0];
    *(float4*)&out[(size_t)(row0 + r) * 128 + 64 + tx * 4] = *(float4*)&o[4];
  }
}

// =====================================================================
// Block-wide (256 threads) sum helper
// =====================================================================
__device__ __forceinline__ float blockSum256(float v, float* sh)
{
#pragma unroll
  for (int d = 32; d; d >>= 1) v += __shfl_down(v, d, 64);
  __syncthreads();
  if ((threadIdx.x & 63) == 0) sh[threadIdx.x >> 6] = v;
  __syncthreads();
  return sh[0] + sh[1] + sh[2] + sh[3];
}

// =====================================================================
// Fused normalize+convert launch (fast path):
// blocks [0,Bz):        q row LN + L2 + bf16 out
// blocks [Bz, Bz+NEz):  key row norm + bf16(keys*rk) + rk
// =====================================================================
__global__ __launch_bounds__(256)
void norm_cvt_fused(float* __restrict__ q, const float* __restrict__ g,
                    const float* __restrict__ be, ushort_t* __restrict__ qb,
                    const float* __restrict__ keys, float* __restrict__ rk,
                    ushort_t* __restrict__ knb)
{
  __shared__ float sh[4];
  const int b = blockIdx.x, t = threadIdx.x;
  if (b < Bz) {
    const int row = b;
    float* qr = q + (size_t)row * Ez;
    float x[12];
#pragma unroll
    for (int i = 0; i < 12; ++i) x[i] = qr[t + (i << 8)];
    float s = 0.f;
#pragma unroll
    for (int i = 0; i < 12; ++i) s += x[i];
    const float m = blockSum256(s, sh) * (1.f / (float)Ez);
    float vs = 0.f;
#pragma unroll
    for (int i = 0; i < 12; ++i) { const float d = x[i] - m; vs += d * d; }
    const float v = blockSum256(vs, sh) * (1.f / (float)Ez);
    const float rs = rsqrtf(v + 1e-5f);
    float y[12]; float qs = 0.f;
#pragma unroll
    for (int i = 0; i < 12; ++i) {
      const int c = t + (i << 8);
      const float yy = (x[i] - m) * rs * g[c] + be[c];
      y[i] = yy; qs += yy * yy;
    }
    const float tot = blockSum256(qs, sh);
    const float s2 = rsqrtf(tot + 1e-12f);
#pragma unroll
    for (int i = 0; i < 12; ++i) {
      const int c = t + (i << 8);
      const float yn = y[i] * s2;
      qr[c] = yn;
      qb[(size_t)row * Ez + c] = f2bf(yn);
    }
  } else {
    const int row = b - Bz;
    const float* xr = keys + (size_t)row * Ez;
    float x[12]; float qs = 0.f;
#pragma unroll
    for (int i = 0; i < 12; ++i) { x[i] = xr[t + (i << 8)]; qs += x[i] * x[i]; }
    const float tot = blockSum256(qs, sh);
    const float s = rsqrtf(tot + 1e-12f);
    if (t == 0) rk[row] = s;
#pragma unroll
    for (int i = 0; i < 12; ++i)
      knb[(size_t)row * Ez + t + (i << 8)] = f2bf(x[i] * s);
  }
}

// Row LN (width 3072) + L2 normalize, in place (fallback)
__global__ __launch_bounds__(256)
void ln_l2_q(float* __restrict__ q, const float* __restrict__ g,
             const float* __restrict__ be)
{
  __shared__ float sh[4];
  const int row = blockIdx.x, t = threadIdx.x;
  float* qr = q + (size_t)row * Ez;
  float x[12];
#pragma unroll
  for (int i = 0; i < 12; ++i) x[i] = qr[t + (i << 8)];
  float s = 0.f;
#pragma unroll
  for (int i = 0; i < 12; ++i) s += x[i];
  const float m = blockSum256(s, sh) * (1.f / (float)Ez);
  float vs = 0.f;
#pragma unroll
  for (int i = 0; i < 12; ++i) { const float d = x[i] - m; vs += d * d; }
  const float v = blockSum256(vs, sh) * (1.f / (float)Ez);
  const float rs = rsqrtf(v + 1e-5f);
  float y[12]; float qs = 0.f;
#pragma unroll
  for (int i = 0; i < 12; ++i) {
    const int c = t + (i << 8);
    const float yy = (x[i] - m) * rs * g[c] + be[c];
    y[i] = yy; qs += yy * yy;
  }
  const float tot = blockSum256(qs, sh);
  const float s2 = rsqrtf(tot + 1e-12f);
#pragma unroll
  for (int i = 0; i < 12; ++i) qr[t + (i << 8)] = y[i] * s2;
}

// rk[n] only (fallback)
__global__ __launch_bounds__(256)
void keynorm(const float* __restrict__ keys, float* __restrict__ rk)
{
  __shared__ float sh[4];
  const int row = blockIdx.x, t = threadIdx.x;
  const float* xr = keys + (size_t)row * Ez;
  float qs = 0.f;
#pragma unroll
  for (int i = 0; i < 12; ++i) { const float x = xr[t + (i << 8)]; qs += x * x; }
  const float tot = blockSum256(qs, sh);
  if (t == 0) rk[row] = rsqrtf(tot + 1e-12f);
}

// Combined weight transpose+split: blockIdx.y<8 -> se_w2 (C=512),
// else se_w3 (C=3072). W is (512 x C), outputs (C x 512) hi/lo bf16.
__global__ __launch_bounds__(256)
void wt_split2(const float* __restrict__ w2, ushort_t* __restrict__ h2,
               ushort_t* __restrict__ l2v,
               const float* __restrict__ w3, ushort_t* __restrict__ h3,
               ushort_t* __restrict__ l3v)
{
  __shared__ float tile[64][65];
  const float* w; ushort_t* hT; ushort_t* lT; int C; int n0;
  if ((int)blockIdx.y < 8) { w = w2; hT = h2; lT = l2v; C = 512;  n0 = blockIdx.y * 64; }
  else                     { w = w3; hT = h3; lT = l3v; C = 3072; n0 = (blockIdx.y - 8) * 64; }
  const int k0 = blockIdx.x * 64;
  const int t = threadIdx.x;
  const int c = t & 63, r4 = t >> 6;
#pragma unroll
  for (int rr = 0; rr < 16; ++rr) {
    const int r = rr * 4 + r4;
    tile[r][c] = w[(size_t)(k0 + r) * C + n0 + c];
  }
  __syncthreads();
#pragma unroll
  for (int rr = 0; rr < 16; ++rr) {
    const int n = rr * 4 + r4;
    const float a = tile[c][n];
    const ushort_t h = f2bf(a);
    hT[(size_t)(n0 + n) * 512 + k0 + c] = h;
    lT[(size_t)(n0 + n) * 512 + k0 + c] = f2bf(a - bf2f(h));
  }
}

// cc_w1 (3072 x 512 fp32) -> transposed bf16 (512 x 3072), coalesced
__global__ __launch_bounds__(256)
void cvt_w1t_t(const float* __restrict__ w, ushort_t* __restrict__ out)
{
  __shared__ float tile[64][65];
  const int k0 = blockIdx.x * 64;   // 48 blocks
  const int n0 = blockIdx.y * 64;   // 8 blocks
  const int t = threadIdx.x;
  const int c = t & 63, r4 = t >> 6;
#pragma unroll
  for (int rr = 0; rr < 16; ++rr) {
    const int r = rr * 4 + r4;
    tile[r][c] = w[(size_t)(k0 + r) * 512 + n0 + c];
  }
  __syncthreads();
#pragma unroll
  for (int rr = 0; rr < 16; ++rr) {
    const int n = rr * 4 + r4;
    out[(size_t)(n0 + n) * Ez + k0 + c] = f2bf(tile[c][n]);
  }
}

// =====================================================================
// Top-16 per row of the 8192 x 4096 u16-key score matrix.
// =====================================================================
__global__ __launch_bounds__(256)
void topk16(const ushort_t* __restrict__ S, int* __restrict__ outIdx)
{
  __shared__ uint_t cand[64];
  const int row = blockIdx.x, t = threadIdx.x;
  const int w = t >> 6, lane = t & 63;
  const int base = (w << 10) + (lane << 4);
  const ushort_t* sr = S + (size_t)row * NEz + base;
  uint4 v0 = *(const uint4*)sr;
  uint4 v1 = *(const uint4*)(sr + 8);
  const uint_t cb = (uint_t)(4095 - base);
  uint_t p[16];
  p[0]  = ((v0.x & 0xFFFFu) << 12) | (cb - 0);
  p[1]  = ((v0.x >> 16)     << 12) | (cb - 1);
  p[2]  = ((v0.y & 0xFFFFu) << 12) | (cb - 2);
  p[3]  = ((v0.y >> 16)     << 12) | (cb - 3);
  p[4]  = ((v0.z & 0xFFFFu) << 12) | (cb - 4);
  p[5]  = ((v0.z >> 16)     << 12) | (cb - 5);
  p[6]  = ((v0.w & 0xFFFFu) << 12) | (cb - 6);
  p[7]  = ((v0.w >> 16)     << 12) | (cb - 7);
  p[8]  = ((v1.x & 0xFFFFu) << 12) | (cb - 8);
  p[9]  = ((v1.x >> 16)     << 12) | (cb - 9);
  p[10] = ((v1.y & 0xFFFFu) << 12) | (cb - 10);
  p[11] = ((v1.y >> 16)     << 12) | (cb - 11);
  p[12] = ((v1.z & 0xFFFFu) << 12) | (cb - 12);
  p[13] = ((v1.z >> 16)     << 12) | (cb - 13);
  p[14] = ((v1.w & 0xFFFFu) << 12) | (cb - 14);
  p[15] = ((v1.w >> 16)     << 12) | (cb - 15);

  for (int it = 0; it < 16; ++it) {
    uint_t m = p[0];
#pragma unroll
    for (int j = 1; j < 16; ++j) m = umax_(m, p[j]);
#pragma unroll
    for (int d = 1; d < 64; d <<= 1)
      m = umax_(m, (uint_t)__shfl_xor((int)m, d, 64));
    if (lane == it) cand[(w << 4) + it] = m;
#pragma unroll
    for (int j = 0; j < 16; ++j) p[j] = (p[j] == m) ? 0u : p[j];
  }
  __syncthreads();
  if (t < 64) {
    uint_t mine = cand[t];
    for (int it = 0; it < 16; ++it) {
      uint_t m = mine;
#pragma unroll
      for (int d = 1; d < 64; d <<= 1)
        m = umax_(m, (uint_t)__shfl_xor((int)m, d, 64));
      if (t == it) outIdx[(size_t)row * 16 + it] = 4095 - (int)(m & 0xFFFu);
      mine = (mine == m) ? 0u : mine;
    }
  }
}

// =====================================================================
// Fused rescore + gather: one block per batch row (16 candidates).
// ctxOut must NOT alias qn (fast path uses separate region).
// =====================================================================
template<bool BFOUT>
__global__ __launch_bounds__(256)
void rescore_gather(const float* __restrict__ qn, const float* __restrict__ keys,
                    const float* __restrict__ rk, const int* __restrict__ cand,
                    void* __restrict__ ctxOut)
{
  __shared__ float qs[Ez];
  __shared__ double sv[16];
  __shared__ int si[16];
  __shared__ int sel10[10];
  const int row = blockIdx.x, t = threadIdx.x;
  const int w = t >> 6, lane = t & 63;

  {
    const float* qr = qn + (size_t)row * Ez;
#pragma unroll
    for (int i = 0; i < 3; ++i) {
      const int c = (t << 2) + (i << 10);
      *(float4*)&qs[c] = *(const float4*)&qr[c];
    }
  }
  __syncthreads();

#pragma unroll
  for (int cc = 0; cc < 4; ++cc) {
    const int slot = w * 4 + cc;
    const int id = cand[(size_t)row * 16 + slot];
    const float* kr = keys + (size_t)id * Ez;
    double s = 0.0;
#pragma unroll
    for (int it = 0; it < 12; ++it) {
      const int c = (lane << 2) + (it << 8);
      float4 k4 = *(const float4*)&kr[c];
      float4 q4 = *(const float4*)&qs[c];
      s += (double)q4.x * (double)k4.x;
      s += (double)q4.y * (double)k4.y;
      s += (double)q4.z * (double)k4.z;
      s += (double)q4.w * (double)k4.w;
    }
#pragma unroll
    for (int d = 32; d; d >>= 1) s += __shfl_down(s, d, 64);
    if (lane == 0) { sv[slot] = s * (double)rk[id]; si[slot] = id; }
  }
  __syncthreads();

  if (t == 0) {
    for (int it = 0; it < 10; ++it) {
      int bj = 0; double bvv = sv[0]; int bi = si[0];
      for (int j = 1; j < 16; ++j) {
        const double v = sv[j]; const int i2 = si[j];
        if (v > bvv || (v == bvv && i2 < bi)) { bj = j; bvv = v; bi = i2; }
      }
      sel10[it] = bi;
      sv[bj] = -1e300;
    }
  }
  __syncthreads();

  int id[10];
#pragma unroll
  for (int j = 0; j < 10; ++j) id[j] = sel10[j];

#pragma unroll
  for (int i = 0; i < 3; ++i) {
    const int c = (t << 2) + (i << 10);
    float4 a = {0.f, 0.f, 0.f, 0.f};
#pragma unroll
    for (int j = 0; j < 10; ++j) {
      float4 v = *(const float4*)&keys[(size_t)id[j] * Ez + c];
      a.x += v.x; a.y += v.y; a.z += v.z; a.w += v.w;
    }
    if (BFOUT) {
      ushort4 o;
      o.x = f2bf(a.x * 0.1f); o.y = f2bf(a.y * 0.1f);
      o.z = f2bf(a.z * 0.1f); o.w = f2bf(a.w * 0.1f);
      *(ushort4*)&((ushort_t*)ctxOut)[(size_t)row * Ez + c] = o;
    } else {
      float4 o;
      o.x = a.x * 0.1f; o.y = a.y * 0.1f; o.z = a.z * 0.1f; o.w = a.w * 0.1f;
      *(float4*)&((float*)ctxOut)[(size_t)row * Ez + c] = o;
    }
  }
}

// =====================================================================
// Router: 115 -> 64 -> 64 -> 4, clip, + gumbel, softmax, straight-through
// =====================================================================
__global__ __launch_bounds__(256)
void router_kernel(const float* __restrict__ state, const float* __restrict__ gn,
                   const float* __restrict__ w1, const float* __restrict__ b1,
                   const float* __restrict__ w2, const float* __restrict__ b2,
                   const float* __restrict__ w3, const float* __restrict__ b3,
                   float* __restrict__ outAlpha)
{
  const int row = blockIdx.x * 256 + threadIdx.x;
  const float* sr = state + (size_t)row * Sz;
  float h1[64];
#pragma unroll
  for (int j = 0; j < 64; ++j) h1[j] = b1[j];
  for (int k = 0; k < Sz; ++k) {
    const float a = sr[k];
    const float* wr = w1 + (size_t)k * 64;
#pragma unroll
    for (int j = 0; j < 64; ++j) h1[j] = fmaf(a, wr[j], h1[j]);
  }
#pragma unroll
  for (int j = 0; j < 64; ++j) h1[j] = fmaxf(h1[j], 0.f);
  float h2[64];
#pragma unroll
  for (int j = 0; j < 64; ++j) h2[j] = b2[j];
#pragma unroll
  for (int k = 0; k < 64; ++k) {
    const float a = h1[k];
    const float* wr = w2 + (size_t)k * 64;
#pragma unroll
    for (int j = 0; j < 64; ++j) h2[j] = fmaf(a, wr[j], h2[j]);
  }
#pragma unroll
  for (int j = 0; j < 64; ++j) h2[j] = fmaxf(h2[j], 0.f);
  float z[4];
#pragma unroll
  for (int a = 0; a < 4; ++a) {
    float s = b3[a];
#pragma unroll
    for (int k = 0; k < 64; ++k) s = fmaf(h2[k], w3[k * 4 + a], s);
    s = fminf(fmaxf(s, -20.f), 20.f);
    z[a] = s + gn[(size_t)row * 4 + a];   // TAU = 1
  }
  float mz = z[0];
#pragma unroll
  for (int a = 1; a < 4; ++a) mz = fmaxf(mz, z[a]);
  float e[4]; float se = 0.f;
#pragma unroll
  for (int a = 0; a < 4; ++a) { e[a] = expf(z[a] - mz); se += e[a]; }
  const float inv = 1.f / se;
  float y[4];
#pragma unroll
  for (int a = 0; a < 4; ++a) y[a] = e[a] * inv;
  int am = 0;
#pragma unroll
  for (int a = 1; a < 4; ++a) if (y[a] > y[am]) am = a;
#pragma unroll
  for (int a = 0; a < 4; ++a) {
    const float hard = (a == am) ? 1.f : 0.f;
    outAlpha[(size_t)row * 4 + a] = y[a] + (hard - y[a]);
  }
}

// critic head, coalesced: 128 blocks, wave handles 16 rows, lane = 4 cols
__global__ __launch_bounds__(256)
void critic_head(const float* __restrict__ c2, const float* __restrict__ w3,
                 const float* __restrict__ b3, float* __restrict__ outv)
{
  const int t = threadIdx.x;
  const int w = t >> 6, lane = t & 63;
  const int row0 = blockIdx.x * 64 + w * 16;
  float wv[4];
  *(float4*)&wv[0] = *(const float4*)&w3[lane * 4];
  const float b0 = b3[0];
#pragma unroll
  for (int rr = 0; rr < 16; ++rr) {
    const int row = row0 + rr;
    float4 x = *(const float4*)&c2[(size_t)row * 256 + lane * 4];
    float s = x.x * wv[0] + x.y * wv[1] + x.z * wv[2] + x.w * wv[3];
#pragma unroll
    for (int d = 32; d; d >>= 1) s += __shfl_down(s, d, 64);
    if (lane == 0) outv[row] = s + b0;
  }
}

// all-4 actor heads fused; 32 rows/block (256 blocks = full GPU)
struct HeadP { const float* w3[4]; const float* b3[4]; };

__global__ __launch_bounds__(256)
void actor_head4(const float* __restrict__ x2g, HeadP p,
                 const float* __restrict__ alpha, float* __restrict__ outL)
{
  __shared__ float wsm[4][128 * 23];
  __shared__ float bs[4][23];
  const int t = threadIdx.x;
#pragma unroll
  for (int a = 0; a < 4; ++a) {
    for (int i = t; i < 128 * 23; i += 256) wsm[a][i] = p.w3[a][i];
    if (t < 23) bs[a][t] = p.b3[a][t];
  }
  __syncthreads();
  const int row = blockIdx.x * 32 + (t >> 3);
  const int cg = t & 7;
  float sum[3] = {0.f, 0.f, 0.f};
#pragma unroll
  for (int a = 0; a < 4; ++a) {
    const float al = alpha[(size_t)row * 4 + a];
    const float* xr = x2g + (size_t)a * Bz * 128 + (size_t)row * 128;
    float acc[3] = {0.f, 0.f, 0.f};
    for (int kk = 0; kk < 128; ++kk) {
      const float xa = xr[kk];
#pragma unroll
      for (int j = 0; j < 3; ++j) {
        const int col = cg + 8 * j;
        if (col < 23) acc[j] = fmaf(xa, wsm[a][kk * 23 + col], acc[j]);
      }
    }
#pragma unroll
    for (int j = 0; j < 3; ++j) {
      const int col = cg + 8 * j;
      if (col < 23) sum[j] += al * (acc[j] + bs[a][col]);
    }
  }
#pragma unroll
  for (int j = 0; j < 3; ++j) {
    const int col = cg + 8 * j;
    if (col < 23) outL[(size_t)row * 23 + col] = sum[j];
  }
}

// =====================================================================
extern "C" void kernel_launch(void* const* d_in, const int* in_sizes, int n_in,
                              void* d_out, int out_size, void* d_ws, size_t ws_size,
                              hipStream_t stream)
{
  const float* state  = (const float*)d_in[0];
  const float* gumbel = (const float*)d_in[1];
  const float* keys   = (const float*)d_in[2];
  const float* se_w1 = (const float*)d_in[3];
  const float* se_b1 = (const float*)d_in[4];
  const float* se_w2 = (const float*)d_in[5];
  const float* se_b2 = (const float*)d_in[6];
  const float* se_w3 = (const float*)d_in[7];
  const float* se_b3 = (const float*)d_in[8];
  const float* se_g  = (const float*)d_in[9];
  const float* se_be = (const float*)d_in[10];
  const float* cc_w1 = (const float*)d_in[11];
  const float* cc_b1 = (const float*)d_in[12];
  const float* cc_w2 = (const float*)d_in[13];
  const float* cc_b2 = (const float*)d_in[14];
  const float* cc_g  = (const float*)d_in[15];
  const float* cc_be = (const float*)d_in[16];
  const float* r_w1 = (const float*)d_in[57];
  const float* r_b1 = (const float*)d_in[58];
  const float* r_w2 = (const float*)d_in[59];
  const float* r_b2 = (const float*)d_in[60];
  const float* r_w3 = (const float*)d_in[61];
  const float* r_b3 = (const float*)d_in[62];
  const float* c_w1 = (const float*)d_in[63];
  const float* c_b1 = (const float*)d_in[64];
  const float* c_w2 = (const float*)d_in[65];
  const float* c_b2 = (const float*)d_in[66];
  const float* c_w3 = (const float*)d_in[67];
  const float* c_b3 = (const float*)d_in[68];

  // ---- workspace layout ----
  float* wsf = (float*)d_ws;
  const size_t qF = (size_t)Bz * Ez;          // 25,165,824 floats
  const size_t uF = (size_t)16777216;         // union region, floats
  float* q = wsf;
  float* U = wsf + qF;
  // U internal (time-multiplexed), float offsets:
  ushort_t* sAh  = (ushort_t*)(U + 0);          // 8192x512 halves
  ushort_t* sAl  = (ushort_t*)(U + 2097152);
  ushort_t* sBh  = (ushort_t*)(U + 4194304);
  ushort_t* sBl  = (ushort_t*)(U + 6291456);
  ushort_t* w3hT = (ushort_t*)(U + 8388608);    // 3072x512 halves
  ushort_t* w3lT = (ushort_t*)(U + 9175040);
  ushort_t* w2hT = (ushort_t*)(U + 9961472);    // 512x512 halves
  ushort_t* w2lT = (ushort_t*)(U + 10092544);
  // fallback path fp32 buffers (same region, stream-ordered):
  float* sA = U;                                 // 8192x512 fp32 (fallback)
  float* sB = U + 4194304;                       // 8192x512 fp32 (fallback)
  ushort_t* scoresU = (ushort_t*)U;              // 8192x4096 u16 (whole U)
  ushort_t* ctxb = (ushort_t*)U;                 // bf16 ctx (8192x3072 halves),
                                                 // overlays dead scores post-topk
  float* cch = U + 12582912;                     // 8192x512 fp32
  float* shr = U;                                // 8192x128 (post-ctx phase)
  float* x1g = U + 1 * 1048576;                  // 4 x 8192x128
  float* x2g = U + 5 * 1048576;                  // 4 x 8192x128
  // critic temporaries in the (not yet written) q region:
  float* cr1 = q;                                // 8192x256
  float* cr2 = q + 2097152;                      // 8192x256
  // fast-path bf16 buffers after U:
  ushort_t* qbf  = (ushort_t*)(wsf + qF + uF);   // 8192x3072
  ushort_t* knbf = qbf + qF;                     // 4096x3072
  ushort_t* w1T  = knbf + (size_t)NEz * Ez;      // 512x3072
  const size_t bfHalves = qF + (size_t)NEz * Ez + (size_t)512 * Ez;
  const size_t baseBytes = (qF + uF) * sizeof(float);
  const size_t tailBytes = 4096 * 4 + (size_t)Bz * 16 * 4;
  const bool fast = ws_size >= baseBytes + bfHalves * 2 + tailBytes;
  float* tailF = (float*)((char*)d_ws + (fast ? baseBytes + bfHalves * 2 : baseBytes));
  float* rk  = tailF;
  int* cand  = (int*)(tailF + 4096);

  float* outL = (float*)d_out;                 // 8192*23
  float* outA = outL + (size_t)Bz * 23;        // 8192*4
  float* outV = outA + (size_t)Bz * 4;         // 8192*1

  const dim3 blk(256);

  // --- encoder L1 (hi/lo split out on fast path) + critic L1 ---
  {
    GPart e0 = {state, se_w1, se_b1, fast ? nullptr : sA,
                fast ? sAh : nullptr, fast ? sAl : nullptr, 512, 115, 4};
    GPart e1 = {state, c_w1, c_b1, cr1, nullptr, nullptr, 256, 115, 2};
    gemm128_dual<<<dim3(6, 64), blk, 0, stream>>>(e0, e1);
  }
  // --- critic L2 (fp32) ---
  gemm128<true, true><<<dim3(2, 64), blk, 0, stream>>>(cr1, c_w2, c_b2, cr2, 256, 256);

  if (fast) {
    // combined weight transpose+split (se_w2 + se_w3)
    wt_split2<<<dim3(8, 56), blk, 0, stream>>>(se_w2, w2hT, w2lT, se_w3, w3hT, w3lT);
    // encoder L2 via bf16x3 MFMA: relu + hi/lo split out
    mfma3_bt<1><<<dim3(4, 64), blk, 0, stream>>>(sAh, sAl, w2hT, w2lT, se_b2,
                                                 nullptr, sBh, sBl, 512, 512);
  } else {
    gemm128<true, true><<<dim3(4, 64), blk, 0, stream>>>(sA, se_w2, se_b2, sB, 512, 512);
  }

  // critic head + router (cr1/cr2 die before q is written)
  critic_head<<<dim3(128), blk, 0, stream>>>(cr2, c_w3, c_b3, outV);
  router_kernel<<<dim3(32), blk, 0, stream>>>(state, gumbel, r_w1, r_b1, r_w2, r_b2,
                                              r_w3, r_b3, outA);

  if (fast) {
    // encoder L3 (se_w3) via bf16x3 MFMA -> q fp32
    mfma3_bt<0><<<dim3(24, 64), blk, 0, stream>>>(sBh, sBl, w3hT, w3lT, se_b3,
                                                  q, nullptr, nullptr, 3072, 512);
    // fused: q LN+L2+bf16 and keys norm+bf16 in one launch
    norm_cvt_fused<<<dim3(Bz + NEz), blk, 0, stream>>>(q, se_g, se_be, qbf,
                                                       keys, rk, knbf);
    cvt_w1t_t<<<dim3(48, 8), blk, 0, stream>>>(cc_w1, w1T);
    // screen: BK=64 (2 sub-tiles) — measured optimum
    mfma_bt<2><<<dim3(32, 64), blk, 0, stream>>>(qbf, knbf, scoresU, NEz, Ez);
  } else {
    gemm128<false, true><<<dim3(24, 64), blk, 0, stream>>>(sB, se_w3, se_b3, q, 3072, 512);
    ln_l2_q<<<dim3(Bz), blk, 0, stream>>>(q, se_g, se_be);
    keynorm<<<dim3(NEz), blk, 0, stream>>>(keys, rk);
    gemm_scores<<<dim3(32, 64), blk, 0, stream>>>(q, keys, rk, scoresU);
  }

  // --- top-16 screen, fused fp64 rescore + top-10 set + context gather ---
  topk16<<<dim3(Bz), blk, 0, stream>>>(scoresU, cand);

  // --- context + compressor ---
  if (fast) {
    // ctx -> ctxb in U (scores dead after topk; NO aliasing with q)
    rescore_gather<true><<<dim3(Bz), blk, 0, stream>>>(q, keys, rk, cand, ctxb);
    mfma_bt64<<<dim3(4, 128), blk, 0, stream>>>(ctxb, w1T, cc_b1, cch, 512, Ez);
  } else {
    // fallback: ctx fp32 overlays q row-for-row (self-row only: safe)
    rescore_gather<false><<<dim3(Bz), blk, 0, stream>>>(q, keys, rk, cand, q);
    gemm128<true, true><<<dim3(4, 64), blk, 0, stream>>>(q, cc_w1, cc_b1, cch, 512, Ez);
  }
  {
    LN4 pcc = {};
    pcc.W[0] = cc_w2; pcc.b[0] = cc_b2; pcc.g[0] = cc_g; pcc.be[0] = cc_be;
    gemm_ln4<false, false><<<dim3(128, 1), blk, 0, stream>>>(cch, 0, 512, nullptr, pcc,
                                                             shr, 0);
  }

  // --- actors (batched over blockIdx.y) ---
  {
    LN4 p1 = {}, p2 = {};
    HeadP ph = {};
    const int eoffs[4] = {0, 20, 40, 45};
    const int elens[4] = {50, 20, 10, 15};
    for (int a = 0; a < 4; ++a) {
      const int base = 17 + 10 * a;
      p1.W[a]  = (const float*)d_in[base + 0];
      p1.b[a]  = (const float*)d_in[base + 1];
      p1.g[a]  = (const float*)d_in[base + 2];
      p1.be[a] = (const float*)d_in[base + 3];
      p1.eoff[a] = eoffs[a]; p1.elen[a] = elens[a];
      p2.W[a]  = (const float*)d_in[base + 4];
      p2.b[a]  = (const float*)d_in[base + 5];
      p2.g[a]  = (const float*)d_in[base + 6];
      p2.be[a] = (const float*)d_in[base + 7];
      ph.w3[a] = (const float*)d_in[base + 8];
      ph.b3[a] = (const float*)d_in[base + 9];
    }
    gemm_ln4<true, true ><<<dim3(128, 4), blk, 0, stream>>>(shr, 0, 128, state, p1,
                                                            x1g, (size_t)Bz * 128);
    gemm_ln4<true, false><<<dim3(128, 4), blk, 0, stream>>>(x1g, (size_t)Bz * 128, 128,
                                                            nullptr, p2,
                                                            x2g, (size_t)Bz * 128);
    actor_head4<<<dim3(256), blk, 0, stream>>>(x2g, ph, outA, outL);
  }
}